// Round 9
// baseline (2028.441 us; speedup 1.0000x reference)
//
#include <hip/hip_runtime.h>
#include <float.h>

typedef unsigned int u32;
typedef unsigned long long u64;
typedef unsigned short u16;

// Bb=512, F=16 -> 8192 beam rows, D=128, DH=256, K=4096, A=32, Fo=16, M=2.
// Selection-critical math reproduces numpy's f32 arithmetic bitwise (model):
//  - matmul: per-output sequential f32 FMA over k ascending (sgemm micro-kernel)
//  - np.sum(last axis): 8-accumulator pairwise (n<=128 base case), no FMA
//  - dist/d2 combine: separate f32 mul + f32 sub (ufuncs don't fuse)
//  - all top-k: f32 keys, ties -> lower index (stable, = jax top_k & np)
// The factored MLP is a prescreen only (top-32 cut, ~17x noise margin even
// with bf16 activation storage).

static __device__ __forceinline__ u32 ordu(float f) {
  u32 u = __float_as_uint(f);
  return u ^ (u32)(((int)u >> 31) | (int)0x80000000);
}
static __device__ __forceinline__ u16 f2bf(float f) {  // RNE f32->bf16
  u32 b = __float_as_uint(f);
  b += 0x7fffu + ((b >> 16) & 1u);
  return (u16)(b >> 16);
}

// ---------------- prep ----------------

// codebook_rq [4096][128] -> cbT [128][4096]
__global__ __launch_bounds__(256) void k_cbrqT(const float* __restrict__ cbrq,
                                               float* __restrict__ cbT) {
  __shared__ float tile[128 * 33];
  const int k0 = blockIdx.x * 32;
  const int t = threadIdx.x;
#pragma unroll
  for (int rep = 0; rep < 16; ++rep) {
    const int flat = rep * 256 + t;
    const int kk = flat >> 7, d = flat & 127;
    tile[d * 33 + kk] = cbrq[(k0 + kk) * 128 + d];
  }
  __syncthreads();
#pragma unroll
  for (int rep = 0; rep < 16; ++rep) {
    const int flat = rep * 256 + t;
    const int d = flat >> 5, kk = flat & 31;
    cbT[d * 4096 + k0 + kk] = tile[d * 33 + kk];
  }
}

// cb_sq[k] = np.sum pairwise-8 emulation (exact), via cbT for coalescing
__global__ __launch_bounds__(256) void k_cbsq(const float* __restrict__ cbT,
                                              float* __restrict__ cb_sq) {
  const int k = blockIdx.x * 256 + threadIdx.x;
  float r[8];
#pragma unroll
  for (int j = 0; j < 8; ++j) {
    const float v = cbT[j * 4096 + k];
    r[j] = __fmul_rn(v, v);
  }
  for (int i = 8; i < 128; i += 8) {
#pragma unroll
    for (int j = 0; j < 8; ++j) {
      const float v = cbT[(i + j) * 4096 + k];
      r[j] = __fadd_rn(r[j], __fmul_rn(v, v));
    }
  }
  cb_sq[k] = __fadd_rn(
      __fadd_rn(__fadd_rn(r[0], r[1]), __fadd_rn(r[2], r[3])),
      __fadd_rn(__fadd_rn(r[4], r[5]), __fadd_rn(r[6], r[7])));
}

// xt f32 = x - xhat
__global__ __launch_bounds__(256) void k_xt(const float* __restrict__ x,
                                            const float* __restrict__ xhat,
                                            float* __restrict__ xt) {
  const int i = blockIdx.x * 256 + threadIdx.x;
  const int row = i >> 5, d4 = i & 31;
  const float4 a = ((const float4*)x)[(row >> 4) * 32 + d4];
  const float4 b = ((const float4*)xhat)[i];
  float4 r;
  r.x = __fsub_rn(a.x, b.x); r.y = __fsub_rn(a.y, b.y);
  r.z = __fsub_rn(a.z, b.z); r.w = __fsub_rn(a.w, b.w);
  ((float4*)xt)[i] = r;
}

// tmp_h[code][j] = seqFMA_d(cb[code][d]*in_w[d][j]) + in_b[j]
__global__ __launch_bounds__(256) void k_codeh(const float* __restrict__ cb,
                                               const float* __restrict__ in_w,
                                               const float* __restrict__ in_b,
                                               float* __restrict__ tmp_h) {
  __shared__ float row[128];
  const int code = blockIdx.x;
  const int t = threadIdx.x;
  if (t < 128) row[t] = cb[code * 128 + t];
  __syncthreads();
  float a = 0.f;
  for (int d = 0; d < 128; ++d) a = __builtin_fmaf(row[d], in_w[d * 256 + t], a);
  tmp_h[code * 256 + t] = __fadd_rn(a, in_b[t]);
}

// prescreen bias prep
__global__ __launch_bounds__(256) void k_biasprep(
    const float* __restrict__ rb_b1, const float* __restrict__ rb_b2,
    const float* __restrict__ rb_w1, const float* __restrict__ out_w,
    const float* __restrict__ out_b, float* __restrict__ bias2v,
    float* __restrict__ biasDv) {
  const int t = threadIdx.x;
  const float* w11 = rb_w1 + 65536;
  float s = rb_b1[256 + t];
  for (int i = 0; i < 256; ++i) s += rb_b2[i] * w11[i * 256 + t];
  bias2v[t] = s;
  if (t < 128) {
    float s2 = out_b[t];
    for (int i = 0; i < 256; ++i)
      s2 += (rb_b2[i] + rb_b2[256 + i]) * out_w[i * 128 + t];
    biasDv[t] = s2;
  }
}

// ---------------- generic f32 GEMM (prescreen precompute only) ----------------
__global__ __launch_bounds__(256, 4) void gemm_f32(
    const float* __restrict__ Am, const float* __restrict__ Bm,
    float* __restrict__ Cm, const int Mi, const int Ni, const int Ki,
    const float* __restrict__ bias, const float* __restrict__ addm) {
  __shared__ float As[16][68];
  __shared__ float Bs[16][68];
  const int m0 = blockIdx.x * 64, n0 = blockIdx.y * 64;
  const int t = threadIdx.x;
  const int tm = (t & 15) * 4, tn = (t >> 4) * 4;
  float acc[4][4] = {};
  for (int k0 = 0; k0 < Ki; k0 += 16) {
    {
      const int row = t >> 2, q = t & 3;
      const float4 a4 = *(const float4*)(Am + (size_t)(m0 + row) * Ki + k0 + q * 4);
      As[q * 4 + 0][row] = a4.x; As[q * 4 + 1][row] = a4.y;
      As[q * 4 + 2][row] = a4.z; As[q * 4 + 3][row] = a4.w;
      const int kk = t >> 4, n4 = t & 15;
      *(float4*)&Bs[kk][n4 * 4] =
          *(const float4*)(Bm + (size_t)(k0 + kk) * Ni + n0 + n4 * 4);
    }
    __syncthreads();
#pragma unroll
    for (int kk = 0; kk < 16; ++kk) {
      const float4 av = *(const float4*)&As[kk][tm];
      const float4 bv = *(const float4*)&Bs[kk][tn];
      const float aa[4] = {av.x, av.y, av.z, av.w};
      const float bb[4] = {bv.x, bv.y, bv.z, bv.w};
#pragma unroll
      for (int i = 0; i < 4; ++i)
#pragma unroll
        for (int j = 0; j < 4; ++j) acc[i][j] += aa[i] * bb[j];
    }
    __syncthreads();
  }
#pragma unroll
  for (int i = 0; i < 4; ++i) {
    const int m = m0 + tm + i;
#pragma unroll
    for (int j = 0; j < 4; ++j) {
      const int n = n0 + tn + j;
      float v = acc[i][j];
      if (bias) v += bias[n];
      if (addm) v += addm[(size_t)m * Ni + n];
      Cm[(size_t)m * Ni + n] = v;
    }
  }
}

// ---------------- stage 1: bitwise-np f32 dists + stable top-32 ----------------
__global__ __launch_bounds__(512, 2) void k_stage1(
    const float* __restrict__ xt, const float* __restrict__ cbT,
    const float* __restrict__ cb_sq, int* __restrict__ topc) {
  __shared__ u32 distL[4 * 4096];  // 64 KB
  __shared__ float xtL[512];
  const int r0 = blockIdx.x * 4;
  const int t = threadIdx.x;
  xtL[t] = xt[r0 * 128 + t];
  __syncthreads();
  for (int kb = 0; kb < 8; ++kb) {
    const int k = kb * 512 + t;
    float a0 = 0.f, a1 = 0.f, a2 = 0.f, a3 = 0.f;
    for (int d = 0; d < 128; ++d) {
      const float cv = cbT[d * 4096 + k];
      a0 = __builtin_fmaf(xtL[d], cv, a0);
      a1 = __builtin_fmaf(xtL[128 + d], cv, a1);
      a2 = __builtin_fmaf(xtL[256 + d], cv, a2);
      a3 = __builtin_fmaf(xtL[384 + d], cv, a3);
    }
    const float cs = cb_sq[k];
    distL[k] = ordu(__fsub_rn(cs, __fmul_rn(2.0f, a0)));
    distL[4096 + k] = ordu(__fsub_rn(cs, __fmul_rn(2.0f, a1)));
    distL[8192 + k] = ordu(__fsub_rn(cs, __fmul_rn(2.0f, a2)));
    distL[12288 + k] = ordu(__fsub_rn(cs, __fmul_rn(2.0f, a3)));
  }
  __syncthreads();
  const int w = t >> 6, lane = t & 63;
  if (w < 4) {
    u32* dr = distL + w * 4096;
    for (int it = 0; it < 32; ++it) {
      u64 m = ~0ull;
      for (int e = 0; e < 64; ++e) {
        const int idx = e * 64 + lane;
        const u64 key = ((u64)dr[idx] << 32) | (u32)idx;
        m = (key < m) ? key : m;
      }
#pragma unroll
      for (int sh = 1; sh < 64; sh <<= 1) {
        const u64 o = __shfl_xor(m, sh);
        m = (o < m) ? o : m;
      }
      const int bi = (int)(m & 0xFFFFFFFFu);
      if (lane == 0) topc[(r0 + w) * 32 + it] = bi;
      if ((bi & 63) == lane) dr[bi] = 0xFFFFFFFFu;
    }
  }
}

// ---------------- stage 2: factored MLP prescreen (bf16 act storage) ----------------
// 1 beam row / block, 256 threads. r1/r2 stored bf16 in a single reused 16KB
// LDS buffer; weights (W21,V1,V2) streamed from L2. LDS ~21.8 KB ->
// 6-7 blocks/CU -> 6-7 waves/SIMD.
__global__ __launch_bounds__(256, 6) void k_mlp(
    const int* __restrict__ topc, const float* __restrict__ A1,
    const float* __restrict__ A2, const float* __restrict__ Dc,
    const float* __restrict__ B1, const float* __restrict__ B2,
    const float* __restrict__ Dr, const float* __restrict__ W21,
    const float* __restrict__ V1, const float* __restrict__ V2,
    const float* __restrict__ xhat, const float* __restrict__ x,
    float* __restrict__ d2g) {
  __shared__ u16 sbuf[256 * 32];  // bf16 [i][c]: r1, then r2
  __shared__ float B1r[256];
  __shared__ int codesL[32];
  __shared__ float d2red[32][33];

  const int tt = threadIdx.x;
  const int r = blockIdx.x;  // beam row
  const int bb = r >> 4;

  B1r[tt] = B1[r * 256 + tt];
  if (tt < 32) codesL[tt] = topc[r * 32 + tt];
  __syncthreads();

  // phase 1: r1 = relu(A1[code] + B1) -> bf16 sbuf [i][c]
  {
    const int c = tt & 31, g = tt >> 5;
    const int code = codesL[c];
    const float4* A14 = (const float4*)(A1 + code * 256 + g * 32);
#pragma unroll
    for (int e4 = 0; e4 < 8; ++e4) {
      const float4 a = A14[e4];
      const int i = g * 32 + e4 * 4;
      sbuf[(i + 0) * 32 + c] = f2bf(fmaxf(a.x + B1r[i + 0], 0.f));
      sbuf[(i + 1) * 32 + c] = f2bf(fmaxf(a.y + B1r[i + 1], 0.f));
      sbuf[(i + 2) * 32 + c] = f2bf(fmaxf(a.z + B1r[i + 2], 0.f));
      sbuf[(i + 3) * 32 + c] = f2bf(fmaxf(a.w + B1r[i + 3], 0.f));
    }
  }
  __syncthreads();

  const int c0 = (tt & 7) * 4;
  const int d0 = (tt >> 3) * 4;
  const int j0 = (tt >> 3) * 8;

  // phase 3a: acc2 = r1 @ V1  (V1 from L2)
  float acc2[4][4] = {};
#pragma unroll 2
  for (int i = 0; i < 256; ++i) {
    const u32* q = (const u32*)&sbuf[i * 32 + c0];
    const u32 qa = q[0], qb = q[1];
    const float ra[4] = {__uint_as_float(qa << 16),
                         __uint_as_float(qa & 0xffff0000u),
                         __uint_as_float(qb << 16),
                         __uint_as_float(qb & 0xffff0000u)};
    const float4 v1 = *(const float4*)&V1[i * 128 + d0];
    const float va[4] = {v1.x, v1.y, v1.z, v1.w};
#pragma unroll
    for (int cc = 0; cc < 4; ++cc)
#pragma unroll
      for (int dd = 0; dd < 4; ++dd) acc2[cc][dd] += ra[cc] * va[dd];
  }

  // phase 2: z2 = r1 @ W21  (W21 from L2)
  float acc[4][8] = {};
#pragma unroll 2
  for (int i = 0; i < 256; ++i) {
    const u32* q = (const u32*)&sbuf[i * 32 + c0];
    const u32 qa = q[0], qb = q[1];
    const float ra[4] = {__uint_as_float(qa << 16),
                         __uint_as_float(qa & 0xffff0000u),
                         __uint_as_float(qb << 16),
                         __uint_as_float(qb & 0xffff0000u)};
    const float4 w0 = *(const float4*)&W21[i * 256 + j0];
    const float4 w1 = *(const float4*)&W21[i * 256 + j0 + 4];
    const float wa[8] = {w0.x, w0.y, w0.z, w0.w, w1.x, w1.y, w1.z, w1.w};
#pragma unroll
    for (int cc = 0; cc < 4; ++cc)
#pragma unroll
      for (int jj = 0; jj < 8; ++jj) acc[cc][jj] += ra[cc] * wa[jj];
  }
  // z2 += A2[code]+B2[row], relu
  {
    const float4 b20 = *(const float4*)&B2[r * 256 + j0];
    const float4 b21 = *(const float4*)&B2[r * 256 + j0 + 4];
    const float b2v[8] = {b20.x, b20.y, b20.z, b20.w,
                          b21.x, b21.y, b21.z, b21.w};
#pragma unroll
    for (int cc = 0; cc < 4; ++cc) {
      const int code = codesL[c0 + cc];
      const float4 a20 = *(const float4*)&A2[code * 256 + j0];
      const float4 a21 = *(const float4*)&A2[code * 256 + j0 + 4];
      const float a2v[8] = {a20.x, a20.y, a20.z, a20.w,
                            a21.x, a21.y, a21.z, a21.w};
#pragma unroll
      for (int jj = 0; jj < 8; ++jj)
        acc[cc][jj] = fmaxf(acc[cc][jj] + a2v[jj] + b2v[jj], 0.f);
    }
  }
  __syncthreads();  // all reads of r1 complete
  // write r2 (bf16, packed pairs)
  {
#pragma unroll
    for (int jj = 0; jj < 8; ++jj) {
      const u32 p0 = (u32)f2bf(acc[0][jj]) | ((u32)f2bf(acc[1][jj]) << 16);
      const u32 p1 = (u32)f2bf(acc[2][jj]) | ((u32)f2bf(acc[3][jj]) << 16);
      u32* q = (u32*)&sbuf[(j0 + jj) * 32 + c0];
      q[0] = p0; q[1] = p1;
    }
  }
  __syncthreads();

  // phase 3b: acc2 += r2 @ V2  (V2 from L2)
#pragma unroll 2
  for (int j = 0; j < 256; ++j) {
    const u32* q = (const u32*)&sbuf[j * 32 + c0];
    const u32 qa = q[0], qb = q[1];
    const float ra[4] = {__uint_as_float(qa << 16),
                         __uint_as_float(qa & 0xffff0000u),
                         __uint_as_float(qb << 16),
                         __uint_as_float(qb & 0xffff0000u)};
    const float4 v2 = *(const float4*)&V2[j * 128 + d0];
    const float va[4] = {v2.x, v2.y, v2.z, v2.w};
#pragma unroll
    for (int cc = 0; cc < 4; ++cc)
#pragma unroll
      for (int dd = 0; dd < 4; ++dd) acc2[cc][dd] += ra[cc] * va[dd];
  }

  // epilogue: d2 partials
  {
    const float4 drv = *(const float4*)&Dr[r * 128 + d0];
    const float4 xh = *(const float4*)&xhat[r * 128 + d0];
    const float4 xv = *(const float4*)&x[bb * 128 + d0];
    const float drL[4] = {drv.x, drv.y, drv.z, drv.w};
    const float xhL[4] = {xh.x, xh.y, xh.z, xh.w};
    const float xL[4] = {xv.x, xv.y, xv.z, xv.w};
#pragma unroll
    for (int cc = 0; cc < 4; ++cc) {
      const int code = codesL[c0 + cc];
      const float4 dc = *(const float4*)&Dc[code * 128 + d0];
      const float dcv[4] = {dc.x, dc.y, dc.z, dc.w};
      float s = 0.f;
#pragma unroll
      for (int dd = 0; dd < 4; ++dd) {
        const float cand = acc2[cc][dd] + dcv[dd] + drL[dd] + xhL[dd];
        s += cand * cand - 2.f * xL[dd] * cand;
      }
      d2red[c0 + cc][tt >> 3] = s;
    }
  }
  __syncthreads();
  if (tt < 32) {
    float s = 0.f;
#pragma unroll
    for (int g = 0; g < 32; ++g) s += d2red[tt][g];
    d2g[bb * 512 + (r & 15) * 32 + tt] = s;
  }
}

// ---------------- stage 3a: prescreen top-32 per base query ----------------
__global__ __launch_bounds__(64, 1) void k_sel32(const float* __restrict__ d2g,
                                                 int* __restrict__ sel32) {
  __shared__ u32 d2u[512];
  const int bb = blockIdx.x;
  const int t = threadIdx.x;
  for (int i = t; i < 512; i += 64) d2u[i] = ordu(d2g[bb * 512 + i]);
  __syncthreads();
  for (int it = 0; it < 32; ++it) {
    u64 m = ~0ull;
#pragma unroll
    for (int e = 0; e < 8; ++e) {
      const int idx = e * 64 + t;
      const u64 key = ((u64)d2u[idx] << 32) | (u32)idx;
      m = (key < m) ? key : m;
    }
#pragma unroll
    for (int sh = 1; sh < 64; sh <<= 1) {
      const u64 o = __shfl_xor(m, sh);
      m = (o < m) ? o : m;
    }
    const int s = (int)(m & 0xFFFFFFFFu);
    if ((s & 63) == t) d2u[s] = 0xFFFFFFFFu;
    if (t == 0) sel32[bb * 32 + it] = s;
  }
}

// ---------------- stage 3b: np-emulated rescore of top-32 ----------------
__global__ __launch_bounds__(256, 4) void k_rescore(
    const int* __restrict__ sel32, const int* __restrict__ topc,
    const float* __restrict__ tmp_h, const float* __restrict__ cb,
    const float* __restrict__ xhat, const float* __restrict__ x,
    const float* __restrict__ cc_w, const float* __restrict__ cc_b,
    const float* __restrict__ rb_w1, const float* __restrict__ rb_b1,
    const float* __restrict__ rb_w2, const float* __restrict__ rb_b2,
    const float* __restrict__ out_w, const float* __restrict__ out_b,
    float* __restrict__ d2r, float* __restrict__ candv) {
  __shared__ float A_[8][256], B_[8][256], C_[8][256];
  __shared__ float cbL[8][128], xhL[8][128], candL[8][128], xqL[128];
  __shared__ int codeL[8], rowL[8];
  const int bb = blockIdx.x >> 2;
  const int j0 = (blockIdx.x & 3) * 8;
  const int t = threadIdx.x;
  if (t < 8) {
    const int s = sel32[bb * 32 + j0 + t];
    rowL[t] = bb * 16 + (s >> 5);
    codeL[t] = topc[(bb * 16 + (s >> 5)) * 32 + (s & 31)];
  }
  if (t < 128) xqL[t] = x[bb * 128 + t];
  __syncthreads();
  for (int idx = t; idx < 1024; idx += 256) {
    const int c = idx >> 7, d = idx & 127;
    cbL[c][d] = cb[codeL[c] * 128 + d];
    xhL[c][d] = xhat[rowL[c] * 128 + d];
  }
  for (int idx = t; idx < 2048; idx += 256) {
    const int c = idx >> 8, i = idx & 255;
    A_[c][i] = tmp_h[codeL[c] * 256 + i];
  }
  __syncthreads();
  // h0 = seqFMA(concat(h_in, xhat) @ cc_w) + cc_b  -> B_
  {
    float acc[8] = {};
    for (int i = 0; i < 256; ++i) {
      const float w = cc_w[i * 256 + t];
#pragma unroll
      for (int c = 0; c < 8; ++c) acc[c] = __builtin_fmaf(A_[c][i], w, acc[c]);
    }
    for (int d = 0; d < 128; ++d) {
      const float w = cc_w[(256 + d) * 256 + t];
#pragma unroll
      for (int c = 0; c < 8; ++c) acc[c] = __builtin_fmaf(xhL[c][d], w, acc[c]);
    }
    const float b = cc_b[t];
#pragma unroll
    for (int c = 0; c < 8; ++c) B_[c][t] = __fadd_rn(acc[c], b);
  }
  __syncthreads();
  // r1 = relu(seqFMA(h0 @ w1_0) + b1_0) -> C_
  {
    float acc[8] = {};
    for (int i = 0; i < 256; ++i) {
      const float w = rb_w1[i * 256 + t];
#pragma unroll
      for (int c = 0; c < 8; ++c) acc[c] = __builtin_fmaf(B_[c][i], w, acc[c]);
    }
    const float b = rb_b1[t];
#pragma unroll
    for (int c = 0; c < 8; ++c) C_[c][t] = fmaxf(__fadd_rn(acc[c], b), 0.f);
  }
  __syncthreads();
  // h1 = (h0 + seqFMA(r1 @ w2_0)) + b2_0 -> A_
  {
    float acc[8] = {};
    for (int i = 0; i < 256; ++i) {
      const float w = rb_w2[i * 256 + t];
#pragma unroll
      for (int c = 0; c < 8; ++c) acc[c] = __builtin_fmaf(C_[c][i], w, acc[c]);
    }
    const float b = rb_b2[t];
#pragma unroll
    for (int c = 0; c < 8; ++c)
      A_[c][t] = __fadd_rn(__fadd_rn(B_[c][t], acc[c]), b);
  }
  __syncthreads();
  // r2 = relu(seqFMA(h1 @ w1_1) + b1_1) -> B_
  {
    float acc[8] = {};
    const float* w11 = rb_w1 + 65536;
    for (int i = 0; i < 256; ++i) {
      const float w = w11[i * 256 + t];
#pragma unroll
      for (int c = 0; c < 8; ++c) acc[c] = __builtin_fmaf(A_[c][i], w, acc[c]);
    }
    const float b = rb_b1[256 + t];
#pragma unroll
    for (int c = 0; c < 8; ++c) B_[c][t] = fmaxf(__fadd_rn(acc[c], b), 0.f);
  }
  __syncthreads();
  // h2 = (h1 + seqFMA(r2 @ w2_1)) + b2_1 -> C_
  {
    float acc[8] = {};
    const float* w21 = rb_w2 + 65536;
    for (int i = 0; i < 256; ++i) {
      const float w = w21[i * 256 + t];
#pragma unroll
      for (int c = 0; c < 8; ++c) acc[c] = __builtin_fmaf(B_[c][i], w, acc[c]);
    }
    const float b = rb_b2[256 + t];
#pragma unroll
    for (int c = 0; c < 8; ++c)
      C_[c][t] = __fadd_rn(__fadd_rn(A_[c][t], acc[c]), b);
  }
  __syncthreads();
  // cand = ((seqFMA(h2@out_w) + out_b) + cw_in) + xhat
  if (t < 128) {
    float acc[8] = {};
    for (int i = 0; i < 256; ++i) {
      const float w = out_w[i * 128 + t];
#pragma unroll
      for (int c = 0; c < 8; ++c) acc[c] = __builtin_fmaf(C_[c][i], w, acc[c]);
    }
    const float ob = out_b[t];
#pragma unroll
    for (int c = 0; c < 8; ++c) {
      const float cw_ = __fadd_rn(__fadd_rn(acc[c], ob), cbL[c][t]);
      const float cand = __fadd_rn(cw_, xhL[c][t]);
      candL[c][t] = cand;
      candv[(bb * 32 + j0 + c) * 128 + t] = cand;
    }
  }
  __syncthreads();
  if (t < 8) {
    float r[8];
#pragma unroll
    for (int j = 0; j < 8; ++j) {
      const float v = candL[t][j];
      r[j] = __fmul_rn(v, v);
    }
    for (int i = 8; i < 128; i += 8) {
#pragma unroll
      for (int j = 0; j < 8; ++j) {
        const float v = candL[t][i + j];
        r[j] = __fadd_rn(r[j], __fmul_rn(v, v));
      }
    }
    const float s1f = __fadd_rn(
        __fadd_rn(__fadd_rn(r[0], r[1]), __fadd_rn(r[2], r[3])),
        __fadd_rn(__fadd_rn(r[4], r[5]), __fadd_rn(r[6], r[7])));
    double s2 = 0.0;
    for (int d = 0; d < 128; ++d)
      s2 += (double)xqL[d] * (double)candL[t][d];
    const float s2f = (float)s2;
    d2r[bb * 32 + j0 + t] = __fsub_rn(s1f, __fmul_rn(2.0f, s2f));
  }
}

// ---------------- stage 3c/4: stable top-16 by f32 d2 ----------------
__global__ __launch_bounds__(64, 1) void k_final(
    const float* __restrict__ d2r, const int* __restrict__ sel32,
    const int* __restrict__ topc, const int* __restrict__ codes_in,
    const float* __restrict__ candv, float* __restrict__ out) {
  __shared__ u32 winLo[16];
  const int bb = blockIdx.x;
  const int t = threadIdx.x;
  u64 key = ~0ull;
  if (t < 32) {
    const u32 s = (u32)sel32[bb * 32 + t];
    key = ((u64)ordu(d2r[bb * 32 + t]) << 32) | (s << 5) | (u32)t;
  }
  for (int it = 0; it < 16; ++it) {
    u64 m = key;
#pragma unroll
    for (int sh = 1; sh < 64; sh <<= 1) {
      const u64 o = __shfl_xor(m, sh);
      m = (o < m) ? o : m;
    }
    if (key == m) key = ~0ull;
    if (t == 0) winLo[it] = (u32)(m & 0xFFFFFFFFu);
  }
  __syncthreads();
  if (t < 16) {
    const u32 lo = winLo[t];
    const int s = (int)((lo >> 5) & 511u);
    const int f = s >> 5;
    const int code = topc[(bb * 16 + f) * 32 + (s & 31)];
    float* oc = out + 512 * 16 * 128;
    oc[bb * 16 + t] = (float)codes_in[bb * 16 + f];
    oc[8192 + bb * 16 + t] = (float)codes_in[8192 + bb * 16 + f];
    oc[16384 + bb * 16 + t] = (float)code;
  }
  __syncthreads();
  for (int idx = t; idx < 2048; idx += 64) {
    const int w_ = idx >> 7, d = idx & 127;
    const int j = (int)(winLo[w_] & 31u);
    out[(bb * 16 + w_) * 128 + d] = candv[(bb * 32 + j) * 128 + d];
  }
}

// ---------------- launch ----------------
extern "C" void kernel_launch(void* const* d_in, const int* in_sizes, int n_in,
                              void* d_out, int out_size, void* d_ws,
                              size_t ws_size, hipStream_t stream) {
  const float* x = (const float*)d_in[0];
  const float* xhat = (const float*)d_in[1];
  const int* codes = (const int*)d_in[2];
  const float* cb = (const float*)d_in[3];
  const float* cbrq = (const float*)d_in[4];
  const float* in_w = (const float*)d_in[5];
  const float* in_b = (const float*)d_in[6];
  const float* cc_w = (const float*)d_in[7];
  const float* cc_b = (const float*)d_in[8];
  const float* rb_w1 = (const float*)d_in[9];
  const float* rb_b1 = (const float*)d_in[10];
  const float* rb_w2 = (const float*)d_in[11];
  const float* rb_b2 = (const float*)d_in[12];
  const float* out_w = (const float*)d_in[13];
  const float* out_b = (const float*)d_in[14];
  float* out = (float*)d_out;

  float* ws = (float*)d_ws;
  size_t o = 0;
  float* cb_sq = ws + o; o += 4096;
  float* xt = ws + o;    const size_t xt_off = o; o += (size_t)8192 * 128;
  float* cbT = ws + o;   o += (size_t)128 * 4096;
  float* tmp_h = ws + o; o += (size_t)4096 * 256;   // LIVE through k_rescore
  float* pc = ws + o;    const size_t pc_off = o; o += (size_t)4096 * 256;
  float* pb = ws + o;    o += (size_t)8192 * 256;
  float* A1 = ws + o;    o += (size_t)4096 * 256;
  float* A2 = ws + o;    o += (size_t)4096 * 256;
  float* Dc = ws + o;    o += (size_t)4096 * 128;
  float* B1 = ws + o;    o += (size_t)8192 * 256;
  float* B2 = ws + o;    o += (size_t)8192 * 256;
  float* Dr = ws + o;    o += (size_t)8192 * 128;
  float* W21 = ws + o;   o += 65536;
  float* V1 = ws + o;    o += 32768;
  float* V2 = ws + o;    o += 32768;
  float* bias2v = ws + o; o += 256;
  float* biasDv = ws + o; o += 128;
  int* topc = (int*)(ws + o); o += 262144;
  float* d2g = ws + o;   o += 262144;
  float* d2r = ws + xt_off;
  int* sel32 = (int*)(ws + xt_off + 16384);
  float* candv = ws + pc_off;

  k_cbrqT<<<dim3(128), dim3(256), 0, stream>>>(cbrq, cbT);
  k_cbsq<<<dim3(16), dim3(256), 0, stream>>>(cbT, cb_sq);
  k_xt<<<dim3(1024), dim3(256), 0, stream>>>(x, xhat, xt);
  k_biasprep<<<dim3(1), dim3(256), 0, stream>>>(rb_b1, rb_b2, rb_w1, out_w,
                                                out_b, bias2v, biasDv);
  k_codeh<<<dim3(4096), dim3(256), 0, stream>>>(cb, in_w, in_b, tmp_h);
  gemm_f32<<<dim3(64, 4), dim3(256), 0, stream>>>(tmp_h, cc_w, pc, 4096, 256,
                                                  256, nullptr, nullptr);
  gemm_f32<<<dim3(128, 4), dim3(256), 0, stream>>>(xhat, cc_w + 256 * 256, pb,
                                                   8192, 256, 128, cc_b,
                                                   nullptr);
  gemm_f32<<<dim3(64, 4), dim3(256), 0, stream>>>(pc, rb_w1, A1, 4096, 256, 256,
                                                  nullptr, nullptr);
  gemm_f32<<<dim3(64, 4), dim3(256), 0, stream>>>(pc, rb_w1 + 65536, A2, 4096,
                                                  256, 256, nullptr, nullptr);
  gemm_f32<<<dim3(64, 2), dim3(256), 0, stream>>>(pc, out_w, Dc, 4096, 128, 256,
                                                  nullptr, cb);
  gemm_f32<<<dim3(128, 4), dim3(256), 0, stream>>>(pb, rb_w1, B1, 8192, 256,
                                                   256, rb_b1, nullptr);
  gemm_f32<<<dim3(128, 4), dim3(256), 0, stream>>>(pb, rb_w1 + 65536, B2, 8192,
                                                   256, 256, bias2v, nullptr);
  gemm_f32<<<dim3(128, 2), dim3(256), 0, stream>>>(pb, out_w, Dr, 8192, 128,
                                                   256, biasDv, nullptr);
  gemm_f32<<<dim3(4, 4), dim3(256), 0, stream>>>(rb_w2, rb_w1 + 65536, W21, 256,
                                                 256, 256, nullptr, nullptr);
  gemm_f32<<<dim3(4, 2), dim3(256), 0, stream>>>(rb_w2, out_w, V1, 256, 128,
                                                 256, nullptr, nullptr);
  gemm_f32<<<dim3(4, 2), dim3(256), 0, stream>>>(rb_w2 + 65536, out_w, V2, 256,
                                                 128, 256, nullptr, nullptr);

  k_stage1<<<dim3(2048), dim3(512), 0, stream>>>(xt, cbT, cb_sq, topc);
  k_mlp<<<dim3(8192), dim3(256), 0, stream>>>(topc, A1, A2, Dc, B1, B2, Dr, W21,
                                              V1, V2, xhat, x, d2g);
  k_sel32<<<dim3(512), dim3(64), 0, stream>>>(d2g, sel32);
  k_rescore<<<dim3(2048), dim3(256), 0, stream>>>(
      sel32, topc, tmp_h, cb, xhat, x, cc_w, cc_b, rb_w1, rb_b1, rb_w2, rb_b2,
      out_w, out_b, d2r, candv);
  k_final<<<dim3(512), dim3(64), 0, stream>>>(d2r, sel32, topc, codes, candv,
                                              out);
  (void)in_sizes; (void)n_in; (void)out_size; (void)ws_size;
}

// Round 10
// 1133.357 us; speedup vs baseline: 1.7898x; 1.7898x over previous
//
#include <hip/hip_runtime.h>
#include <float.h>

typedef unsigned int u32;
typedef unsigned long long u64;
typedef unsigned short u16;
typedef __attribute__((ext_vector_type(8))) short s16x8;
typedef __attribute__((ext_vector_type(4))) float f32x4;

// Bb=512, F=16 -> 8192 beam rows, D=128, DH=256, K=4096, A=32, Fo=16, M=2.
// Selection-critical math reproduces numpy's f32 arithmetic bitwise (model):
//  - matmul: per-output sequential f32 FMA over k ascending (sgemm micro-kernel)
//  - np.sum(last axis): 8-accumulator pairwise (n<=128 base case), no FMA
//  - dist/d2 combine: separate f32 mul + f32 sub (ufuncs don't fuse)
//  - all top-k: f32 keys, ties -> lower index (stable, = jax top_k & np)
// The factored MLP prescreen (top-32 cut, ~17x margin) now runs on MFMA
// (bf16 fragments). k-slot permutation cancels between A and B frags; C/D
// mapping col=lane&15,row=(lane>>4)*4+reg is HW-verified.

static __device__ __forceinline__ u32 ordu(float f) {
  u32 u = __float_as_uint(f);
  return u ^ (u32)(((int)u >> 31) | (int)0x80000000);
}
static __device__ __forceinline__ u16 f2bf(float f) {  // RNE f32->bf16
  u32 b = __float_as_uint(f);
  b += 0x7fffu + ((b >> 16) & 1u);
  return (u16)(b >> 16);
}

// ---------------- prep ----------------

__global__ __launch_bounds__(256) void k_cbrqT(const float* __restrict__ cbrq,
                                               float* __restrict__ cbT) {
  __shared__ float tile[128 * 33];
  const int k0 = blockIdx.x * 32;
  const int t = threadIdx.x;
#pragma unroll
  for (int rep = 0; rep < 16; ++rep) {
    const int flat = rep * 256 + t;
    const int kk = flat >> 7, d = flat & 127;
    tile[d * 33 + kk] = cbrq[(k0 + kk) * 128 + d];
  }
  __syncthreads();
#pragma unroll
  for (int rep = 0; rep < 16; ++rep) {
    const int flat = rep * 256 + t;
    const int d = flat >> 5, kk = flat & 31;
    cbT[d * 4096 + k0 + kk] = tile[d * 33 + kk];
  }
}

__global__ __launch_bounds__(256) void k_cbsq(const float* __restrict__ cbT,
                                              float* __restrict__ cb_sq) {
  const int k = blockIdx.x * 256 + threadIdx.x;
  float r[8];
#pragma unroll
  for (int j = 0; j < 8; ++j) {
    const float v = cbT[j * 4096 + k];
    r[j] = __fmul_rn(v, v);
  }
  for (int i = 8; i < 128; i += 8) {
#pragma unroll
    for (int j = 0; j < 8; ++j) {
      const float v = cbT[(i + j) * 4096 + k];
      r[j] = __fadd_rn(r[j], __fmul_rn(v, v));
    }
  }
  cb_sq[k] = __fadd_rn(
      __fadd_rn(__fadd_rn(r[0], r[1]), __fadd_rn(r[2], r[3])),
      __fadd_rn(__fadd_rn(r[4], r[5]), __fadd_rn(r[6], r[7])));
}

__global__ __launch_bounds__(256) void k_xt(const float* __restrict__ x,
                                            const float* __restrict__ xhat,
                                            float* __restrict__ xt) {
  const int i = blockIdx.x * 256 + threadIdx.x;
  const int row = i >> 5, d4 = i & 31;
  const float4 a = ((const float4*)x)[(row >> 4) * 32 + d4];
  const float4 b = ((const float4*)xhat)[i];
  float4 r;
  r.x = __fsub_rn(a.x, b.x); r.y = __fsub_rn(a.y, b.y);
  r.z = __fsub_rn(a.z, b.z); r.w = __fsub_rn(a.w, b.w);
  ((float4*)xt)[i] = r;
}

__global__ __launch_bounds__(256) void k_codeh(const float* __restrict__ cb,
                                               const float* __restrict__ in_w,
                                               const float* __restrict__ in_b,
                                               float* __restrict__ tmp_h) {
  __shared__ float row[128];
  const int code = blockIdx.x;
  const int t = threadIdx.x;
  if (t < 128) row[t] = cb[code * 128 + t];
  __syncthreads();
  float a = 0.f;
  for (int d = 0; d < 128; ++d) a = __builtin_fmaf(row[d], in_w[d * 256 + t], a);
  tmp_h[code * 256 + t] = __fadd_rn(a, in_b[t]);
}

__global__ __launch_bounds__(256) void k_biasprep(
    const float* __restrict__ rb_b1, const float* __restrict__ rb_b2,
    const float* __restrict__ rb_w1, const float* __restrict__ out_w,
    const float* __restrict__ out_b, float* __restrict__ bias2v,
    float* __restrict__ biasDv) {
  const int t = threadIdx.x;
  const float* w11 = rb_w1 + 65536;
  float s = rb_b1[256 + t];
  for (int i = 0; i < 256; ++i) s += rb_b2[i] * w11[i * 256 + t];
  bias2v[t] = s;
  if (t < 128) {
    float s2 = out_b[t];
    for (int i = 0; i < 256; ++i)
      s2 += (rb_b2[i] + rb_b2[256 + i]) * out_w[i * 128 + t];
    biasDv[t] = s2;
  }
}

// pack W21/V1/V2 (f32) into bf16 MFMA B-fragment layout:
// frag (kt,nt), lane l, elem j  <-  W[kt*32 + (l>>4)*8 + j][nt*16 + (l&15)]
__global__ __launch_bounds__(256) void k_wfrag(
    const float* __restrict__ W21, const float* __restrict__ V1,
    const float* __restrict__ V2, u16* __restrict__ W21f,
    u16* __restrict__ V1f, u16* __restrict__ V2f) {
  const int gid = blockIdx.x * 256 + threadIdx.x;  // 16384 total
  const int l = gid & 63;
  const int grp = gid >> 6;  // [0,256)
  const int kq = (l >> 4) * 8;
  const int nn = l & 15;
  if (grp < 128) {
    const int kt = grp >> 4, nt = grp & 15;
    u16* dst = W21f + (size_t)(grp * 64 + l) * 8;
#pragma unroll
    for (int j = 0; j < 8; ++j)
      dst[j] = f2bf(W21[(kt * 32 + kq + j) * 256 + nt * 16 + nn]);
  } else if (grp < 192) {
    const int g2 = grp - 128, kt = g2 >> 3, nt = g2 & 7;
    u16* dst = V1f + (size_t)(g2 * 64 + l) * 8;
#pragma unroll
    for (int j = 0; j < 8; ++j)
      dst[j] = f2bf(V1[(kt * 32 + kq + j) * 128 + nt * 16 + nn]);
  } else {
    const int g2 = grp - 192, kt = g2 >> 3, nt = g2 & 7;
    u16* dst = V2f + (size_t)(g2 * 64 + l) * 8;
#pragma unroll
    for (int j = 0; j < 8; ++j)
      dst[j] = f2bf(V2[(kt * 32 + kq + j) * 128 + nt * 16 + nn]);
  }
}

// ---------------- generic f32 GEMM (prescreen precompute only) ----------------
__global__ __launch_bounds__(256, 4) void gemm_f32(
    const float* __restrict__ Am, const float* __restrict__ Bm,
    float* __restrict__ Cm, const int Mi, const int Ni, const int Ki,
    const float* __restrict__ bias, const float* __restrict__ addm) {
  __shared__ float As[16][68];
  __shared__ float Bs[16][68];
  const int m0 = blockIdx.x * 64, n0 = blockIdx.y * 64;
  const int t = threadIdx.x;
  const int tm = (t & 15) * 4, tn = (t >> 4) * 4;
  float acc[4][4] = {};
  for (int k0 = 0; k0 < Ki; k0 += 16) {
    {
      const int row = t >> 2, q = t & 3;
      const float4 a4 = *(const float4*)(Am + (size_t)(m0 + row) * Ki + k0 + q * 4);
      As[q * 4 + 0][row] = a4.x; As[q * 4 + 1][row] = a4.y;
      As[q * 4 + 2][row] = a4.z; As[q * 4 + 3][row] = a4.w;
      const int kk = t >> 4, n4 = t & 15;
      *(float4*)&Bs[kk][n4 * 4] =
          *(const float4*)(Bm + (size_t)(k0 + kk) * Ni + n0 + n4 * 4);
    }
    __syncthreads();
#pragma unroll
    for (int kk = 0; kk < 16; ++kk) {
      const float4 av = *(const float4*)&As[kk][tm];
      const float4 bv = *(const float4*)&Bs[kk][tn];
      const float aa[4] = {av.x, av.y, av.z, av.w};
      const float bb[4] = {bv.x, bv.y, bv.z, bv.w};
#pragma unroll
      for (int i = 0; i < 4; ++i)
#pragma unroll
        for (int j = 0; j < 4; ++j) acc[i][j] += aa[i] * bb[j];
    }
    __syncthreads();
  }
#pragma unroll
  for (int i = 0; i < 4; ++i) {
    const int m = m0 + tm + i;
#pragma unroll
    for (int j = 0; j < 4; ++j) {
      const int n = n0 + tn + j;
      float v = acc[i][j];
      if (bias) v += bias[n];
      if (addm) v += addm[(size_t)m * Ni + n];
      Cm[(size_t)m * Ni + n] = v;
    }
  }
}

// ---------------- stage 1: bitwise-np f32 dists + stable top-32 ----------------
__global__ __launch_bounds__(512, 2) void k_stage1(
    const float* __restrict__ xt, const float* __restrict__ cbT,
    const float* __restrict__ cb_sq, int* __restrict__ topc) {
  __shared__ u32 distL[4 * 4096];  // 64 KB
  __shared__ float xtL[512];
  const int r0 = blockIdx.x * 4;
  const int t = threadIdx.x;
  xtL[t] = xt[r0 * 128 + t];
  __syncthreads();
  for (int kb = 0; kb < 8; ++kb) {
    const int k = kb * 512 + t;
    float a0 = 0.f, a1 = 0.f, a2 = 0.f, a3 = 0.f;
    for (int d = 0; d < 128; ++d) {
      const float cv = cbT[d * 4096 + k];
      a0 = __builtin_fmaf(xtL[d], cv, a0);
      a1 = __builtin_fmaf(xtL[128 + d], cv, a1);
      a2 = __builtin_fmaf(xtL[256 + d], cv, a2);
      a3 = __builtin_fmaf(xtL[384 + d], cv, a3);
    }
    const float cs = cb_sq[k];
    distL[k] = ordu(__fsub_rn(cs, __fmul_rn(2.0f, a0)));
    distL[4096 + k] = ordu(__fsub_rn(cs, __fmul_rn(2.0f, a1)));
    distL[8192 + k] = ordu(__fsub_rn(cs, __fmul_rn(2.0f, a2)));
    distL[12288 + k] = ordu(__fsub_rn(cs, __fmul_rn(2.0f, a3)));
  }
  __syncthreads();
  const int w = t >> 6, lane = t & 63;
  if (w < 4) {
    u32* dr = distL + w * 4096;
    for (int it = 0; it < 32; ++it) {
      u64 m = ~0ull;
      for (int e = 0; e < 64; ++e) {
        const int idx = e * 64 + lane;
        const u64 key = ((u64)dr[idx] << 32) | (u32)idx;
        m = (key < m) ? key : m;
      }
#pragma unroll
      for (int sh = 1; sh < 64; sh <<= 1) {
        const u64 o = __shfl_xor(m, sh);
        m = (o < m) ? o : m;
      }
      const int bi = (int)(m & 0xFFFFFFFFu);
      if (lane == 0) topc[(r0 + w) * 32 + it] = bi;
      if ((bi & 63) == lane) dr[bi] = 0xFFFFFFFFu;
    }
  }
}

// ---------------- stage 2: MFMA bf16 prescreen ----------------
// 1 beam row / block, 256 threads = 4 waves. r1/r2 bf16 in padded LDS
// ([32][264]); weight frags streamed from L2. Wave w: z2 cols [w*64,w*64+64),
// cw cols [w*32,w*32+32).
__global__ __launch_bounds__(256, 4) void k_mlp(
    const int* __restrict__ topc, const float* __restrict__ A1,
    const float* __restrict__ A2, const float* __restrict__ B1,
    const float* __restrict__ B2, const float* __restrict__ Dc,
    const float* __restrict__ Dr, const u16* __restrict__ W21f,
    const u16* __restrict__ V1f, const u16* __restrict__ V2f,
    const float* __restrict__ xhat, const float* __restrict__ x,
    float* __restrict__ d2g) {
  __shared__ __align__(16) u16 abuf[32 * 264];  // 16.5 KB, r1 then r2
  __shared__ float B1r[256];
  __shared__ int codesL[32];
  __shared__ float d2red[32][4];

  const int tt = threadIdx.x;
  const int br = blockIdx.x;  // beam row
  const int bb = br >> 4;
  const int w = tt >> 6, l = tt & 63;

  B1r[tt] = B1[br * 256 + tt];
  if (tt < 32) codesL[tt] = topc[br * 32 + tt];
  __syncthreads();

  // phase 1: r1 = relu(A1[code]+B1) -> abuf bf16 [cand][264]
  {
    const int c = tt & 31, g = tt >> 5;
    const int code = codesL[c];
    const float4* A14 = (const float4*)(A1 + code * 256 + g * 32);
    u32* dst = (u32*)(abuf + c * 264 + g * 32);
#pragma unroll
    for (int e4 = 0; e4 < 8; ++e4) {
      const float4 a = A14[e4];
      const int i = g * 32 + e4 * 4;
      const u32 p0 = (u32)f2bf(fmaxf(a.x + B1r[i], 0.f)) |
                     ((u32)f2bf(fmaxf(a.y + B1r[i + 1], 0.f)) << 16);
      const u32 p1 = (u32)f2bf(fmaxf(a.z + B1r[i + 2], 0.f)) |
                     ((u32)f2bf(fmaxf(a.w + B1r[i + 3], 0.f)) << 16);
      dst[e4 * 2] = p0;
      dst[e4 * 2 + 1] = p1;
    }
  }
  __syncthreads();

  const int arow = l & 15;       // m within tile / n within tile
  const int kq = (l >> 4) * 8;   // k base within 32-k tile
  const s16x8* wf = (const s16x8*)W21f;
  const s16x8* v1f = (const s16x8*)V1f;
  const s16x8* v2f = (const s16x8*)V2f;
  const f32x4 zero4 = {0.f, 0.f, 0.f, 0.f};

  // phase 2: z2 = r1 @ W21
  f32x4 accf[2][4];
#pragma unroll
  for (int mt = 0; mt < 2; ++mt)
#pragma unroll
    for (int ntl = 0; ntl < 4; ++ntl) accf[mt][ntl] = zero4;
  for (int kt = 0; kt < 8; ++kt) {
    const s16x8 a0 = *(const s16x8*)(abuf + arow * 264 + kt * 32 + kq);
    const s16x8 a1 = *(const s16x8*)(abuf + (16 + arow) * 264 + kt * 32 + kq);
#pragma unroll
    for (int ntl = 0; ntl < 4; ++ntl) {
      const s16x8 b = wf[(kt * 16 + w * 4 + ntl) * 64 + l];
      accf[0][ntl] =
          __builtin_amdgcn_mfma_f32_16x16x32_bf16(a0, b, accf[0][ntl], 0, 0, 0);
      accf[1][ntl] =
          __builtin_amdgcn_mfma_f32_16x16x32_bf16(a1, b, accf[1][ntl], 0, 0, 0);
    }
  }

  // phase 3a: acc2 = r1 @ V1
  f32x4 acc2f[2][2];
#pragma unroll
  for (int mt = 0; mt < 2; ++mt)
#pragma unroll
    for (int ntl = 0; ntl < 2; ++ntl) acc2f[mt][ntl] = zero4;
  for (int kt = 0; kt < 8; ++kt) {
    const s16x8 a0 = *(const s16x8*)(abuf + arow * 264 + kt * 32 + kq);
    const s16x8 a1 = *(const s16x8*)(abuf + (16 + arow) * 264 + kt * 32 + kq);
#pragma unroll
    for (int ntl = 0; ntl < 2; ++ntl) {
      const s16x8 b = v1f[(kt * 8 + w * 2 + ntl) * 64 + l];
      acc2f[0][ntl] = __builtin_amdgcn_mfma_f32_16x16x32_bf16(
          a0, b, acc2f[0][ntl], 0, 0, 0);
      acc2f[1][ntl] = __builtin_amdgcn_mfma_f32_16x16x32_bf16(
          a1, b, acc2f[1][ntl], 0, 0, 0);
    }
  }

  // z2 epilogue: r2 = relu(z2 + A2[code] + B2[row]) (values to regs)
  u16 r2v[2][4][4];
#pragma unroll
  for (int mt = 0; mt < 2; ++mt)
#pragma unroll
    for (int ntl = 0; ntl < 4; ++ntl) {
      const int n = w * 64 + ntl * 16 + arow;
      const float b2 = B2[br * 256 + n];
      const f32x4 cf = accf[mt][ntl];
#pragma unroll
      for (int rg = 0; rg < 4; ++rg) {
        const int m = mt * 16 + (l >> 4) * 4 + rg;
        const float a2 = A2[codesL[m] * 256 + n];
        r2v[mt][ntl][rg] = f2bf(fmaxf(cf[rg] + a2 + b2, 0.f));
      }
    }
  __syncthreads();  // all r1 reads complete
#pragma unroll
  for (int mt = 0; mt < 2; ++mt)
#pragma unroll
    for (int ntl = 0; ntl < 4; ++ntl) {
      const int n = w * 64 + ntl * 16 + arow;
#pragma unroll
      for (int rg = 0; rg < 4; ++rg) {
        const int m = mt * 16 + (l >> 4) * 4 + rg;
        abuf[m * 264 + n] = r2v[mt][ntl][rg];
      }
    }
  __syncthreads();

  // phase 3b: acc2 += r2 @ V2
  for (int kt = 0; kt < 8; ++kt) {
    const s16x8 a0 = *(const s16x8*)(abuf + arow * 264 + kt * 32 + kq);
    const s16x8 a1 = *(const s16x8*)(abuf + (16 + arow) * 264 + kt * 32 + kq);
#pragma unroll
    for (int ntl = 0; ntl < 2; ++ntl) {
      const s16x8 b = v2f[(kt * 8 + w * 2 + ntl) * 64 + l];
      acc2f[0][ntl] = __builtin_amdgcn_mfma_f32_16x16x32_bf16(
          a0, b, acc2f[0][ntl], 0, 0, 0);
      acc2f[1][ntl] = __builtin_amdgcn_mfma_f32_16x16x32_bf16(
          a1, b, acc2f[1][ntl], 0, 0, 0);
    }
  }

  // d2 epilogue
  float sm[2][4];
#pragma unroll
  for (int mt = 0; mt < 2; ++mt)
#pragma unroll
    for (int rg = 0; rg < 4; ++rg) sm[mt][rg] = 0.f;
#pragma unroll
  for (int ntl = 0; ntl < 2; ++ntl) {
    const int d = w * 32 + ntl * 16 + arow;
    const float dr = Dr[br * 128 + d];
    const float xh = xhat[br * 128 + d];
    const float xq = x[bb * 128 + d];
#pragma unroll
    for (int mt = 0; mt < 2; ++mt) {
      const f32x4 cf = acc2f[mt][ntl];
#pragma unroll
      for (int rg = 0; rg < 4; ++rg) {
        const int m = mt * 16 + (l >> 4) * 4 + rg;
        const float cand = cf[rg] + Dc[codesL[m] * 128 + d] + dr + xh;
        sm[mt][rg] += cand * cand - 2.f * xq * cand;
      }
    }
  }
#pragma unroll
  for (int mt = 0; mt < 2; ++mt)
#pragma unroll
    for (int rg = 0; rg < 4; ++rg) {
      float s = sm[mt][rg];
      s += __shfl_xor(s, 1);
      s += __shfl_xor(s, 2);
      s += __shfl_xor(s, 4);
      s += __shfl_xor(s, 8);
      if (arow == 0) d2red[mt * 16 + (l >> 4) * 4 + rg][w] = s;
    }
  __syncthreads();
  if (tt < 32)
    d2g[bb * 512 + (br & 15) * 32 + tt] =
        d2red[tt][0] + d2red[tt][1] + d2red[tt][2] + d2red[tt][3];
}

// ---------------- stage 3a: prescreen top-32 per base query ----------------
__global__ __launch_bounds__(64, 1) void k_sel32(const float* __restrict__ d2g,
                                                 int* __restrict__ sel32) {
  __shared__ u32 d2u[512];
  const int bb = blockIdx.x;
  const int t = threadIdx.x;
  for (int i = t; i < 512; i += 64) d2u[i] = ordu(d2g[bb * 512 + i]);
  __syncthreads();
  for (int it = 0; it < 32; ++it) {
    u64 m = ~0ull;
#pragma unroll
    for (int e = 0; e < 8; ++e) {
      const int idx = e * 64 + t;
      const u64 key = ((u64)d2u[idx] << 32) | (u32)idx;
      m = (key < m) ? key : m;
    }
#pragma unroll
    for (int sh = 1; sh < 64; sh <<= 1) {
      const u64 o = __shfl_xor(m, sh);
      m = (o < m) ? o : m;
    }
    const int s = (int)(m & 0xFFFFFFFFu);
    if ((s & 63) == t) d2u[s] = 0xFFFFFFFFu;
    if (t == 0) sel32[bb * 32 + it] = s;
  }
}

// ---------------- stage 3b: np-emulated rescore of top-32 ----------------
__global__ __launch_bounds__(256, 4) void k_rescore(
    const int* __restrict__ sel32, const int* __restrict__ topc,
    const float* __restrict__ tmp_h, const float* __restrict__ cb,
    const float* __restrict__ xhat, const float* __restrict__ x,
    const float* __restrict__ cc_w, const float* __restrict__ cc_b,
    const float* __restrict__ rb_w1, const float* __restrict__ rb_b1,
    const float* __restrict__ rb_w2, const float* __restrict__ rb_b2,
    const float* __restrict__ out_w, const float* __restrict__ out_b,
    float* __restrict__ d2r, float* __restrict__ candv) {
  __shared__ float A_[8][256], B_[8][256], C_[8][256];
  __shared__ float cbL[8][128], xhL[8][128], candL[8][128], xqL[128];
  __shared__ int codeL[8], rowL[8];
  const int bb = blockIdx.x >> 2;
  const int j0 = (blockIdx.x & 3) * 8;
  const int t = threadIdx.x;
  if (t < 8) {
    const int s = sel32[bb * 32 + j0 + t];
    rowL[t] = bb * 16 + (s >> 5);
    codeL[t] = topc[(bb * 16 + (s >> 5)) * 32 + (s & 31)];
  }
  if (t < 128) xqL[t] = x[bb * 128 + t];
  __syncthreads();
  for (int idx = t; idx < 1024; idx += 256) {
    const int c = idx >> 7, d = idx & 127;
    cbL[c][d] = cb[codeL[c] * 128 + d];
    xhL[c][d] = xhat[rowL[c] * 128 + d];
  }
  for (int idx = t; idx < 2048; idx += 256) {
    const int c = idx >> 8, i = idx & 255;
    A_[c][i] = tmp_h[codeL[c] * 256 + i];
  }
  __syncthreads();
  {
    float acc[8] = {};
    for (int i = 0; i < 256; ++i) {
      const float w = cc_w[i * 256 + t];
#pragma unroll
      for (int c = 0; c < 8; ++c) acc[c] = __builtin_fmaf(A_[c][i], w, acc[c]);
    }
    for (int d = 0; d < 128; ++d) {
      const float w = cc_w[(256 + d) * 256 + t];
#pragma unroll
      for (int c = 0; c < 8; ++c) acc[c] = __builtin_fmaf(xhL[c][d], w, acc[c]);
    }
    const float b = cc_b[t];
#pragma unroll
    for (int c = 0; c < 8; ++c) B_[c][t] = __fadd_rn(acc[c], b);
  }
  __syncthreads();
  {
    float acc[8] = {};
    for (int i = 0; i < 256; ++i) {
      const float w = rb_w1[i * 256 + t];
#pragma unroll
      for (int c = 0; c < 8; ++c) acc[c] = __builtin_fmaf(B_[c][i], w, acc[c]);
    }
    const float b = rb_b1[t];
#pragma unroll
    for (int c = 0; c < 8; ++c) C_[c][t] = fmaxf(__fadd_rn(acc[c], b), 0.f);
  }
  __syncthreads();
  {
    float acc[8] = {};
    for (int i = 0; i < 256; ++i) {
      const float w = rb_w2[i * 256 + t];
#pragma unroll
      for (int c = 0; c < 8; ++c) acc[c] = __builtin_fmaf(C_[c][i], w, acc[c]);
    }
    const float b = rb_b2[t];
#pragma unroll
    for (int c = 0; c < 8; ++c)
      A_[c][t] = __fadd_rn(__fadd_rn(B_[c][t], acc[c]), b);
  }
  __syncthreads();
  {
    float acc[8] = {};
    const float* w11 = rb_w1 + 65536;
    for (int i = 0; i < 256; ++i) {
      const float w = w11[i * 256 + t];
#pragma unroll
      for (int c = 0; c < 8; ++c) acc[c] = __builtin_fmaf(A_[c][i], w, acc[c]);
    }
    const float b = rb_b1[256 + t];
#pragma unroll
    for (int c = 0; c < 8; ++c) B_[c][t] = fmaxf(__fadd_rn(acc[c], b), 0.f);
  }
  __syncthreads();
  {
    float acc[8] = {};
    const float* w21 = rb_w2 + 65536;
    for (int i = 0; i < 256; ++i) {
      const float w = w21[i * 256 + t];
#pragma unroll
      for (int c = 0; c < 8; ++c) acc[c] = __builtin_fmaf(B_[c][i], w, acc[c]);
    }
    const float b = rb_b2[256 + t];
#pragma unroll
    for (int c = 0; c < 8; ++c)
      C_[c][t] = __fadd_rn(__fadd_rn(A_[c][t], acc[c]), b);
  }
  __syncthreads();
  if (t < 128) {
    float acc[8] = {};
    for (int i = 0; i < 256; ++i) {
      const float w = out_w[i * 128 + t];
#pragma unroll
      for (int c = 0; c < 8; ++c) acc[c] = __builtin_fmaf(C_[c][i], w, acc[c]);
    }
    const float ob = out_b[t];
#pragma unroll
    for (int c = 0; c < 8; ++c) {
      const float cw_ = __fadd_rn(__fadd_rn(acc[c], ob), cbL[c][t]);
      const float cand = __fadd_rn(cw_, xhL[c][t]);
      candL[c][t] = cand;
      candv[(bb * 32 + j0 + c) * 128 + t] = cand;
    }
  }
  __syncthreads();
  if (t < 8) {
    float r[8];
#pragma unroll
    for (int j = 0; j < 8; ++j) {
      const float v = candL[t][j];
      r[j] = __fmul_rn(v, v);
    }
    for (int i = 8; i < 128; i += 8) {
#pragma unroll
      for (int j = 0; j < 8; ++j) {
        const float v = candL[t][i + j];
        r[j] = __fadd_rn(r[j], __fmul_rn(v, v));
      }
    }
    const float s1f = __fadd_rn(
        __fadd_rn(__fadd_rn(r[0], r[1]), __fadd_rn(r[2], r[3])),
        __fadd_rn(__fadd_rn(r[4], r[5]), __fadd_rn(r[6], r[7])));
    double s2 = 0.0;
    for (int d = 0; d < 128; ++d)
      s2 += (double)xqL[d] * (double)candL[t][d];
    const float s2f = (float)s2;
    d2r[bb * 32 + j0 + t] = __fsub_rn(s1f, __fmul_rn(2.0f, s2f));
  }
}

// ---------------- stage 3c/4: stable top-16 by f32 d2 ----------------
__global__ __launch_bounds__(64, 1) void k_final(
    const float* __restrict__ d2r, const int* __restrict__ sel32,
    const int* __restrict__ topc, const int* __restrict__ codes_in,
    const float* __restrict__ candv, float* __restrict__ out) {
  __shared__ u32 winLo[16];
  const int bb = blockIdx.x;
  const int t = threadIdx.x;
  u64 key = ~0ull;
  if (t < 32) {
    const u32 s = (u32)sel32[bb * 32 + t];
    key = ((u64)ordu(d2r[bb * 32 + t]) << 32) | (s << 5) | (u32)t;
  }
  for (int it = 0; it < 16; ++it) {
    u64 m = key;
#pragma unroll
    for (int sh = 1; sh < 64; sh <<= 1) {
      const u64 o = __shfl_xor(m, sh);
      m = (o < m) ? o : m;
    }
    if (key == m) key = ~0ull;
    if (t == 0) winLo[it] = (u32)(m & 0xFFFFFFFFu);
  }
  __syncthreads();
  if (t < 16) {
    const u32 lo = winLo[t];
    const int s = (int)((lo >> 5) & 511u);
    const int f = s >> 5;
    const int code = topc[(bb * 16 + f) * 32 + (s & 31)];
    float* oc = out + 512 * 16 * 128;
    oc[bb * 16 + t] = (float)codes_in[bb * 16 + f];
    oc[8192 + bb * 16 + t] = (float)codes_in[8192 + bb * 16 + f];
    oc[16384 + bb * 16 + t] = (float)code;
  }
  __syncthreads();
  for (int idx = t; idx < 2048; idx += 64) {
    const int w_ = idx >> 7, d = idx & 127;
    const int j = (int)(winLo[w_] & 31u);
    out[(bb * 16 + w_) * 128 + d] = candv[(bb * 32 + j) * 128 + d];
  }
}

// ---------------- launch ----------------
extern "C" void kernel_launch(void* const* d_in, const int* in_sizes, int n_in,
                              void* d_out, int out_size, void* d_ws,
                              size_t ws_size, hipStream_t stream) {
  const float* x = (const float*)d_in[0];
  const float* xhat = (const float*)d_in[1];
  const int* codes = (const int*)d_in[2];
  const float* cb = (const float*)d_in[3];
  const float* cbrq = (const float*)d_in[4];
  const float* in_w = (const float*)d_in[5];
  const float* in_b = (const float*)d_in[6];
  const float* cc_w = (const float*)d_in[7];
  const float* cc_b = (const float*)d_in[8];
  const float* rb_w1 = (const float*)d_in[9];
  const float* rb_b1 = (const float*)d_in[10];
  const float* rb_w2 = (const float*)d_in[11];
  const float* rb_b2 = (const float*)d_in[12];
  const float* out_w = (const float*)d_in[13];
  const float* out_b = (const float*)d_in[14];
  float* out = (float*)d_out;

  float* ws = (float*)d_ws;
  size_t o = 0;
  float* cb_sq = ws + o; o += 4096;
  float* xt = ws + o;    const size_t xt_off = o; o += (size_t)8192 * 128;
  float* cbT = ws + o;   o += (size_t)128 * 4096;
  float* tmp_h = ws + o; o += (size_t)4096 * 256;   // LIVE through k_rescore
  float* pc = ws + o;    const size_t pc_off = o; o += (size_t)4096 * 256;
  float* pb = ws + o;    o += (size_t)8192 * 256;
  float* A1 = ws + o;    o += (size_t)4096 * 256;
  float* A2 = ws + o;    o += (size_t)4096 * 256;
  float* Dc = ws + o;    o += (size_t)4096 * 128;
  float* B1 = ws + o;    o += (size_t)8192 * 256;
  float* B2 = ws + o;    o += (size_t)8192 * 256;
  float* Dr = ws + o;    o += (size_t)8192 * 128;
  float* W21 = ws + o;   o += 65536;
  float* V1 = ws + o;    o += 32768;
  float* V2 = ws + o;    o += 32768;
  float* bias2v = ws + o; o += 256;
  float* biasDv = ws + o; o += 128;
  int* topc = (int*)(ws + o); o += 262144;
  float* d2g = ws + o;   o += 262144;
  u16* W21f = (u16*)(ws + o); o += 32768;  // 65536 bf16
  u16* V1f = (u16*)(ws + o);  o += 16384;  // 32768 bf16
  u16* V2f = (u16*)(ws + o);  o += 16384;
  float* d2r = ws + xt_off;
  int* sel32 = (int*)(ws + xt_off + 16384);
  float* candv = ws + pc_off;

  k_cbrqT<<<dim3(128), dim3(256), 0, stream>>>(cbrq, cbT);
  k_cbsq<<<dim3(16), dim3(256), 0, stream>>>(cbT, cb_sq);
  k_xt<<<dim3(1024), dim3(256), 0, stream>>>(x, xhat, xt);
  k_biasprep<<<dim3(1), dim3(256), 0, stream>>>(rb_b1, rb_b2, rb_w1, out_w,
                                                out_b, bias2v, biasDv);
  k_codeh<<<dim3(4096), dim3(256), 0, stream>>>(cb, in_w, in_b, tmp_h);
  gemm_f32<<<dim3(64, 4), dim3(256), 0, stream>>>(tmp_h, cc_w, pc, 4096, 256,
                                                  256, nullptr, nullptr);
  gemm_f32<<<dim3(128, 4), dim3(256), 0, stream>>>(xhat, cc_w + 256 * 256, pb,
                                                   8192, 256, 128, cc_b,
                                                   nullptr);
  gemm_f32<<<dim3(64, 4), dim3(256), 0, stream>>>(pc, rb_w1, A1, 4096, 256, 256,
                                                  nullptr, nullptr);
  gemm_f32<<<dim3(64, 4), dim3(256), 0, stream>>>(pc, rb_w1 + 65536, A2, 4096,
                                                  256, 256, nullptr, nullptr);
  gemm_f32<<<dim3(64, 2), dim3(256), 0, stream>>>(pc, out_w, Dc, 4096, 128, 256,
                                                  nullptr, cb);
  gemm_f32<<<dim3(128, 4), dim3(256), 0, stream>>>(pb, rb_w1, B1, 8192, 256,
                                                   256, rb_b1, nullptr);
  gemm_f32<<<dim3(128, 4), dim3(256), 0, stream>>>(pb, rb_w1 + 65536, B2, 8192,
                                                   256, 256, bias2v, nullptr);
  gemm_f32<<<dim3(128, 2), dim3(256), 0, stream>>>(pb, out_w, Dr, 8192, 128,
                                                   256, biasDv, nullptr);
  gemm_f32<<<dim3(4, 4), dim3(256), 0, stream>>>(rb_w2, rb_w1 + 65536, W21, 256,
                                                 256, 256, nullptr, nullptr);
  gemm_f32<<<dim3(4, 2), dim3(256), 0, stream>>>(rb_w2, out_w, V1, 256, 128,
                                                 256, nullptr, nullptr);
  gemm_f32<<<dim3(4, 2), dim3(256), 0, stream>>>(rb_w2 + 65536, out_w, V2, 256,
                                                 128, 256, nullptr, nullptr);
  k_wfrag<<<dim3(64), dim3(256), 0, stream>>>(W21, V1, V2, W21f, V1f, V2f);

  k_stage1<<<dim3(2048), dim3(512), 0, stream>>>(xt, cbT, cb_sq, topc);
  k_mlp<<<dim3(8192), dim3(256), 0, stream>>>(topc, A1, A2, B1, B2, Dc, Dr,
                                              W21f, V1f, V2f, xhat, x, d2g);
  k_sel32<<<dim3(512), dim3(64), 0, stream>>>(d2g, sel32);
  k_rescore<<<dim3(2048), dim3(256), 0, stream>>>(
      sel32, topc, tmp_h, cb, xhat, x, cc_w, cc_b, rb_w1, rb_b1, rb_w2, rb_b2,
      out_w, out_b, d2r, candv);
  k_final<<<dim3(512), dim3(64), 0, stream>>>(d2r, sel32, topc, codes, candv,
                                              out);
  (void)in_sizes; (void)n_in; (void)out_size; (void)ws_size;
}

// Round 11
// 922.959 us; speedup vs baseline: 2.1978x; 1.2280x over previous
//
#include <hip/hip_runtime.h>
#include <float.h>

typedef unsigned int u32;
typedef unsigned long long u64;
typedef unsigned short u16;
typedef __attribute__((ext_vector_type(8))) short s16x8;
typedef __attribute__((ext_vector_type(4))) float f32x4;

// Bb=512, F=16 -> 8192 beam rows, D=128, DH=256, K=4096, A=32, Fo=16, M=2.
// Selection-critical math reproduces numpy's f32 arithmetic bitwise (model):
//  - matmul: per-output sequential f32 FMA over k ascending (sgemm micro-kernel)
//  - np.sum(last axis): 8-accumulator pairwise (n<=128 base case), no FMA
//  - dist/d2 combine: separate f32 mul + f32 sub (ufuncs don't fuse)
//  - all top-k: f32 keys, ties -> lower index (stable, = jax top_k & np)
// The factored MLP prescreen (top-32 cut, ~17x margin) runs on MFMA bf16.

static __device__ __forceinline__ u32 ordu(float f) {
  u32 u = __float_as_uint(f);
  return u ^ (u32)(((int)u >> 31) | (int)0x80000000);
}
static __device__ __forceinline__ u16 f2bf(float f) {  // RNE f32->bf16
  u32 b = __float_as_uint(f);
  b += 0x7fffu + ((b >> 16) & 1u);
  return (u16)(b >> 16);
}

// ---------------- prep ----------------

__global__ __launch_bounds__(256) void k_cbrqT(const float* __restrict__ cbrq,
                                               float* __restrict__ cbT) {
  __shared__ float tile[128 * 33];
  const int k0 = blockIdx.x * 32;
  const int t = threadIdx.x;
#pragma unroll
  for (int rep = 0; rep < 16; ++rep) {
    const int flat = rep * 256 + t;
    const int kk = flat >> 7, d = flat & 127;
    tile[d * 33 + kk] = cbrq[(k0 + kk) * 128 + d];
  }
  __syncthreads();
#pragma unroll
  for (int rep = 0; rep < 16; ++rep) {
    const int flat = rep * 256 + t;
    const int d = flat >> 5, kk = flat & 31;
    cbT[d * 4096 + k0 + kk] = tile[d * 33 + kk];
  }
}

__global__ __launch_bounds__(256) void k_cbsq(const float* __restrict__ cbT,
                                              float* __restrict__ cb_sq) {
  const int k = blockIdx.x * 256 + threadIdx.x;
  float r[8];
#pragma unroll
  for (int j = 0; j < 8; ++j) {
    const float v = cbT[j * 4096 + k];
    r[j] = __fmul_rn(v, v);
  }
  for (int i = 8; i < 128; i += 8) {
#pragma unroll
    for (int j = 0; j < 8; ++j) {
      const float v = cbT[(i + j) * 4096 + k];
      r[j] = __fadd_rn(r[j], __fmul_rn(v, v));
    }
  }
  cb_sq[k] = __fadd_rn(
      __fadd_rn(__fadd_rn(r[0], r[1]), __fadd_rn(r[2], r[3])),
      __fadd_rn(__fadd_rn(r[4], r[5]), __fadd_rn(r[6], r[7])));
}

__global__ __launch_bounds__(256) void k_xt(const float* __restrict__ x,
                                            const float* __restrict__ xhat,
                                            float* __restrict__ xt) {
  const int i = blockIdx.x * 256 + threadIdx.x;
  const int row = i >> 5, d4 = i & 31;
  const float4 a = ((const float4*)x)[(row >> 4) * 32 + d4];
  const float4 b = ((const float4*)xhat)[i];
  float4 r;
  r.x = __fsub_rn(a.x, b.x); r.y = __fsub_rn(a.y, b.y);
  r.z = __fsub_rn(a.z, b.z); r.w = __fsub_rn(a.w, b.w);
  ((float4*)xt)[i] = r;
}

__global__ __launch_bounds__(256) void k_codeh(const float* __restrict__ cb,
                                               const float* __restrict__ in_w,
                                               const float* __restrict__ in_b,
                                               float* __restrict__ tmp_h) {
  __shared__ float row[128];
  const int code = blockIdx.x;
  const int t = threadIdx.x;
  if (t < 128) row[t] = cb[code * 128 + t];
  __syncthreads();
  float a = 0.f;
  for (int d = 0; d < 128; ++d) a = __builtin_fmaf(row[d], in_w[d * 256 + t], a);
  tmp_h[code * 256 + t] = __fadd_rn(a, in_b[t]);
}

__global__ __launch_bounds__(256) void k_biasprep(
    const float* __restrict__ rb_b1, const float* __restrict__ rb_b2,
    const float* __restrict__ rb_w1, const float* __restrict__ out_w,
    const float* __restrict__ out_b, float* __restrict__ bias2v,
    float* __restrict__ biasDv) {
  const int t = threadIdx.x;
  const float* w11 = rb_w1 + 65536;
  float s = rb_b1[256 + t];
  for (int i = 0; i < 256; ++i) s += rb_b2[i] * w11[i * 256 + t];
  bias2v[t] = s;
  if (t < 128) {
    float s2 = out_b[t];
    for (int i = 0; i < 256; ++i)
      s2 += (rb_b2[i] + rb_b2[256 + i]) * out_w[i * 128 + t];
    biasDv[t] = s2;
  }
}

// pack W21/V1/V2 (f32) into bf16 MFMA B-fragment layout
__global__ __launch_bounds__(256) void k_wfrag(
    const float* __restrict__ W21, const float* __restrict__ V1,
    const float* __restrict__ V2, u16* __restrict__ W21f,
    u16* __restrict__ V1f, u16* __restrict__ V2f) {
  const int gid = blockIdx.x * 256 + threadIdx.x;  // 16384 total
  const int l = gid & 63;
  const int grp = gid >> 6;  // [0,256)
  const int kq = (l >> 4) * 8;
  const int nn = l & 15;
  if (grp < 128) {
    const int kt = grp >> 4, nt = grp & 15;
    u16* dst = W21f + (size_t)(grp * 64 + l) * 8;
#pragma unroll
    for (int j = 0; j < 8; ++j)
      dst[j] = f2bf(W21[(kt * 32 + kq + j) * 256 + nt * 16 + nn]);
  } else if (grp < 192) {
    const int g2 = grp - 128, kt = g2 >> 3, nt = g2 & 7;
    u16* dst = V1f + (size_t)(g2 * 64 + l) * 8;
#pragma unroll
    for (int j = 0; j < 8; ++j)
      dst[j] = f2bf(V1[(kt * 32 + kq + j) * 128 + nt * 16 + nn]);
  } else {
    const int g2 = grp - 192, kt = g2 >> 3, nt = g2 & 7;
    u16* dst = V2f + (size_t)(g2 * 64 + l) * 8;
#pragma unroll
    for (int j = 0; j < 8; ++j)
      dst[j] = f2bf(V2[(kt * 32 + kq + j) * 128 + nt * 16 + nn]);
  }
}

// ---------------- generic f32 GEMM (prescreen precompute only) ----------------
__global__ __launch_bounds__(256, 4) void gemm_f32(
    const float* __restrict__ Am, const float* __restrict__ Bm,
    float* __restrict__ Cm, const int Mi, const int Ni, const int Ki,
    const float* __restrict__ bias, const float* __restrict__ addm) {
  __shared__ float As[16][68];
  __shared__ float Bs[16][68];
  const int m0 = blockIdx.x * 64, n0 = blockIdx.y * 64;
  const int t = threadIdx.x;
  const int tm = (t & 15) * 4, tn = (t >> 4) * 4;
  float acc[4][4] = {};
  for (int k0 = 0; k0 < Ki; k0 += 16) {
    {
      const int row = t >> 2, q = t & 3;
      const float4 a4 = *(const float4*)(Am + (size_t)(m0 + row) * Ki + k0 + q * 4);
      As[q * 4 + 0][row] = a4.x; As[q * 4 + 1][row] = a4.y;
      As[q * 4 + 2][row] = a4.z; As[q * 4 + 3][row] = a4.w;
      const int kk = t >> 4, n4 = t & 15;
      *(float4*)&Bs[kk][n4 * 4] =
          *(const float4*)(Bm + (size_t)(k0 + kk) * Ni + n0 + n4 * 4);
    }
    __syncthreads();
#pragma unroll
    for (int kk = 0; kk < 16; ++kk) {
      const float4 av = *(const float4*)&As[kk][tm];
      const float4 bv = *(const float4*)&Bs[kk][tn];
      const float aa[4] = {av.x, av.y, av.z, av.w};
      const float bb[4] = {bv.x, bv.y, bv.z, bv.w};
#pragma unroll
      for (int i = 0; i < 4; ++i)
#pragma unroll
        for (int j = 0; j < 4; ++j) acc[i][j] += aa[i] * bb[j];
    }
    __syncthreads();
  }
#pragma unroll
  for (int i = 0; i < 4; ++i) {
    const int m = m0 + tm + i;
#pragma unroll
    for (int j = 0; j < 4; ++j) {
      const int n = n0 + tn + j;
      float v = acc[i][j];
      if (bias) v += bias[n];
      if (addm) v += addm[(size_t)m * Ni + n];
      Cm[(size_t)m * Ni + n] = v;
    }
  }
}

// ---------------- stage 1: bitwise-np f32 dists + stable top-32 ----------------
// 4 rows/block, 512 threads. Thread owns 8 consecutive k-cols x 4 rows (32 acc,
// seq-FMA over d -> bitwise-np). Extraction: per-lane reg top-2 + u64 butterfly
// pops; full strip rescan only when a lane wins twice (rare).
__global__ __launch_bounds__(512, 2) void k_stage1(
    const float* __restrict__ xt, const float* __restrict__ cbT,
    const float* __restrict__ cb_sq, int* __restrict__ topc) {
  __shared__ u32 distL[4 * 4096];  // 64 KB
  __shared__ float xtL[512];
  const int r0 = blockIdx.x * 4;
  const int t = threadIdx.x;
  xtL[t] = xt[r0 * 128 + t];
  __syncthreads();
  {
    const int k0 = t * 8;
    float acc[4][8] = {};
    for (int d = 0; d < 128; ++d) {
      const float4 c0 = *(const float4*)&cbT[d * 4096 + k0];
      const float4 c1 = *(const float4*)&cbT[d * 4096 + k0 + 4];
      const float cv[8] = {c0.x, c0.y, c0.z, c0.w, c1.x, c1.y, c1.z, c1.w};
      const float x0 = xtL[d], x1 = xtL[128 + d], x2 = xtL[256 + d],
                  x3 = xtL[384 + d];
#pragma unroll
      for (int j = 0; j < 8; ++j) {
        acc[0][j] = __builtin_fmaf(x0, cv[j], acc[0][j]);
        acc[1][j] = __builtin_fmaf(x1, cv[j], acc[1][j]);
        acc[2][j] = __builtin_fmaf(x2, cv[j], acc[2][j]);
        acc[3][j] = __builtin_fmaf(x3, cv[j], acc[3][j]);
      }
    }
    const float4 s0 = *(const float4*)&cb_sq[k0];
    const float4 s1 = *(const float4*)&cb_sq[k0 + 4];
    const float cs[8] = {s0.x, s0.y, s0.z, s0.w, s1.x, s1.y, s1.z, s1.w};
#pragma unroll
    for (int rr = 0; rr < 4; ++rr)
#pragma unroll
      for (int j = 0; j < 8; ++j)
        distL[rr * 4096 + k0 + j] =
            ordu(__fsub_rn(cs[j], __fmul_rn(2.0f, acc[rr][j])));
  }
  __syncthreads();
  const int w = t >> 6, lane = t & 63;
  if (w < 4) {
    u32* dr = distL + w * 4096;
    // per-lane register top-2 of strip idx = e*64+lane
    u64 m1 = ~0ull, m2 = ~0ull;
    for (int e = 0; e < 64; ++e) {
      const int idx = e * 64 + lane;
      const u64 key = ((u64)dr[idx] << 32) | (u32)idx;
      if (key < m1) { m2 = m1; m1 = key; } else if (key < m2) { m2 = key; }
    }
    bool have2 = true;
    for (int it = 0; it < 32; ++it) {
      u64 g = m1;
#pragma unroll
      for (int sh = 1; sh < 64; sh <<= 1) {
        const u64 o = __shfl_xor(g, sh);
        g = (o < g) ? o : g;
      }
      const int bi = (int)(g & 0xFFFFFFFFu);
      if (lane == 0) topc[(r0 + w) * 32 + it] = bi;
      if ((bi & 63) == lane) {
        dr[bi] = 0xFFFFFFFFu;  // mark removed (> any real ordu key)
        if (have2) {
          m1 = m2; m2 = ~0ull; have2 = false;
        } else {
          m1 = m2 = ~0ull;
          for (int e = 0; e < 64; ++e) {
            const int idx = e * 64 + lane;
            const u64 key = ((u64)dr[idx] << 32) | (u32)idx;
            if (key < m1) { m2 = m1; m1 = key; } else if (key < m2) { m2 = key; }
          }
          have2 = true;
        }
      }
    }
  }
}

// ---------------- stage 2: MFMA bf16 prescreen ----------------
__global__ __launch_bounds__(256, 4) void k_mlp(
    const int* __restrict__ topc, const float* __restrict__ A1,
    const float* __restrict__ A2, const float* __restrict__ B1,
    const float* __restrict__ B2, const float* __restrict__ Dc,
    const float* __restrict__ Dr, const u16* __restrict__ W21f,
    const u16* __restrict__ V1f, const u16* __restrict__ V2f,
    const float* __restrict__ xhat, const float* __restrict__ x,
    float* __restrict__ d2g) {
  __shared__ __align__(16) u16 abuf[32 * 264];  // 16.5 KB, r1 then r2
  __shared__ float B1r[256];
  __shared__ int codesL[32];
  __shared__ float d2red[32][4];

  const int tt = threadIdx.x;
  const int br = blockIdx.x;  // beam row
  const int bb = br >> 4;
  const int w = tt >> 6, l = tt & 63;

  B1r[tt] = B1[br * 256 + tt];
  if (tt < 32) codesL[tt] = topc[br * 32 + tt];
  __syncthreads();

  // phase 1: r1 = relu(A1[code]+B1) -> abuf bf16 [cand][264]
  {
    const int c = tt & 31, g = tt >> 5;
    const int code = codesL[c];
    const float4* A14 = (const float4*)(A1 + code * 256 + g * 32);
    u32* dst = (u32*)(abuf + c * 264 + g * 32);
#pragma unroll
    for (int e4 = 0; e4 < 8; ++e4) {
      const float4 a = A14[e4];
      const int i = g * 32 + e4 * 4;
      const u32 p0 = (u32)f2bf(fmaxf(a.x + B1r[i], 0.f)) |
                     ((u32)f2bf(fmaxf(a.y + B1r[i + 1], 0.f)) << 16);
      const u32 p1 = (u32)f2bf(fmaxf(a.z + B1r[i + 2], 0.f)) |
                     ((u32)f2bf(fmaxf(a.w + B1r[i + 3], 0.f)) << 16);
      dst[e4 * 2] = p0;
      dst[e4 * 2 + 1] = p1;
    }
  }
  __syncthreads();

  const int arow = l & 15;
  const int kq = (l >> 4) * 8;
  const s16x8* wf = (const s16x8*)W21f;
  const s16x8* v1f = (const s16x8*)V1f;
  const s16x8* v2f = (const s16x8*)V2f;
  const f32x4 zero4 = {0.f, 0.f, 0.f, 0.f};

  // phase 2: z2 = r1 @ W21
  f32x4 accf[2][4];
#pragma unroll
  for (int mt = 0; mt < 2; ++mt)
#pragma unroll
    for (int ntl = 0; ntl < 4; ++ntl) accf[mt][ntl] = zero4;
  for (int kt = 0; kt < 8; ++kt) {
    const s16x8 a0 = *(const s16x8*)(abuf + arow * 264 + kt * 32 + kq);
    const s16x8 a1 = *(const s16x8*)(abuf + (16 + arow) * 264 + kt * 32 + kq);
#pragma unroll
    for (int ntl = 0; ntl < 4; ++ntl) {
      const s16x8 b = wf[(kt * 16 + w * 4 + ntl) * 64 + l];
      accf[0][ntl] =
          __builtin_amdgcn_mfma_f32_16x16x32_bf16(a0, b, accf[0][ntl], 0, 0, 0);
      accf[1][ntl] =
          __builtin_amdgcn_mfma_f32_16x16x32_bf16(a1, b, accf[1][ntl], 0, 0, 0);
    }
  }

  // phase 3a: acc2 = r1 @ V1
  f32x4 acc2f[2][2];
#pragma unroll
  for (int mt = 0; mt < 2; ++mt)
#pragma unroll
    for (int ntl = 0; ntl < 2; ++ntl) acc2f[mt][ntl] = zero4;
  for (int kt = 0; kt < 8; ++kt) {
    const s16x8 a0 = *(const s16x8*)(abuf + arow * 264 + kt * 32 + kq);
    const s16x8 a1 = *(const s16x8*)(abuf + (16 + arow) * 264 + kt * 32 + kq);
#pragma unroll
    for (int ntl = 0; ntl < 2; ++ntl) {
      const s16x8 b = v1f[(kt * 8 + w * 2 + ntl) * 64 + l];
      acc2f[0][ntl] = __builtin_amdgcn_mfma_f32_16x16x32_bf16(
          a0, b, acc2f[0][ntl], 0, 0, 0);
      acc2f[1][ntl] = __builtin_amdgcn_mfma_f32_16x16x32_bf16(
          a1, b, acc2f[1][ntl], 0, 0, 0);
    }
  }

  // z2 epilogue: r2 = relu(z2 + A2[code] + B2[row])
  u16 r2v[2][4][4];
#pragma unroll
  for (int mt = 0; mt < 2; ++mt)
#pragma unroll
    for (int ntl = 0; ntl < 4; ++ntl) {
      const int n = w * 64 + ntl * 16 + arow;
      const float b2 = B2[br * 256 + n];
      const f32x4 cf = accf[mt][ntl];
#pragma unroll
      for (int rg = 0; rg < 4; ++rg) {
        const int m = mt * 16 + (l >> 4) * 4 + rg;
        const float a2 = A2[codesL[m] * 256 + n];
        r2v[mt][ntl][rg] = f2bf(fmaxf(cf[rg] + a2 + b2, 0.f));
      }
    }
  __syncthreads();
#pragma unroll
  for (int mt = 0; mt < 2; ++mt)
#pragma unroll
    for (int ntl = 0; ntl < 4; ++ntl) {
      const int n = w * 64 + ntl * 16 + arow;
#pragma unroll
      for (int rg = 0; rg < 4; ++rg) {
        const int m = mt * 16 + (l >> 4) * 4 + rg;
        abuf[m * 264 + n] = r2v[mt][ntl][rg];
      }
    }
  __syncthreads();

  // phase 3b: acc2 += r2 @ V2
  for (int kt = 0; kt < 8; ++kt) {
    const s16x8 a0 = *(const s16x8*)(abuf + arow * 264 + kt * 32 + kq);
    const s16x8 a1 = *(const s16x8*)(abuf + (16 + arow) * 264 + kt * 32 + kq);
#pragma unroll
    for (int ntl = 0; ntl < 2; ++ntl) {
      const s16x8 b = v2f[(kt * 8 + w * 2 + ntl) * 64 + l];
      acc2f[0][ntl] = __builtin_amdgcn_mfma_f32_16x16x32_bf16(
          a0, b, acc2f[0][ntl], 0, 0, 0);
      acc2f[1][ntl] = __builtin_amdgcn_mfma_f32_16x16x32_bf16(
          a1, b, acc2f[1][ntl], 0, 0, 0);
    }
  }

  // d2 epilogue
  float sm[2][4];
#pragma unroll
  for (int mt = 0; mt < 2; ++mt)
#pragma unroll
    for (int rg = 0; rg < 4; ++rg) sm[mt][rg] = 0.f;
#pragma unroll
  for (int ntl = 0; ntl < 2; ++ntl) {
    const int d = w * 32 + ntl * 16 + arow;
    const float dr = Dr[br * 128 + d];
    const float xh = xhat[br * 128 + d];
    const float xq = x[bb * 128 + d];
#pragma unroll
    for (int mt = 0; mt < 2; ++mt) {
      const f32x4 cf = acc2f[mt][ntl];
#pragma unroll
      for (int rg = 0; rg < 4; ++rg) {
        const int m = mt * 16 + (l >> 4) * 4 + rg;
        const float cand = cf[rg] + Dc[codesL[m] * 128 + d] + dr + xh;
        sm[mt][rg] += cand * cand - 2.f * xq * cand;
      }
    }
  }
#pragma unroll
  for (int mt = 0; mt < 2; ++mt)
#pragma unroll
    for (int rg = 0; rg < 4; ++rg) {
      float s = sm[mt][rg];
      s += __shfl_xor(s, 1);
      s += __shfl_xor(s, 2);
      s += __shfl_xor(s, 4);
      s += __shfl_xor(s, 8);
      if (arow == 0) d2red[mt * 16 + (l >> 4) * 4 + rg][w] = s;
    }
  __syncthreads();
  if (tt < 32)
    d2g[bb * 512 + (br & 15) * 32 + tt] =
        d2red[tt][0] + d2red[tt][1] + d2red[tt][2] + d2red[tt][3];
}

// ---------------- stage 3a: prescreen top-32 per base query ----------------
__global__ __launch_bounds__(64, 1) void k_sel32(const float* __restrict__ d2g,
                                                 int* __restrict__ sel32) {
  __shared__ u32 d2u[512];
  const int bb = blockIdx.x;
  const int t = threadIdx.x;
  for (int i = t; i < 512; i += 64) d2u[i] = ordu(d2g[bb * 512 + i]);
  __syncthreads();
  for (int it = 0; it < 32; ++it) {
    u64 m = ~0ull;
#pragma unroll
    for (int e = 0; e < 8; ++e) {
      const int idx = e * 64 + t;
      const u64 key = ((u64)d2u[idx] << 32) | (u32)idx;
      m = (key < m) ? key : m;
    }
#pragma unroll
    for (int sh = 1; sh < 64; sh <<= 1) {
      const u64 o = __shfl_xor(m, sh);
      m = (o < m) ? o : m;
    }
    const int s = (int)(m & 0xFFFFFFFFu);
    if ((s & 63) == t) d2u[s] = 0xFFFFFFFFu;
    if (t == 0) sel32[bb * 32 + it] = s;
  }
}

// ---------------- stage 3b: np-emulated rescore of top-32 ----------------
__global__ __launch_bounds__(256, 4) void k_rescore(
    const int* __restrict__ sel32, const int* __restrict__ topc,
    const float* __restrict__ tmp_h, const float* __restrict__ cb,
    const float* __restrict__ xhat, const float* __restrict__ x,
    const float* __restrict__ cc_w, const float* __restrict__ cc_b,
    const float* __restrict__ rb_w1, const float* __restrict__ rb_b1,
    const float* __restrict__ rb_w2, const float* __restrict__ rb_b2,
    const float* __restrict__ out_w, const float* __restrict__ out_b,
    float* __restrict__ d2r, float* __restrict__ candv) {
  __shared__ float A_[8][256], B_[8][256], C_[8][256];
  __shared__ float cbL[8][128], xhL[8][128], candL[8][128], xqL[128];
  __shared__ int codeL[8], rowL[8];
  const int bb = blockIdx.x >> 2;
  const int j0 = (blockIdx.x & 3) * 8;
  const int t = threadIdx.x;
  if (t < 8) {
    const int s = sel32[bb * 32 + j0 + t];
    rowL[t] = bb * 16 + (s >> 5);
    codeL[t] = topc[(bb * 16 + (s >> 5)) * 32 + (s & 31)];
  }
  if (t < 128) xqL[t] = x[bb * 128 + t];
  __syncthreads();
  for (int idx = t; idx < 1024; idx += 256) {
    const int c = idx >> 7, d = idx & 127;
    cbL[c][d] = cb[codeL[c] * 128 + d];
    xhL[c][d] = xhat[rowL[c] * 128 + d];
  }
  for (int idx = t; idx < 2048; idx += 256) {
    const int c = idx >> 8, i = idx & 255;
    A_[c][i] = tmp_h[codeL[c] * 256 + i];
  }
  __syncthreads();
  {
    float acc[8] = {};
    for (int i = 0; i < 256; ++i) {
      const float w = cc_w[i * 256 + t];
#pragma unroll
      for (int c = 0; c < 8; ++c) acc[c] = __builtin_fmaf(A_[c][i], w, acc[c]);
    }
    for (int d = 0; d < 128; ++d) {
      const float w = cc_w[(256 + d) * 256 + t];
#pragma unroll
      for (int c = 0; c < 8; ++c) acc[c] = __builtin_fmaf(xhL[c][d], w, acc[c]);
    }
    const float b = cc_b[t];
#pragma unroll
    for (int c = 0; c < 8; ++c) B_[c][t] = __fadd_rn(acc[c], b);
  }
  __syncthreads();
  {
    float acc[8] = {};
    for (int i = 0; i < 256; ++i) {
      const float w = rb_w1[i * 256 + t];
#pragma unroll
      for (int c = 0; c < 8; ++c) acc[c] = __builtin_fmaf(B_[c][i], w, acc[c]);
    }
    const float b = rb_b1[t];
#pragma unroll
    for (int c = 0; c < 8; ++c) C_[c][t] = fmaxf(__fadd_rn(acc[c], b), 0.f);
  }
  __syncthreads();
  {
    float acc[8] = {};
    for (int i = 0; i < 256; ++i) {
      const float w = rb_w2[i * 256 + t];
#pragma unroll
      for (int c = 0; c < 8; ++c) acc[c] = __builtin_fmaf(C_[c][i], w, acc[c]);
    }
    const float b = rb_b2[t];
#pragma unroll
    for (int c = 0; c < 8; ++c)
      A_[c][t] = __fadd_rn(__fadd_rn(B_[c][t], acc[c]), b);
  }
  __syncthreads();
  {
    float acc[8] = {};
    const float* w11 = rb_w1 + 65536;
    for (int i = 0; i < 256; ++i) {
      const float w = w11[i * 256 + t];
#pragma unroll
      for (int c = 0; c < 8; ++c) acc[c] = __builtin_fmaf(A_[c][i], w, acc[c]);
    }
    const float b = rb_b1[256 + t];
#pragma unroll
    for (int c = 0; c < 8; ++c) B_[c][t] = fmaxf(__fadd_rn(acc[c], b), 0.f);
  }
  __syncthreads();
  {
    float acc[8] = {};
    const float* w21 = rb_w2 + 65536;
    for (int i = 0; i < 256; ++i) {
      const float w = w21[i * 256 + t];
#pragma unroll
      for (int c = 0; c < 8; ++c) acc[c] = __builtin_fmaf(B_[c][i], w, acc[c]);
    }
    const float b = rb_b2[256 + t];
#pragma unroll
    for (int c = 0; c < 8; ++c)
      C_[c][t] = __fadd_rn(__fadd_rn(A_[c][t], acc[c]), b);
  }
  __syncthreads();
  if (t < 128) {
    float acc[8] = {};
    for (int i = 0; i < 256; ++i) {
      const float w = out_w[i * 128 + t];
#pragma unroll
      for (int c = 0; c < 8; ++c) acc[c] = __builtin_fmaf(C_[c][i], w, acc[c]);
    }
    const float ob = out_b[t];
#pragma unroll
    for (int c = 0; c < 8; ++c) {
      const float cw_ = __fadd_rn(__fadd_rn(acc[c], ob), cbL[c][t]);
      const float cand = __fadd_rn(cw_, xhL[c][t]);
      candL[c][t] = cand;
      candv[(bb * 32 + j0 + c) * 128 + t] = cand;
    }
  }
  __syncthreads();
  if (t < 8) {
    float r[8];
#pragma unroll
    for (int j = 0; j < 8; ++j) {
      const float v = candL[t][j];
      r[j] = __fmul_rn(v, v);
    }
    for (int i = 8; i < 128; i += 8) {
#pragma unroll
      for (int j = 0; j < 8; ++j) {
        const float v = candL[t][i + j];
        r[j] = __fadd_rn(r[j], __fmul_rn(v, v));
      }
    }
    const float s1f = __fadd_rn(
        __fadd_rn(__fadd_rn(r[0], r[1]), __fadd_rn(r[2], r[3])),
        __fadd_rn(__fadd_rn(r[4], r[5]), __fadd_rn(r[6], r[7])));
    double s2 = 0.0;
    for (int d = 0; d < 128; ++d)
      s2 += (double)xqL[d] * (double)candL[t][d];
    const float s2f = (float)s2;
    d2r[bb * 32 + j0 + t] = __fsub_rn(s1f, __fmul_rn(2.0f, s2f));
  }
}

// ---------------- stage 3c/4: stable top-16 by f32 d2 ----------------
__global__ __launch_bounds__(64, 1) void k_final(
    const float* __restrict__ d2r, const int* __restrict__ sel32,
    const int* __restrict__ topc, const int* __restrict__ codes_in,
    const float* __restrict__ candv, float* __restrict__ out) {
  __shared__ u32 winLo[16];
  const int bb = blockIdx.x;
  const int t = threadIdx.x;
  u64 key = ~0ull;
  if (t < 32) {
    const u32 s = (u32)sel32[bb * 32 + t];
    key = ((u64)ordu(d2r[bb * 32 + t]) << 32) | (s << 5) | (u32)t;
  }
  for (int it = 0; it < 16; ++it) {
    u64 m = key;
#pragma unroll
    for (int sh = 1; sh < 64; sh <<= 1) {
      const u64 o = __shfl_xor(m, sh);
      m = (o < m) ? o : m;
    }
    if (key == m) key = ~0ull;
    if (t == 0) winLo[it] = (u32)(m & 0xFFFFFFFFu);
  }
  __syncthreads();
  if (t < 16) {
    const u32 lo = winLo[t];
    const int s = (int)((lo >> 5) & 511u);
    const int f = s >> 5;
    const int code = topc[(bb * 16 + f) * 32 + (s & 31)];
    float* oc = out + 512 * 16 * 128;
    oc[bb * 16 + t] = (float)codes_in[bb * 16 + f];
    oc[8192 + bb * 16 + t] = (float)codes_in[8192 + bb * 16 + f];
    oc[16384 + bb * 16 + t] = (float)code;
  }
  __syncthreads();
  for (int idx = t; idx < 2048; idx += 64) {
    const int w_ = idx >> 7, d = idx & 127;
    const int j = (int)(winLo[w_] & 31u);
    out[(bb * 16 + w_) * 128 + d] = candv[(bb * 32 + j) * 128 + d];
  }
}

// ---------------- launch ----------------
extern "C" void kernel_launch(void* const* d_in, const int* in_sizes, int n_in,
                              void* d_out, int out_size, void* d_ws,
                              size_t ws_size, hipStream_t stream) {
  const float* x = (const float*)d_in[0];
  const float* xhat = (const float*)d_in[1];
  const int* codes = (const int*)d_in[2];
  const float* cb = (const float*)d_in[3];
  const float* cbrq = (const float*)d_in[4];
  const float* in_w = (const float*)d_in[5];
  const float* in_b = (const float*)d_in[6];
  const float* cc_w = (const float*)d_in[7];
  const float* cc_b = (const float*)d_in[8];
  const float* rb_w1 = (const float*)d_in[9];
  const float* rb_b1 = (const float*)d_in[10];
  const float* rb_w2 = (const float*)d_in[11];
  const float* rb_b2 = (const float*)d_in[12];
  const float* out_w = (const float*)d_in[13];
  const float* out_b = (const float*)d_in[14];
  float* out = (float*)d_out;

  float* ws = (float*)d_ws;
  size_t o = 0;
  float* cb_sq = ws + o; o += 4096;
  float* xt = ws + o;    const size_t xt_off = o; o += (size_t)8192 * 128;
  float* cbT = ws + o;   o += (size_t)128 * 4096;
  float* tmp_h = ws + o; o += (size_t)4096 * 256;   // LIVE through k_rescore
  float* pc = ws + o;    const size_t pc_off = o; o += (size_t)4096 * 256;
  float* pb = ws + o;    o += (size_t)8192 * 256;
  float* A1 = ws + o;    o += (size_t)4096 * 256;
  float* A2 = ws + o;    o += (size_t)4096 * 256;
  float* Dc = ws + o;    o += (size_t)4096 * 128;
  float* B1 = ws + o;    o += (size_t)8192 * 256;
  float* B2 = ws + o;    o += (size_t)8192 * 256;
  float* Dr = ws + o;    o += (size_t)8192 * 128;
  float* W21 = ws + o;   o += 65536;
  float* V1 = ws + o;    o += 32768;
  float* V2 = ws + o;    o += 32768;
  float* bias2v = ws + o; o += 256;
  float* biasDv = ws + o; o += 128;
  int* topc = (int*)(ws + o); o += 262144;
  float* d2g = ws + o;   o += 262144;
  u16* W21f = (u16*)(ws + o); o += 32768;  // 65536 bf16
  u16* V1f = (u16*)(ws + o);  o += 16384;  // 32768 bf16
  u16* V2f = (u16*)(ws + o);  o += 16384;
  float* d2r = ws + xt_off;
  int* sel32 = (int*)(ws + xt_off + 16384);
  float* candv = ws + pc_off;

  k_cbrqT<<<dim3(128), dim3(256), 0, stream>>>(cbrq, cbT);
  k_cbsq<<<dim3(16), dim3(256), 0, stream>>>(cbT, cb_sq);
  k_xt<<<dim3(1024), dim3(256), 0, stream>>>(x, xhat, xt);
  k_biasprep<<<dim3(1), dim3(256), 0, stream>>>(rb_b1, rb_b2, rb_w1, out_w,
                                                out_b, bias2v, biasDv);
  k_codeh<<<dim3(4096), dim3(256), 0, stream>>>(cb, in_w, in_b, tmp_h);
  gemm_f32<<<dim3(64, 4), dim3(256), 0, stream>>>(tmp_h, cc_w, pc, 4096, 256,
                                                  256, nullptr, nullptr);
  gemm_f32<<<dim3(128, 4), dim3(256), 0, stream>>>(xhat, cc_w + 256 * 256, pb,
                                                   8192, 256, 128, cc_b,
                                                   nullptr);
  gemm_f32<<<dim3(64, 4), dim3(256), 0, stream>>>(pc, rb_w1, A1, 4096, 256, 256,
                                                  nullptr, nullptr);
  gemm_f32<<<dim3(64, 4), dim3(256), 0, stream>>>(pc, rb_w1 + 65536, A2, 4096,
                                                  256, 256, nullptr, nullptr);
  gemm_f32<<<dim3(64, 2), dim3(256), 0, stream>>>(pc, out_w, Dc, 4096, 128, 256,
                                                  nullptr, cb);
  gemm_f32<<<dim3(128, 4), dim3(256), 0, stream>>>(pb, rb_w1, B1, 8192, 256,
                                                   256, rb_b1, nullptr);
  gemm_f32<<<dim3(128, 4), dim3(256), 0, stream>>>(pb, rb_w1 + 65536, B2, 8192,
                                                   256, 256, bias2v, nullptr);
  gemm_f32<<<dim3(128, 2), dim3(256), 0, stream>>>(pb, out_w, Dr, 8192, 128,
                                                   256, biasDv, nullptr);
  gemm_f32<<<dim3(4, 4), dim3(256), 0, stream>>>(rb_w2, rb_w1 + 65536, W21, 256,
                                                 256, 256, nullptr, nullptr);
  gemm_f32<<<dim3(4, 2), dim3(256), 0, stream>>>(rb_w2, out_w, V1, 256, 128,
                                                 256, nullptr, nullptr);
  gemm_f32<<<dim3(4, 2), dim3(256), 0, stream>>>(rb_w2 + 65536, out_w, V2, 256,
                                                 128, 256, nullptr, nullptr);
  k_wfrag<<<dim3(64), dim3(256), 0, stream>>>(W21, V1, V2, W21f, V1f, V2f);

  k_stage1<<<dim3(2048), dim3(512), 0, stream>>>(xt, cbT, cb_sq, topc);
  k_mlp<<<dim3(8192), dim3(256), 0, stream>>>(topc, A1, A2, B1, B2, Dc, Dr,
                                              W21f, V1f, V2f, xhat, x, d2g);
  k_sel32<<<dim3(512), dim3(64), 0, stream>>>(d2g, sel32);
  k_rescore<<<dim3(2048), dim3(256), 0, stream>>>(
      sel32, topc, tmp_h, cb, xhat, x, cc_w, cc_b, rb_w1, rb_b1, rb_w2, rb_b2,
      out_w, out_b, d2r, candv);
  k_final<<<dim3(512), dim3(64), 0, stream>>>(d2r, sel32, topc, codes, candv,
                                              out);
  (void)in_sizes; (void)n_in; (void)out_size; (void)ws_size;
}

// Round 12
// 910.302 us; speedup vs baseline: 2.2283x; 1.0139x over previous
//
#include <hip/hip_runtime.h>
#include <float.h>

typedef unsigned int u32;
typedef unsigned long long u64;
typedef unsigned short u16;
typedef __attribute__((ext_vector_type(8))) short s16x8;
typedef __attribute__((ext_vector_type(4))) float f32x4;

// Bb=512, F=16 -> 8192 beam rows, D=128, DH=256, K=4096, A=32, Fo=16, M=2.
// Selection-critical math reproduces numpy's f32 arithmetic bitwise (model):
//  - matmul: per-output sequential f32 FMA over k ascending (sgemm micro-kernel)
//  - np.sum(last axis): 8-accumulator pairwise (n<=128 base case), no FMA
//  - dist/d2 combine: separate f32 mul + f32 sub (ufuncs don't fuse)
//  - all top-k: f32 keys, ties -> lower index (stable, = jax top_k & np)
// The factored MLP prescreen (top-32 cut, ~17x margin) runs on MFMA bf16.

static __device__ __forceinline__ u32 ordu(float f) {
  u32 u = __float_as_uint(f);
  return u ^ (u32)(((int)u >> 31) | (int)0x80000000);
}
static __device__ __forceinline__ u16 f2bf(float f) {  // RNE f32->bf16
  u32 b = __float_as_uint(f);
  b += 0x7fffu + ((b >> 16) & 1u);
  return (u16)(b >> 16);
}

// ---------------- prep ----------------

__global__ __launch_bounds__(256) void k_cbrqT(const float* __restrict__ cbrq,
                                               float* __restrict__ cbT) {
  __shared__ float tile[128 * 33];
  const int k0 = blockIdx.x * 32;
  const int t = threadIdx.x;
#pragma unroll
  for (int rep = 0; rep < 16; ++rep) {
    const int flat = rep * 256 + t;
    const int kk = flat >> 7, d = flat & 127;
    tile[d * 33 + kk] = cbrq[(k0 + kk) * 128 + d];
  }
  __syncthreads();
#pragma unroll
  for (int rep = 0; rep < 16; ++rep) {
    const int flat = rep * 256 + t;
    const int d = flat >> 5, kk = flat & 31;
    cbT[d * 4096 + k0 + kk] = tile[d * 33 + kk];
  }
}

__global__ __launch_bounds__(256) void k_cbsq(const float* __restrict__ cbT,
                                              float* __restrict__ cb_sq) {
  const int k = blockIdx.x * 256 + threadIdx.x;
  float r[8];
#pragma unroll
  for (int j = 0; j < 8; ++j) {
    const float v = cbT[j * 4096 + k];
    r[j] = __fmul_rn(v, v);
  }
  for (int i = 8; i < 128; i += 8) {
#pragma unroll
    for (int j = 0; j < 8; ++j) {
      const float v = cbT[(i + j) * 4096 + k];
      r[j] = __fadd_rn(r[j], __fmul_rn(v, v));
    }
  }
  cb_sq[k] = __fadd_rn(
      __fadd_rn(__fadd_rn(r[0], r[1]), __fadd_rn(r[2], r[3])),
      __fadd_rn(__fadd_rn(r[4], r[5]), __fadd_rn(r[6], r[7])));
}

__global__ __launch_bounds__(256) void k_xt(const float* __restrict__ x,
                                            const float* __restrict__ xhat,
                                            float* __restrict__ xt) {
  const int i = blockIdx.x * 256 + threadIdx.x;
  const int row = i >> 5, d4 = i & 31;
  const float4 a = ((const float4*)x)[(row >> 4) * 32 + d4];
  const float4 b = ((const float4*)xhat)[i];
  float4 r;
  r.x = __fsub_rn(a.x, b.x); r.y = __fsub_rn(a.y, b.y);
  r.z = __fsub_rn(a.z, b.z); r.w = __fsub_rn(a.w, b.w);
  ((float4*)xt)[i] = r;
}

__global__ __launch_bounds__(256) void k_codeh(const float* __restrict__ cb,
                                               const float* __restrict__ in_w,
                                               const float* __restrict__ in_b,
                                               float* __restrict__ tmp_h) {
  __shared__ float row[128];
  const int code = blockIdx.x;
  const int t = threadIdx.x;
  if (t < 128) row[t] = cb[code * 128 + t];
  __syncthreads();
  float a = 0.f;
  for (int d = 0; d < 128; ++d) a = __builtin_fmaf(row[d], in_w[d * 256 + t], a);
  tmp_h[code * 256 + t] = __fadd_rn(a, in_b[t]);
}

__global__ __launch_bounds__(256) void k_biasprep(
    const float* __restrict__ rb_b1, const float* __restrict__ rb_b2,
    const float* __restrict__ rb_w1, const float* __restrict__ out_w,
    const float* __restrict__ out_b, float* __restrict__ bias2v,
    float* __restrict__ biasDv) {
  const int t = threadIdx.x;
  const float* w11 = rb_w1 + 65536;
  float s = rb_b1[256 + t];
  for (int i = 0; i < 256; ++i) s += rb_b2[i] * w11[i * 256 + t];
  bias2v[t] = s;
  if (t < 128) {
    float s2 = out_b[t];
    for (int i = 0; i < 256; ++i)
      s2 += (rb_b2[i] + rb_b2[256 + i]) * out_w[i * 128 + t];
    biasDv[t] = s2;
  }
}

// pack W21/V1/V2 (f32) into bf16 MFMA B-fragment layout
__global__ __launch_bounds__(256) void k_wfrag(
    const float* __restrict__ W21, const float* __restrict__ V1,
    const float* __restrict__ V2, u16* __restrict__ W21f,
    u16* __restrict__ V1f, u16* __restrict__ V2f) {
  const int gid = blockIdx.x * 256 + threadIdx.x;  // 16384 total
  const int l = gid & 63;
  const int grp = gid >> 6;  // [0,256)
  const int kq = (l >> 4) * 8;
  const int nn = l & 15;
  if (grp < 128) {
    const int kt = grp >> 4, nt = grp & 15;
    u16* dst = W21f + (size_t)(grp * 64 + l) * 8;
#pragma unroll
    for (int j = 0; j < 8; ++j)
      dst[j] = f2bf(W21[(kt * 32 + kq + j) * 256 + nt * 16 + nn]);
  } else if (grp < 192) {
    const int g2 = grp - 128, kt = g2 >> 3, nt = g2 & 7;
    u16* dst = V1f + (size_t)(g2 * 64 + l) * 8;
#pragma unroll
    for (int j = 0; j < 8; ++j)
      dst[j] = f2bf(V1[(kt * 32 + kq + j) * 128 + nt * 16 + nn]);
  } else {
    const int g2 = grp - 192, kt = g2 >> 3, nt = g2 & 7;
    u16* dst = V2f + (size_t)(g2 * 64 + l) * 8;
#pragma unroll
    for (int j = 0; j < 8; ++j)
      dst[j] = f2bf(V2[(kt * 32 + kq + j) * 128 + nt * 16 + nn]);
  }
}

// ---------------- generic f32 GEMM (prescreen precompute only) ----------------
__global__ __launch_bounds__(256, 4) void gemm_f32(
    const float* __restrict__ Am, const float* __restrict__ Bm,
    float* __restrict__ Cm, const int Mi, const int Ni, const int Ki,
    const float* __restrict__ bias, const float* __restrict__ addm) {
  __shared__ float As[16][68];
  __shared__ float Bs[16][68];
  const int m0 = blockIdx.x * 64, n0 = blockIdx.y * 64;
  const int t = threadIdx.x;
  const int tm = (t & 15) * 4, tn = (t >> 4) * 4;
  float acc[4][4] = {};
  for (int k0 = 0; k0 < Ki; k0 += 16) {
    {
      const int row = t >> 2, q = t & 3;
      const float4 a4 = *(const float4*)(Am + (size_t)(m0 + row) * Ki + k0 + q * 4);
      As[q * 4 + 0][row] = a4.x; As[q * 4 + 1][row] = a4.y;
      As[q * 4 + 2][row] = a4.z; As[q * 4 + 3][row] = a4.w;
      const int kk = t >> 4, n4 = t & 15;
      *(float4*)&Bs[kk][n4 * 4] =
          *(const float4*)(Bm + (size_t)(k0 + kk) * Ni + n0 + n4 * 4);
    }
    __syncthreads();
#pragma unroll
    for (int kk = 0; kk < 16; ++kk) {
      const float4 av = *(const float4*)&As[kk][tm];
      const float4 bv = *(const float4*)&Bs[kk][tn];
      const float aa[4] = {av.x, av.y, av.z, av.w};
      const float bb[4] = {bv.x, bv.y, bv.z, bv.w};
#pragma unroll
      for (int i = 0; i < 4; ++i)
#pragma unroll
        for (int j = 0; j < 4; ++j) acc[i][j] += aa[i] * bb[j];
    }
    __syncthreads();
  }
#pragma unroll
  for (int i = 0; i < 4; ++i) {
    const int m = m0 + tm + i;
#pragma unroll
    for (int j = 0; j < 4; ++j) {
      const int n = n0 + tn + j;
      float v = acc[i][j];
      if (bias) v += bias[n];
      if (addm) v += addm[(size_t)m * Ni + n];
      Cm[(size_t)m * Ni + n] = v;
    }
  }
}

// ---------------- stage 1: bitwise-np f32 dists + stable top-32 ----------------
__global__ __launch_bounds__(512, 2) void k_stage1(
    const float* __restrict__ xt, const float* __restrict__ cbT,
    const float* __restrict__ cb_sq, int* __restrict__ topc) {
  __shared__ u32 distL[4 * 4096];  // 64 KB
  __shared__ float xtL[512];
  const int r0 = blockIdx.x * 4;
  const int t = threadIdx.x;
  xtL[t] = xt[r0 * 128 + t];
  __syncthreads();
  {
    const int k0 = t * 8;
    float acc[4][8] = {};
    for (int d = 0; d < 128; ++d) {
      const float4 c0 = *(const float4*)&cbT[d * 4096 + k0];
      const float4 c1 = *(const float4*)&cbT[d * 4096 + k0 + 4];
      const float cv[8] = {c0.x, c0.y, c0.z, c0.w, c1.x, c1.y, c1.z, c1.w};
      const float x0 = xtL[d], x1 = xtL[128 + d], x2 = xtL[256 + d],
                  x3 = xtL[384 + d];
#pragma unroll
      for (int j = 0; j < 8; ++j) {
        acc[0][j] = __builtin_fmaf(x0, cv[j], acc[0][j]);
        acc[1][j] = __builtin_fmaf(x1, cv[j], acc[1][j]);
        acc[2][j] = __builtin_fmaf(x2, cv[j], acc[2][j]);
        acc[3][j] = __builtin_fmaf(x3, cv[j], acc[3][j]);
      }
    }
    const float4 s0 = *(const float4*)&cb_sq[k0];
    const float4 s1 = *(const float4*)&cb_sq[k0 + 4];
    const float cs[8] = {s0.x, s0.y, s0.z, s0.w, s1.x, s1.y, s1.z, s1.w};
#pragma unroll
    for (int rr = 0; rr < 4; ++rr)
#pragma unroll
      for (int j = 0; j < 8; ++j)
        distL[rr * 4096 + k0 + j] =
            ordu(__fsub_rn(cs[j], __fmul_rn(2.0f, acc[rr][j])));
  }
  __syncthreads();
  const int w = t >> 6, lane = t & 63;
  if (w < 4) {
    u32* dr = distL + w * 4096;
    u64 m1 = ~0ull, m2 = ~0ull;
    for (int e = 0; e < 64; ++e) {
      const int idx = e * 64 + lane;
      const u64 key = ((u64)dr[idx] << 32) | (u32)idx;
      if (key < m1) { m2 = m1; m1 = key; } else if (key < m2) { m2 = key; }
    }
    bool have2 = true;
    for (int it = 0; it < 32; ++it) {
      u64 g = m1;
#pragma unroll
      for (int sh = 1; sh < 64; sh <<= 1) {
        const u64 o = __shfl_xor(g, sh);
        g = (o < g) ? o : g;
      }
      const int bi = (int)(g & 0xFFFFFFFFu);
      if (lane == 0) topc[(r0 + w) * 32 + it] = bi;
      if ((bi & 63) == lane) {
        dr[bi] = 0xFFFFFFFFu;
        if (have2) {
          m1 = m2; m2 = ~0ull; have2 = false;
        } else {
          m1 = m2 = ~0ull;
          for (int e = 0; e < 64; ++e) {
            const int idx = e * 64 + lane;
            const u64 key = ((u64)dr[idx] << 32) | (u32)idx;
            if (key < m1) { m2 = m1; m1 = key; } else if (key < m2) { m2 = key; }
          }
          have2 = true;
        }
      }
    }
  }
}

// ---------------- stage 2: MFMA bf16 prescreen ----------------
__global__ __launch_bounds__(256, 4) void k_mlp(
    const int* __restrict__ topc, const float* __restrict__ A1,
    const float* __restrict__ A2, const float* __restrict__ B1,
    const float* __restrict__ B2, const float* __restrict__ Dc,
    const float* __restrict__ Dr, const u16* __restrict__ W21f,
    const u16* __restrict__ V1f, const u16* __restrict__ V2f,
    const float* __restrict__ xhat, const float* __restrict__ x,
    float* __restrict__ d2g) {
  __shared__ __align__(16) u16 abuf[32 * 264];  // 16.5 KB, r1 then r2
  __shared__ float B1r[256];
  __shared__ int codesL[32];
  __shared__ float d2red[32][4];

  const int tt = threadIdx.x;
  const int br = blockIdx.x;  // beam row
  const int bb = br >> 4;
  const int w = tt >> 6, l = tt & 63;

  B1r[tt] = B1[br * 256 + tt];
  if (tt < 32) codesL[tt] = topc[br * 32 + tt];
  __syncthreads();

  // phase 1: r1 = relu(A1[code]+B1) -> abuf bf16 [cand][264]
  {
    const int c = tt & 31, g = tt >> 5;
    const int code = codesL[c];
    const float4* A14 = (const float4*)(A1 + code * 256 + g * 32);
    u32* dst = (u32*)(abuf + c * 264 + g * 32);
#pragma unroll
    for (int e4 = 0; e4 < 8; ++e4) {
      const float4 a = A14[e4];
      const int i = g * 32 + e4 * 4;
      const u32 p0 = (u32)f2bf(fmaxf(a.x + B1r[i], 0.f)) |
                     ((u32)f2bf(fmaxf(a.y + B1r[i + 1], 0.f)) << 16);
      const u32 p1 = (u32)f2bf(fmaxf(a.z + B1r[i + 2], 0.f)) |
                     ((u32)f2bf(fmaxf(a.w + B1r[i + 3], 0.f)) << 16);
      dst[e4 * 2] = p0;
      dst[e4 * 2 + 1] = p1;
    }
  }
  __syncthreads();

  const int arow = l & 15;
  const int kq = (l >> 4) * 8;
  const s16x8* wf = (const s16x8*)W21f;
  const s16x8* v1f = (const s16x8*)V1f;
  const s16x8* v2f = (const s16x8*)V2f;
  const f32x4 zero4 = {0.f, 0.f, 0.f, 0.f};

  // phase 2: z2 = r1 @ W21
  f32x4 accf[2][4];
#pragma unroll
  for (int mt = 0; mt < 2; ++mt)
#pragma unroll
    for (int ntl = 0; ntl < 4; ++ntl) accf[mt][ntl] = zero4;
  for (int kt = 0; kt < 8; ++kt) {
    const s16x8 a0 = *(const s16x8*)(abuf + arow * 264 + kt * 32 + kq);
    const s16x8 a1 = *(const s16x8*)(abuf + (16 + arow) * 264 + kt * 32 + kq);
#pragma unroll
    for (int ntl = 0; ntl < 4; ++ntl) {
      const s16x8 b = wf[(kt * 16 + w * 4 + ntl) * 64 + l];
      accf[0][ntl] =
          __builtin_amdgcn_mfma_f32_16x16x32_bf16(a0, b, accf[0][ntl], 0, 0, 0);
      accf[1][ntl] =
          __builtin_amdgcn_mfma_f32_16x16x32_bf16(a1, b, accf[1][ntl], 0, 0, 0);
    }
  }

  // phase 3a: acc2 = r1 @ V1
  f32x4 acc2f[2][2];
#pragma unroll
  for (int mt = 0; mt < 2; ++mt)
#pragma unroll
    for (int ntl = 0; ntl < 2; ++ntl) acc2f[mt][ntl] = zero4;
  for (int kt = 0; kt < 8; ++kt) {
    const s16x8 a0 = *(const s16x8*)(abuf + arow * 264 + kt * 32 + kq);
    const s16x8 a1 = *(const s16x8*)(abuf + (16 + arow) * 264 + kt * 32 + kq);
#pragma unroll
    for (int ntl = 0; ntl < 2; ++ntl) {
      const s16x8 b = v1f[(kt * 8 + w * 2 + ntl) * 64 + l];
      acc2f[0][ntl] = __builtin_amdgcn_mfma_f32_16x16x32_bf16(
          a0, b, acc2f[0][ntl], 0, 0, 0);
      acc2f[1][ntl] = __builtin_amdgcn_mfma_f32_16x16x32_bf16(
          a1, b, acc2f[1][ntl], 0, 0, 0);
    }
  }

  // z2 epilogue: r2 = relu(z2 + A2[code] + B2[row])
  u16 r2v[2][4][4];
#pragma unroll
  for (int mt = 0; mt < 2; ++mt)
#pragma unroll
    for (int ntl = 0; ntl < 4; ++ntl) {
      const int n = w * 64 + ntl * 16 + arow;
      const float b2 = B2[br * 256 + n];
      const f32x4 cf = accf[mt][ntl];
#pragma unroll
      for (int rg = 0; rg < 4; ++rg) {
        const int m = mt * 16 + (l >> 4) * 4 + rg;
        const float a2 = A2[codesL[m] * 256 + n];
        r2v[mt][ntl][rg] = f2bf(fmaxf(cf[rg] + a2 + b2, 0.f));
      }
    }
  __syncthreads();
#pragma unroll
  for (int mt = 0; mt < 2; ++mt)
#pragma unroll
    for (int ntl = 0; ntl < 4; ++ntl) {
      const int n = w * 64 + ntl * 16 + arow;
#pragma unroll
      for (int rg = 0; rg < 4; ++rg) {
        const int m = mt * 16 + (l >> 4) * 4 + rg;
        abuf[m * 264 + n] = r2v[mt][ntl][rg];
      }
    }
  __syncthreads();

  // phase 3b: acc2 += r2 @ V2
  for (int kt = 0; kt < 8; ++kt) {
    const s16x8 a0 = *(const s16x8*)(abuf + arow * 264 + kt * 32 + kq);
    const s16x8 a1 = *(const s16x8*)(abuf + (16 + arow) * 264 + kt * 32 + kq);
#pragma unroll
    for (int ntl = 0; ntl < 2; ++ntl) {
      const s16x8 b = v2f[(kt * 8 + w * 2 + ntl) * 64 + l];
      acc2f[0][ntl] = __builtin_amdgcn_mfma_f32_16x16x32_bf16(
          a0, b, acc2f[0][ntl], 0, 0, 0);
      acc2f[1][ntl] = __builtin_amdgcn_mfma_f32_16x16x32_bf16(
          a1, b, acc2f[1][ntl], 0, 0, 0);
    }
  }

  // d2 epilogue
  float sm[2][4];
#pragma unroll
  for (int mt = 0; mt < 2; ++mt)
#pragma unroll
    for (int rg = 0; rg < 4; ++rg) sm[mt][rg] = 0.f;
#pragma unroll
  for (int ntl = 0; ntl < 2; ++ntl) {
    const int d = w * 32 + ntl * 16 + arow;
    const float dr = Dr[br * 128 + d];
    const float xh = xhat[br * 128 + d];
    const float xq = x[bb * 128 + d];
#pragma unroll
    for (int mt = 0; mt < 2; ++mt) {
      const f32x4 cf = acc2f[mt][ntl];
#pragma unroll
      for (int rg = 0; rg < 4; ++rg) {
        const int m = mt * 16 + (l >> 4) * 4 + rg;
        const float cand = cf[rg] + Dc[codesL[m] * 128 + d] + dr + xh;
        sm[mt][rg] += cand * cand - 2.f * xq * cand;
      }
    }
  }
#pragma unroll
  for (int mt = 0; mt < 2; ++mt)
#pragma unroll
    for (int rg = 0; rg < 4; ++rg) {
      float s = sm[mt][rg];
      s += __shfl_xor(s, 1);
      s += __shfl_xor(s, 2);
      s += __shfl_xor(s, 4);
      s += __shfl_xor(s, 8);
      if (arow == 0) d2red[mt * 16 + (l >> 4) * 4 + rg][w] = s;
    }
  __syncthreads();
  if (tt < 32)
    d2g[bb * 512 + (br & 15) * 32 + tt] =
        d2red[tt][0] + d2red[tt][1] + d2red[tt][2] + d2red[tt][3];
}

// ---------------- stage 3a: prescreen top-32 per base query ----------------
__global__ __launch_bounds__(64, 1) void k_sel32(const float* __restrict__ d2g,
                                                 int* __restrict__ sel32) {
  __shared__ u32 d2u[512];
  const int bb = blockIdx.x;
  const int t = threadIdx.x;
  for (int i = t; i < 512; i += 64) d2u[i] = ordu(d2g[bb * 512 + i]);
  __syncthreads();
  for (int it = 0; it < 32; ++it) {
    u64 m = ~0ull;
#pragma unroll
    for (int e = 0; e < 8; ++e) {
      const int idx = e * 64 + t;
      const u64 key = ((u64)d2u[idx] << 32) | (u32)idx;
      m = (key < m) ? key : m;
    }
#pragma unroll
    for (int sh = 1; sh < 64; sh <<= 1) {
      const u64 o = __shfl_xor(m, sh);
      m = (o < m) ? o : m;
    }
    const int s = (int)(m & 0xFFFFFFFFu);
    if ((s & 63) == t) d2u[s] = 0xFFFFFFFFu;
    if (t == 0) sel32[bb * 32 + it] = s;
  }
}

// ---------------- stage 3b: np-emulated rescore of top-32 ----------------
// seq-FMA over k ascending per accumulator (bitwise-np); float4 activation
// reads (same arithmetic order, 4x fewer LDS instructions).
__global__ __launch_bounds__(256, 4) void k_rescore(
    const int* __restrict__ sel32, const int* __restrict__ topc,
    const float* __restrict__ tmp_h, const float* __restrict__ cb,
    const float* __restrict__ xhat, const float* __restrict__ x,
    const float* __restrict__ cc_w, const float* __restrict__ cc_b,
    const float* __restrict__ rb_w1, const float* __restrict__ rb_b1,
    const float* __restrict__ rb_w2, const float* __restrict__ rb_b2,
    const float* __restrict__ out_w, const float* __restrict__ out_b,
    float* __restrict__ d2r, float* __restrict__ candv) {
  __shared__ float A_[8][256], B_[8][256], C_[8][256];
  __shared__ float cbL[8][128], xhL[8][128], candL[8][128], xqL[128];
  __shared__ int codeL[8], rowL[8];
  const int bb = blockIdx.x >> 2;
  const int j0 = (blockIdx.x & 3) * 8;
  const int t = threadIdx.x;
  if (t < 8) {
    const int s = sel32[bb * 32 + j0 + t];
    rowL[t] = bb * 16 + (s >> 5);
    codeL[t] = topc[(bb * 16 + (s >> 5)) * 32 + (s & 31)];
  }
  if (t < 128) xqL[t] = x[bb * 128 + t];
  __syncthreads();
  for (int idx = t; idx < 1024; idx += 256) {
    const int c = idx >> 7, d = idx & 127;
    cbL[c][d] = cb[codeL[c] * 128 + d];
    xhL[c][d] = xhat[rowL[c] * 128 + d];
  }
  for (int idx = t; idx < 2048; idx += 256) {
    const int c = idx >> 8, i = idx & 255;
    A_[c][i] = tmp_h[codeL[c] * 256 + i];
  }
  __syncthreads();
  // h0 = seqFMA(concat(h_in, xhat) @ cc_w) + cc_b  -> B_
  {
    float acc[8] = {};
    for (int i = 0; i < 256; i += 4) {
      const float w0 = cc_w[(i + 0) * 256 + t], w1 = cc_w[(i + 1) * 256 + t];
      const float w2 = cc_w[(i + 2) * 256 + t], w3 = cc_w[(i + 3) * 256 + t];
#pragma unroll
      for (int c = 0; c < 8; ++c) {
        const float4 h = *(const float4*)&A_[c][i];
        acc[c] = __builtin_fmaf(h.x, w0, acc[c]);
        acc[c] = __builtin_fmaf(h.y, w1, acc[c]);
        acc[c] = __builtin_fmaf(h.z, w2, acc[c]);
        acc[c] = __builtin_fmaf(h.w, w3, acc[c]);
      }
    }
    for (int d = 0; d < 128; d += 4) {
      const float w0 = cc_w[(256 + d + 0) * 256 + t];
      const float w1 = cc_w[(256 + d + 1) * 256 + t];
      const float w2 = cc_w[(256 + d + 2) * 256 + t];
      const float w3 = cc_w[(256 + d + 3) * 256 + t];
#pragma unroll
      for (int c = 0; c < 8; ++c) {
        const float4 h = *(const float4*)&xhL[c][d];
        acc[c] = __builtin_fmaf(h.x, w0, acc[c]);
        acc[c] = __builtin_fmaf(h.y, w1, acc[c]);
        acc[c] = __builtin_fmaf(h.z, w2, acc[c]);
        acc[c] = __builtin_fmaf(h.w, w3, acc[c]);
      }
    }
    const float b = cc_b[t];
#pragma unroll
    for (int c = 0; c < 8; ++c) B_[c][t] = __fadd_rn(acc[c], b);
  }
  __syncthreads();
  // r1 = relu(seqFMA(h0 @ w1_0) + b1_0) -> C_
  {
    float acc[8] = {};
    for (int i = 0; i < 256; i += 4) {
      const float w0 = rb_w1[(i + 0) * 256 + t], w1 = rb_w1[(i + 1) * 256 + t];
      const float w2 = rb_w1[(i + 2) * 256 + t], w3 = rb_w1[(i + 3) * 256 + t];
#pragma unroll
      for (int c = 0; c < 8; ++c) {
        const float4 h = *(const float4*)&B_[c][i];
        acc[c] = __builtin_fmaf(h.x, w0, acc[c]);
        acc[c] = __builtin_fmaf(h.y, w1, acc[c]);
        acc[c] = __builtin_fmaf(h.z, w2, acc[c]);
        acc[c] = __builtin_fmaf(h.w, w3, acc[c]);
      }
    }
    const float b = rb_b1[t];
#pragma unroll
    for (int c = 0; c < 8; ++c) C_[c][t] = fmaxf(__fadd_rn(acc[c], b), 0.f);
  }
  __syncthreads();
  // h1 = (h0 + seqFMA(r1 @ w2_0)) + b2_0 -> A_
  {
    float acc[8] = {};
    for (int i = 0; i < 256; i += 4) {
      const float w0 = rb_w2[(i + 0) * 256 + t], w1 = rb_w2[(i + 1) * 256 + t];
      const float w2 = rb_w2[(i + 2) * 256 + t], w3 = rb_w2[(i + 3) * 256 + t];
#pragma unroll
      for (int c = 0; c < 8; ++c) {
        const float4 h = *(const float4*)&C_[c][i];
        acc[c] = __builtin_fmaf(h.x, w0, acc[c]);
        acc[c] = __builtin_fmaf(h.y, w1, acc[c]);
        acc[c] = __builtin_fmaf(h.z, w2, acc[c]);
        acc[c] = __builtin_fmaf(h.w, w3, acc[c]);
      }
    }
    const float b = rb_b2[t];
#pragma unroll
    for (int c = 0; c < 8; ++c)
      A_[c][t] = __fadd_rn(__fadd_rn(B_[c][t], acc[c]), b);
  }
  __syncthreads();
  // r2 = relu(seqFMA(h1 @ w1_1) + b1_1) -> B_
  {
    float acc[8] = {};
    const float* w11 = rb_w1 + 65536;
    for (int i = 0; i < 256; i += 4) {
      const float w0 = w11[(i + 0) * 256 + t], w1 = w11[(i + 1) * 256 + t];
      const float w2 = w11[(i + 2) * 256 + t], w3 = w11[(i + 3) * 256 + t];
#pragma unroll
      for (int c = 0; c < 8; ++c) {
        const float4 h = *(const float4*)&A_[c][i];
        acc[c] = __builtin_fmaf(h.x, w0, acc[c]);
        acc[c] = __builtin_fmaf(h.y, w1, acc[c]);
        acc[c] = __builtin_fmaf(h.z, w2, acc[c]);
        acc[c] = __builtin_fmaf(h.w, w3, acc[c]);
      }
    }
    const float b = rb_b1[256 + t];
#pragma unroll
    for (int c = 0; c < 8; ++c) B_[c][t] = fmaxf(__fadd_rn(acc[c], b), 0.f);
  }
  __syncthreads();
  // h2 = (h1 + seqFMA(r2 @ w2_1)) + b2_1 -> C_
  {
    float acc[8] = {};
    const float* w21 = rb_w2 + 65536;
    for (int i = 0; i < 256; i += 4) {
      const float w0 = w21[(i + 0) * 256 + t], w1 = w21[(i + 1) * 256 + t];
      const float w2 = w21[(i + 2) * 256 + t], w3 = w21[(i + 3) * 256 + t];
#pragma unroll
      for (int c = 0; c < 8; ++c) {
        const float4 h = *(const float4*)&B_[c][i];
        acc[c] = __builtin_fmaf(h.x, w0, acc[c]);
        acc[c] = __builtin_fmaf(h.y, w1, acc[c]);
        acc[c] = __builtin_fmaf(h.z, w2, acc[c]);
        acc[c] = __builtin_fmaf(h.w, w3, acc[c]);
      }
    }
    const float b = rb_b2[256 + t];
#pragma unroll
    for (int c = 0; c < 8; ++c)
      C_[c][t] = __fadd_rn(__fadd_rn(A_[c][t], acc[c]), b);
  }
  __syncthreads();
  // cand = ((seqFMA(h2@out_w) + out_b) + cw_in) + xhat
  if (t < 128) {
    float acc[8] = {};
    for (int i = 0; i < 256; i += 4) {
      const float w0 = out_w[(i + 0) * 128 + t], w1 = out_w[(i + 1) * 128 + t];
      const float w2 = out_w[(i + 2) * 128 + t], w3 = out_w[(i + 3) * 128 + t];
#pragma unroll
      for (int c = 0; c < 8; ++c) {
        const float4 h = *(const float4*)&C_[c][i];
        acc[c] = __builtin_fmaf(h.x, w0, acc[c]);
        acc[c] = __builtin_fmaf(h.y, w1, acc[c]);
        acc[c] = __builtin_fmaf(h.z, w2, acc[c]);
        acc[c] = __builtin_fmaf(h.w, w3, acc[c]);
      }
    }
    const float ob = out_b[t];
#pragma unroll
    for (int c = 0; c < 8; ++c) {
      const float cw_ = __fadd_rn(__fadd_rn(acc[c], ob), cbL[c][t]);
      const float cand = __fadd_rn(cw_, xhL[c][t]);
      candL[c][t] = cand;
      candv[(bb * 32 + j0 + c) * 128 + t] = cand;
    }
  }
  __syncthreads();
  if (t < 8) {
    float r[8];
#pragma unroll
    for (int j = 0; j < 8; ++j) {
      const float v = candL[t][j];
      r[j] = __fmul_rn(v, v);
    }
    for (int i = 8; i < 128; i += 8) {
#pragma unroll
      for (int j = 0; j < 8; ++j) {
        const float v = candL[t][i + j];
        r[j] = __fadd_rn(r[j], __fmul_rn(v, v));
      }
    }
    const float s1f = __fadd_rn(
        __fadd_rn(__fadd_rn(r[0], r[1]), __fadd_rn(r[2], r[3])),
        __fadd_rn(__fadd_rn(r[4], r[5]), __fadd_rn(r[6], r[7])));
    double s2 = 0.0;
    for (int d = 0; d < 128; ++d)
      s2 += (double)xqL[d] * (double)candL[t][d];
    const float s2f = (float)s2;
    d2r[bb * 32 + j0 + t] = __fsub_rn(s1f, __fmul_rn(2.0f, s2f));
  }
}

// ---------------- stage 3c/4: stable top-16 by f32 d2 ----------------
__global__ __launch_bounds__(64, 1) void k_final(
    const float* __restrict__ d2r, const int* __restrict__ sel32,
    const int* __restrict__ topc, const int* __restrict__ codes_in,
    const float* __restrict__ candv, float* __restrict__ out) {
  __shared__ u32 winLo[16];
  const int bb = blockIdx.x;
  const int t = threadIdx.x;
  u64 key = ~0ull;
  if (t < 32) {
    const u32 s = (u32)sel32[bb * 32 + t];
    key = ((u64)ordu(d2r[bb * 32 + t]) << 32) | (s << 5) | (u32)t;
  }
  for (int it = 0; it < 16; ++it) {
    u64 m = key;
#pragma unroll
    for (int sh = 1; sh < 64; sh <<= 1) {
      const u64 o = __shfl_xor(m, sh);
      m = (o < m) ? o : m;
    }
    if (key == m) key = ~0ull;
    if (t == 0) winLo[it] = (u32)(m & 0xFFFFFFFFu);
  }
  __syncthreads();
  if (t < 16) {
    const u32 lo = winLo[t];
    const int s = (int)((lo >> 5) & 511u);
    const int f = s >> 5;
    const int code = topc[(bb * 16 + f) * 32 + (s & 31)];
    float* oc = out + 512 * 16 * 128;
    oc[bb * 16 + t] = (float)codes_in[bb * 16 + f];
    oc[8192 + bb * 16 + t] = (float)codes_in[8192 + bb * 16 + f];
    oc[16384 + bb * 16 + t] = (float)code;
  }
  __syncthreads();
  for (int idx = t; idx < 2048; idx += 64) {
    const int w_ = idx >> 7, d = idx & 127;
    const int j = (int)(winLo[w_] & 31u);
    out[(bb * 16 + w_) * 128 + d] = candv[(bb * 32 + j) * 128 + d];
  }
}

// ---------------- launch ----------------
extern "C" void kernel_launch(void* const* d_in, const int* in_sizes, int n_in,
                              void* d_out, int out_size, void* d_ws,
                              size_t ws_size, hipStream_t stream) {
  const float* x = (const float*)d_in[0];
  const float* xhat = (const float*)d_in[1];
  const int* codes = (const int*)d_in[2];
  const float* cb = (const float*)d_in[3];
  const float* cbrq = (const float*)d_in[4];
  const float* in_w = (const float*)d_in[5];
  const float* in_b = (const float*)d_in[6];
  const float* cc_w = (const float*)d_in[7];
  const float* cc_b = (const float*)d_in[8];
  const float* rb_w1 = (const float*)d_in[9];
  const float* rb_b1 = (const float*)d_in[10];
  const float* rb_w2 = (const float*)d_in[11];
  const float* rb_b2 = (const float*)d_in[12];
  const float* out_w = (const float*)d_in[13];
  const float* out_b = (const float*)d_in[14];
  float* out = (float*)d_out;

  float* ws = (float*)d_ws;
  size_t o = 0;
  float* cb_sq = ws + o; o += 4096;
  float* xt = ws + o;    const size_t xt_off = o; o += (size_t)8192 * 128;
  float* cbT = ws + o;   o += (size_t)128 * 4096;
  float* tmp_h = ws + o; o += (size_t)4096 * 256;   // LIVE through k_rescore
  float* pc = ws + o;    const size_t pc_off = o; o += (size_t)4096 * 256;
  float* pb = ws + o;    o += (size_t)8192 * 256;
  float* A1 = ws + o;    o += (size_t)4096 * 256;
  float* A2 = ws + o;    o += (size_t)4096 * 256;
  float* Dc = ws + o;    o += (size_t)4096 * 128;
  float* B1 = ws + o;    o += (size_t)8192 * 256;
  float* B2 = ws + o;    o += (size_t)8192 * 256;
  float* Dr = ws + o;    o += (size_t)8192 * 128;
  float* W21 = ws + o;   o += 65536;
  float* V1 = ws + o;    o += 32768;
  float* V2 = ws + o;    o += 32768;
  float* bias2v = ws + o; o += 256;
  float* biasDv = ws + o; o += 128;
  int* topc = (int*)(ws + o); o += 262144;
  float* d2g = ws + o;   o += 262144;
  u16* W21f = (u16*)(ws + o); o += 32768;  // 65536 bf16
  u16* V1f = (u16*)(ws + o);  o += 16384;  // 32768 bf16
  u16* V2f = (u16*)(ws + o);  o += 16384;
  float* d2r = ws + xt_off;
  int* sel32 = (int*)(ws + xt_off + 16384);
  float* candv = ws + pc_off;

  k_cbrqT<<<dim3(128), dim3(256), 0, stream>>>(cbrq, cbT);
  k_cbsq<<<dim3(16), dim3(256), 0, stream>>>(cbT, cb_sq);
  k_xt<<<dim3(1024), dim3(256), 0, stream>>>(x, xhat, xt);
  k_biasprep<<<dim3(1), dim3(256), 0, stream>>>(rb_b1, rb_b2, rb_w1, out_w,
                                                out_b, bias2v, biasDv);
  k_codeh<<<dim3(4096), dim3(256), 0, stream>>>(cb, in_w, in_b, tmp_h);
  gemm_f32<<<dim3(64, 4), dim3(256), 0, stream>>>(tmp_h, cc_w, pc, 4096, 256,
                                                  256, nullptr, nullptr);
  gemm_f32<<<dim3(128, 4), dim3(256), 0, stream>>>(xhat, cc_w + 256 * 256, pb,
                                                   8192, 256, 128, cc_b,
                                                   nullptr);
  gemm_f32<<<dim3(64, 4), dim3(256), 0, stream>>>(pc, rb_w1, A1, 4096, 256, 256,
                                                  nullptr, nullptr);
  gemm_f32<<<dim3(64, 4), dim3(256), 0, stream>>>(pc, rb_w1 + 65536, A2, 4096,
                                                  256, 256, nullptr, nullptr);
  gemm_f32<<<dim3(64, 2), dim3(256), 0, stream>>>(pc, out_w, Dc, 4096, 128, 256,
                                                  nullptr, cb);
  gemm_f32<<<dim3(128, 4), dim3(256), 0, stream>>>(pb, rb_w1, B1, 8192, 256,
                                                   256, rb_b1, nullptr);
  gemm_f32<<<dim3(128, 4), dim3(256), 0, stream>>>(pb, rb_w1 + 65536, B2, 8192,
                                                   256, 256, bias2v, nullptr);
  gemm_f32<<<dim3(128, 2), dim3(256), 0, stream>>>(pb, out_w, Dr, 8192, 128,
                                                   256, biasDv, nullptr);
  gemm_f32<<<dim3(4, 4), dim3(256), 0, stream>>>(rb_w2, rb_w1 + 65536, W21, 256,
                                                 256, 256, nullptr, nullptr);
  gemm_f32<<<dim3(4, 2), dim3(256), 0, stream>>>(rb_w2, out_w, V1, 256, 128,
                                                 256, nullptr, nullptr);
  gemm_f32<<<dim3(4, 2), dim3(256), 0, stream>>>(rb_w2 + 65536, out_w, V2, 256,
                                                 128, 256, nullptr, nullptr);
  k_wfrag<<<dim3(64), dim3(256), 0, stream>>>(W21, V1, V2, W21f, V1f, V2f);

  k_stage1<<<dim3(2048), dim3(512), 0, stream>>>(xt, cbT, cb_sq, topc);
  k_mlp<<<dim3(8192), dim3(256), 0, stream>>>(topc, A1, A2, B1, B2, Dc, Dr,
                                              W21f, V1f, V2f, xhat, x, d2g);
  k_sel32<<<dim3(512), dim3(64), 0, stream>>>(d2g, sel32);
  k_rescore<<<dim3(2048), dim3(256), 0, stream>>>(
      sel32, topc, tmp_h, cb, xhat, x, cc_w, cc_b, rb_w1, rb_b1, rb_w2, rb_b2,
      out_w, out_b, d2r, candv);
  k_final<<<dim3(512), dim3(64), 0, stream>>>(d2r, sel32, topc, codes, candv,
                                              out);
  (void)in_sizes; (void)n_in; (void)out_size; (void)ws_size;
}

// Round 13
// 892.034 us; speedup vs baseline: 2.2740x; 1.0205x over previous
//
#include <hip/hip_runtime.h>
#include <float.h>

typedef unsigned int u32;
typedef unsigned long long u64;
typedef unsigned short u16;
typedef __attribute__((ext_vector_type(8))) short s16x8;
typedef __attribute__((ext_vector_type(4))) float f32x4;

// Bb=512, F=16 -> 8192 beam rows, D=128, DH=256, K=4096, A=32, Fo=16, M=2.
// Selection-critical math reproduces numpy's f32 arithmetic bitwise (model):
//  - matmul: per-output sequential f32 FMA over k ascending (sgemm micro-kernel)
//  - np.sum(last axis): 8-accumulator pairwise (n<=128 base case), no FMA
//  - dist/d2 combine: separate f32 mul + f32 sub (ufuncs don't fuse)
//  - all top-k: f32 keys, ties -> lower index (stable, = jax top_k & np)
// The factored MLP prescreen (top-32 cut, ~17x margin) runs on MFMA bf16;
// its operand chain is algebraically collapsed (A1 = tmp_h@(cc_w0@w1_0) etc).

static __device__ __forceinline__ u32 ordu(float f) {
  u32 u = __float_as_uint(f);
  return u ^ (u32)(((int)u >> 31) | (int)0x80000000);
}
static __device__ __forceinline__ u16 f2bf(float f) {  // RNE f32->bf16
  u32 b = __float_as_uint(f);
  b += 0x7fffu + ((b >> 16) & 1u);
  return (u16)(b >> 16);
}

// ---------------- prep ----------------

__global__ __launch_bounds__(256) void k_cbrqT(const float* __restrict__ cbrq,
                                               float* __restrict__ cbT) {
  __shared__ float tile[128 * 33];
  const int k0 = blockIdx.x * 32;
  const int t = threadIdx.x;
#pragma unroll
  for (int rep = 0; rep < 16; ++rep) {
    const int flat = rep * 256 + t;
    const int kk = flat >> 7, d = flat & 127;
    tile[d * 33 + kk] = cbrq[(k0 + kk) * 128 + d];
  }
  __syncthreads();
#pragma unroll
  for (int rep = 0; rep < 16; ++rep) {
    const int flat = rep * 256 + t;
    const int d = flat >> 5, kk = flat & 31;
    cbT[d * 4096 + k0 + kk] = tile[d * 33 + kk];
  }
}

__global__ __launch_bounds__(256) void k_cbsq(const float* __restrict__ cbT,
                                              float* __restrict__ cb_sq) {
  const int k = blockIdx.x * 256 + threadIdx.x;
  float r[8];
#pragma unroll
  for (int j = 0; j < 8; ++j) {
    const float v = cbT[j * 4096 + k];
    r[j] = __fmul_rn(v, v);
  }
  for (int i = 8; i < 128; i += 8) {
#pragma unroll
    for (int j = 0; j < 8; ++j) {
      const float v = cbT[(i + j) * 4096 + k];
      r[j] = __fadd_rn(r[j], __fmul_rn(v, v));
    }
  }
  cb_sq[k] = __fadd_rn(
      __fadd_rn(__fadd_rn(r[0], r[1]), __fadd_rn(r[2], r[3])),
      __fadd_rn(__fadd_rn(r[4], r[5]), __fadd_rn(r[6], r[7])));
}

__global__ __launch_bounds__(256) void k_xt(const float* __restrict__ x,
                                            const float* __restrict__ xhat,
                                            float* __restrict__ xt) {
  const int i = blockIdx.x * 256 + threadIdx.x;
  const int row = i >> 5, d4 = i & 31;
  const float4 a = ((const float4*)x)[(row >> 4) * 32 + d4];
  const float4 b = ((const float4*)xhat)[i];
  float4 r;
  r.x = __fsub_rn(a.x, b.x); r.y = __fsub_rn(a.y, b.y);
  r.z = __fsub_rn(a.z, b.z); r.w = __fsub_rn(a.w, b.w);
  ((float4*)xt)[i] = r;
}

__global__ __launch_bounds__(256) void k_codeh(const float* __restrict__ cb,
                                               const float* __restrict__ in_w,
                                               const float* __restrict__ in_b,
                                               float* __restrict__ tmp_h) {
  __shared__ float row[128];
  const int code = blockIdx.x;
  const int t = threadIdx.x;
  if (t < 128) row[t] = cb[code * 128 + t];
  __syncthreads();
  float a = 0.f;
  for (int d = 0; d < 128; ++d) a = __builtin_fmaf(row[d], in_w[d * 256 + t], a);
  tmp_h[code * 256 + t] = __fadd_rn(a, in_b[t]);
}

// Wcat[256][640] = [w1_0 | w1_1 | out_w]
__global__ __launch_bounds__(256) void k_pack(const float* __restrict__ rb_w1,
                                              const float* __restrict__ out_w,
                                              float* __restrict__ Wcat) {
  const int i = blockIdx.x;  // 256 rows
  const int t = threadIdx.x;
  Wcat[i * 640 + t] = rb_w1[i * 256 + t];
  Wcat[i * 640 + 256 + t] = rb_w1[65536 + i * 256 + t];
  if (t < 128) Wcat[i * 640 + 512 + t] = out_w[i * 128 + t];
}

// cvec[640] = cc_b @ Wcat + [b1_0 | bias2v | biasDv]  (prescreen-only)
__global__ __launch_bounds__(256) void k_biasprep(
    const float* __restrict__ rb_b1, const float* __restrict__ rb_b2,
    const float* __restrict__ rb_w1, const float* __restrict__ out_w,
    const float* __restrict__ out_b, const float* __restrict__ cc_b,
    const float* __restrict__ Wcat, float* __restrict__ cvec) {
  const int t = threadIdx.x;
  const float* w11 = rb_w1 + 65536;
  float b2v = rb_b1[256 + t];
  for (int i = 0; i < 256; ++i) b2v += rb_b2[i] * w11[i * 256 + t];
  float c0 = rb_b1[t], c1 = b2v;
  for (int i = 0; i < 256; ++i) {
    const float cbi = cc_b[i];
    c0 += cbi * Wcat[i * 640 + t];
    c1 += cbi * Wcat[i * 640 + 256 + t];
  }
  cvec[t] = c0;
  cvec[256 + t] = c1;
  if (t < 128) {
    float bDv = out_b[t];
    for (int i = 0; i < 256; ++i)
      bDv += (rb_b2[i] + rb_b2[256 + i]) * out_w[i * 128 + t];
    float c2 = bDv;
    for (int i = 0; i < 256; ++i) c2 += cc_b[i] * Wcat[i * 640 + 512 + t];
    cvec[512 + t] = c2;
  }
}

// pack W21/V1/V2 (f32) into bf16 MFMA B-fragment layout
__global__ __launch_bounds__(256) void k_wfrag(
    const float* __restrict__ W21, const float* __restrict__ V1,
    const float* __restrict__ V2, u16* __restrict__ W21f,
    u16* __restrict__ V1f, u16* __restrict__ V2f) {
  const int gid = blockIdx.x * 256 + threadIdx.x;  // 16384 total
  const int l = gid & 63;
  const int grp = gid >> 6;  // [0,256)
  const int kq = (l >> 4) * 8;
  const int nn = l & 15;
  if (grp < 128) {
    const int kt = grp >> 4, nt = grp & 15;
    u16* dst = W21f + (size_t)(grp * 64 + l) * 8;
#pragma unroll
    for (int j = 0; j < 8; ++j)
      dst[j] = f2bf(W21[(kt * 32 + kq + j) * 256 + nt * 16 + nn]);
  } else if (grp < 192) {
    const int g2 = grp - 128, kt = g2 >> 3, nt = g2 & 7;
    u16* dst = V1f + (size_t)(g2 * 64 + l) * 8;
#pragma unroll
    for (int j = 0; j < 8; ++j)
      dst[j] = f2bf(V1[(kt * 32 + kq + j) * 128 + nt * 16 + nn]);
  } else {
    const int g2 = grp - 192, kt = g2 >> 3, nt = g2 & 7;
    u16* dst = V2f + (size_t)(g2 * 64 + l) * 8;
#pragma unroll
    for (int j = 0; j < 8; ++j)
      dst[j] = f2bf(V2[(kt * 32 + kq + j) * 128 + nt * 16 + nn]);
  }
}

// ---------------- generic f32 GEMM (small prescreen preps) ----------------
__global__ __launch_bounds__(256, 4) void gemm_f32(
    const float* __restrict__ Am, const float* __restrict__ Bm,
    float* __restrict__ Cm, const int Mi, const int Ni, const int Ki,
    const float* __restrict__ bias, const float* __restrict__ addm) {
  __shared__ float As[16][68];
  __shared__ float Bs[16][68];
  const int m0 = blockIdx.x * 64, n0 = blockIdx.y * 64;
  const int t = threadIdx.x;
  const int tm = (t & 15) * 4, tn = (t >> 4) * 4;
  float acc[4][4] = {};
  for (int k0 = 0; k0 < Ki; k0 += 16) {
    {
      const int row = t >> 2, q = t & 3;
      const float4 a4 = *(const float4*)(Am + (size_t)(m0 + row) * Ki + k0 + q * 4);
      As[q * 4 + 0][row] = a4.x; As[q * 4 + 1][row] = a4.y;
      As[q * 4 + 2][row] = a4.z; As[q * 4 + 3][row] = a4.w;
      const int kk = t >> 4, n4 = t & 15;
      *(float4*)&Bs[kk][n4 * 4] =
          *(const float4*)(Bm + (size_t)(k0 + kk) * Ni + n0 + n4 * 4);
    }
    __syncthreads();
#pragma unroll
    for (int kk = 0; kk < 16; ++kk) {
      const float4 av = *(const float4*)&As[kk][tm];
      const float4 bv = *(const float4*)&Bs[kk][tn];
      const float aa[4] = {av.x, av.y, av.z, av.w};
      const float bb[4] = {bv.x, bv.y, bv.z, bv.w};
#pragma unroll
      for (int i = 0; i < 4; ++i)
#pragma unroll
        for (int j = 0; j < 4; ++j) acc[i][j] += aa[i] * bb[j];
    }
    __syncthreads();
  }
#pragma unroll
  for (int i = 0; i < 4; ++i) {
    const int m = m0 + tm + i;
#pragma unroll
    for (int j = 0; j < 4; ++j) {
      const int n = n0 + tn + j;
      float v = acc[i][j];
      if (bias) v += bias[n];
      if (addm) v += addm[(size_t)m * Ni + n];
      Cm[(size_t)m * Ni + n] = v;
    }
  }
}

// ---------------- scatter GEMM: E = A[M,K]@B[K,640] (+bias) -> O1|O2|O3(+add3) ----------------
__global__ __launch_bounds__(256, 4) void gemm_scatter(
    const float* __restrict__ Am, const float* __restrict__ Bm, const int Mi,
    const int Ki, const float* __restrict__ bias,
    const float* __restrict__ add3, float* __restrict__ O1,
    float* __restrict__ O2, float* __restrict__ O3) {
  __shared__ float As[16][68];
  __shared__ float Bs[16][68];
  const int m0 = blockIdx.x * 64, n0 = blockIdx.y * 64;
  const int t = threadIdx.x;
  const int tm = (t & 15) * 4, tn = (t >> 4) * 4;
  float acc[4][4] = {};
  for (int k0 = 0; k0 < Ki; k0 += 16) {
    {
      const int row = t >> 2, q = t & 3;
      const float4 a4 = *(const float4*)(Am + (size_t)(m0 + row) * Ki + k0 + q * 4);
      As[q * 4 + 0][row] = a4.x; As[q * 4 + 1][row] = a4.y;
      As[q * 4 + 2][row] = a4.z; As[q * 4 + 3][row] = a4.w;
      const int kk = t >> 4, n4 = t & 15;
      *(float4*)&Bs[kk][n4 * 4] =
          *(const float4*)(Bm + (size_t)(k0 + kk) * 640 + n0 + n4 * 4);
    }
    __syncthreads();
#pragma unroll
    for (int kk = 0; kk < 16; ++kk) {
      const float4 av = *(const float4*)&As[kk][tm];
      const float4 bv = *(const float4*)&Bs[kk][tn];
      const float aa[4] = {av.x, av.y, av.z, av.w};
      const float bb[4] = {bv.x, bv.y, bv.z, bv.w};
#pragma unroll
      for (int i = 0; i < 4; ++i)
#pragma unroll
        for (int j = 0; j < 4; ++j) acc[i][j] += aa[i] * bb[j];
    }
    __syncthreads();
  }
#pragma unroll
  for (int i = 0; i < 4; ++i) {
    const int m = m0 + tm + i;
#pragma unroll
    for (int j = 0; j < 4; ++j) {
      const int n = n0 + tn + j;
      float v = acc[i][j];
      if (bias) v += bias[n];
      if (n < 256) {
        O1[(size_t)m * 256 + n] = v;
      } else if (n < 512) {
        O2[(size_t)m * 256 + n - 256] = v;
      } else {
        if (add3) v += add3[(size_t)m * 128 + n - 512];
        O3[(size_t)m * 128 + n - 512] = v;
      }
    }
  }
}

// ---------------- stage 1: bitwise-np f32 dists + stable top-32 ----------------
__global__ __launch_bounds__(512, 2) void k_stage1(
    const float* __restrict__ xt, const float* __restrict__ cbT,
    const float* __restrict__ cb_sq, int* __restrict__ topc) {
  __shared__ u32 distL[4 * 4096];  // 64 KB
  __shared__ float xtL[512];
  const int r0 = blockIdx.x * 4;
  const int t = threadIdx.x;
  xtL[t] = xt[r0 * 128 + t];
  __syncthreads();
  {
    const int k0 = t * 8;
    float acc[4][8] = {};
    for (int d = 0; d < 128; ++d) {
      const float4 c0 = *(const float4*)&cbT[d * 4096 + k0];
      const float4 c1 = *(const float4*)&cbT[d * 4096 + k0 + 4];
      const float cv[8] = {c0.x, c0.y, c0.z, c0.w, c1.x, c1.y, c1.z, c1.w};
      const float x0 = xtL[d], x1 = xtL[128 + d], x2 = xtL[256 + d],
                  x3 = xtL[384 + d];
#pragma unroll
      for (int j = 0; j < 8; ++j) {
        acc[0][j] = __builtin_fmaf(x0, cv[j], acc[0][j]);
        acc[1][j] = __builtin_fmaf(x1, cv[j], acc[1][j]);
        acc[2][j] = __builtin_fmaf(x2, cv[j], acc[2][j]);
        acc[3][j] = __builtin_fmaf(x3, cv[j], acc[3][j]);
      }
    }
    const float4 s0 = *(const float4*)&cb_sq[k0];
    const float4 s1 = *(const float4*)&cb_sq[k0 + 4];
    const float cs[8] = {s0.x, s0.y, s0.z, s0.w, s1.x, s1.y, s1.z, s1.w};
#pragma unroll
    for (int rr = 0; rr < 4; ++rr)
#pragma unroll
      for (int j = 0; j < 8; ++j)
        distL[rr * 4096 + k0 + j] =
            ordu(__fsub_rn(cs[j], __fmul_rn(2.0f, acc[rr][j])));
  }
  __syncthreads();
  const int w = t >> 6, lane = t & 63;
  if (w < 4) {
    u32* dr = distL + w * 4096;
    u64 m1 = ~0ull, m2 = ~0ull;
    for (int e = 0; e < 64; ++e) {
      const int idx = e * 64 + lane;
      const u64 key = ((u64)dr[idx] << 32) | (u32)idx;
      if (key < m1) { m2 = m1; m1 = key; } else if (key < m2) { m2 = key; }
    }
    bool have2 = true;
    for (int it = 0; it < 32; ++it) {
      u64 g = m1;
#pragma unroll
      for (int sh = 1; sh < 64; sh <<= 1) {
        const u64 o = __shfl_xor(g, sh);
        g = (o < g) ? o : g;
      }
      const int bi = (int)(g & 0xFFFFFFFFu);
      if (lane == 0) topc[(r0 + w) * 32 + it] = bi;
      if ((bi & 63) == lane) {
        dr[bi] = 0xFFFFFFFFu;
        if (have2) {
          m1 = m2; m2 = ~0ull; have2 = false;
        } else {
          m1 = m2 = ~0ull;
          for (int e = 0; e < 64; ++e) {
            const int idx = e * 64 + lane;
            const u64 key = ((u64)dr[idx] << 32) | (u32)idx;
            if (key < m1) { m2 = m1; m1 = key; } else if (key < m2) { m2 = key; }
          }
          have2 = true;
        }
      }
    }
  }
}

// ---------------- stage 2: MFMA bf16 prescreen ----------------
__global__ __launch_bounds__(256, 4) void k_mlp(
    const int* __restrict__ topc, const float* __restrict__ A1,
    const float* __restrict__ A2, const float* __restrict__ B1,
    const float* __restrict__ B2, const float* __restrict__ Dc,
    const float* __restrict__ Dr, const u16* __restrict__ W21f,
    const u16* __restrict__ V1f, const u16* __restrict__ V2f,
    const float* __restrict__ xhat, const float* __restrict__ x,
    float* __restrict__ d2g) {
  __shared__ __align__(16) u16 abuf[32 * 264];  // 16.5 KB, r1 then r2
  __shared__ float B1r[256];
  __shared__ int codesL[32];
  __shared__ float d2red[32][4];

  const int tt = threadIdx.x;
  const int br = blockIdx.x;  // beam row
  const int bb = br >> 4;
  const int w = tt >> 6, l = tt & 63;

  B1r[tt] = B1[br * 256 + tt];
  if (tt < 32) codesL[tt] = topc[br * 32 + tt];
  __syncthreads();

  {
    const int c = tt & 31, g = tt >> 5;
    const int code = codesL[c];
    const float4* A14 = (const float4*)(A1 + code * 256 + g * 32);
    u32* dst = (u32*)(abuf + c * 264 + g * 32);
#pragma unroll
    for (int e4 = 0; e4 < 8; ++e4) {
      const float4 a = A14[e4];
      const int i = g * 32 + e4 * 4;
      const u32 p0 = (u32)f2bf(fmaxf(a.x + B1r[i], 0.f)) |
                     ((u32)f2bf(fmaxf(a.y + B1r[i + 1], 0.f)) << 16);
      const u32 p1 = (u32)f2bf(fmaxf(a.z + B1r[i + 2], 0.f)) |
                     ((u32)f2bf(fmaxf(a.w + B1r[i + 3], 0.f)) << 16);
      dst[e4 * 2] = p0;
      dst[e4 * 2 + 1] = p1;
    }
  }
  __syncthreads();

  const int arow = l & 15;
  const int kq = (l >> 4) * 8;
  const s16x8* wf = (const s16x8*)W21f;
  const s16x8* v1f = (const s16x8*)V1f;
  const s16x8* v2f = (const s16x8*)V2f;
  const f32x4 zero4 = {0.f, 0.f, 0.f, 0.f};

  f32x4 accf[2][4];
#pragma unroll
  for (int mt = 0; mt < 2; ++mt)
#pragma unroll
    for (int ntl = 0; ntl < 4; ++ntl) accf[mt][ntl] = zero4;
  for (int kt = 0; kt < 8; ++kt) {
    const s16x8 a0 = *(const s16x8*)(abuf + arow * 264 + kt * 32 + kq);
    const s16x8 a1 = *(const s16x8*)(abuf + (16 + arow) * 264 + kt * 32 + kq);
#pragma unroll
    for (int ntl = 0; ntl < 4; ++ntl) {
      const s16x8 b = wf[(kt * 16 + w * 4 + ntl) * 64 + l];
      accf[0][ntl] =
          __builtin_amdgcn_mfma_f32_16x16x32_bf16(a0, b, accf[0][ntl], 0, 0, 0);
      accf[1][ntl] =
          __builtin_amdgcn_mfma_f32_16x16x32_bf16(a1, b, accf[1][ntl], 0, 0, 0);
    }
  }

  f32x4 acc2f[2][2];
#pragma unroll
  for (int mt = 0; mt < 2; ++mt)
#pragma unroll
    for (int ntl = 0; ntl < 2; ++ntl) acc2f[mt][ntl] = zero4;
  for (int kt = 0; kt < 8; ++kt) {
    const s16x8 a0 = *(const s16x8*)(abuf + arow * 264 + kt * 32 + kq);
    const s16x8 a1 = *(const s16x8*)(abuf + (16 + arow) * 264 + kt * 32 + kq);
#pragma unroll
    for (int ntl = 0; ntl < 2; ++ntl) {
      const s16x8 b = v1f[(kt * 8 + w * 2 + ntl) * 64 + l];
      acc2f[0][ntl] = __builtin_amdgcn_mfma_f32_16x16x32_bf16(
          a0, b, acc2f[0][ntl], 0, 0, 0);
      acc2f[1][ntl] = __builtin_amdgcn_mfma_f32_16x16x32_bf16(
          a1, b, acc2f[1][ntl], 0, 0, 0);
    }
  }

  u16 r2v[2][4][4];
#pragma unroll
  for (int mt = 0; mt < 2; ++mt)
#pragma unroll
    for (int ntl = 0; ntl < 4; ++ntl) {
      const int n = w * 64 + ntl * 16 + arow;
      const float b2 = B2[br * 256 + n];
      const f32x4 cf = accf[mt][ntl];
#pragma unroll
      for (int rg = 0; rg < 4; ++rg) {
        const int m = mt * 16 + (l >> 4) * 4 + rg;
        const float a2 = A2[codesL[m] * 256 + n];
        r2v[mt][ntl][rg] = f2bf(fmaxf(cf[rg] + a2 + b2, 0.f));
      }
    }
  __syncthreads();
#pragma unroll
  for (int mt = 0; mt < 2; ++mt)
#pragma unroll
    for (int ntl = 0; ntl < 4; ++ntl) {
      const int n = w * 64 + ntl * 16 + arow;
#pragma unroll
      for (int rg = 0; rg < 4; ++rg) {
        const int m = mt * 16 + (l >> 4) * 4 + rg;
        abuf[m * 264 + n] = r2v[mt][ntl][rg];
      }
    }
  __syncthreads();

  for (int kt = 0; kt < 8; ++kt) {
    const s16x8 a0 = *(const s16x8*)(abuf + arow * 264 + kt * 32 + kq);
    const s16x8 a1 = *(const s16x8*)(abuf + (16 + arow) * 264 + kt * 32 + kq);
#pragma unroll
    for (int ntl = 0; ntl < 2; ++ntl) {
      const s16x8 b = v2f[(kt * 8 + w * 2 + ntl) * 64 + l];
      acc2f[0][ntl] = __builtin_amdgcn_mfma_f32_16x16x32_bf16(
          a0, b, acc2f[0][ntl], 0, 0, 0);
      acc2f[1][ntl] = __builtin_amdgcn_mfma_f32_16x16x32_bf16(
          a1, b, acc2f[1][ntl], 0, 0, 0);
    }
  }

  float sm[2][4];
#pragma unroll
  for (int mt = 0; mt < 2; ++mt)
#pragma unroll
    for (int rg = 0; rg < 4; ++rg) sm[mt][rg] = 0.f;
#pragma unroll
  for (int ntl = 0; ntl < 2; ++ntl) {
    const int d = w * 32 + ntl * 16 + arow;
    const float dr = Dr[br * 128 + d];
    const float xh = xhat[br * 128 + d];
    const float xq = x[bb * 128 + d];
#pragma unroll
    for (int mt = 0; mt < 2; ++mt) {
      const f32x4 cf = acc2f[mt][ntl];
#pragma unroll
      for (int rg = 0; rg < 4; ++rg) {
        const int m = mt * 16 + (l >> 4) * 4 + rg;
        const float cand = cf[rg] + Dc[codesL[m] * 128 + d] + dr + xh;
        sm[mt][rg] += cand * cand - 2.f * xq * cand;
      }
    }
  }
#pragma unroll
  for (int mt = 0; mt < 2; ++mt)
#pragma unroll
    for (int rg = 0; rg < 4; ++rg) {
      float s = sm[mt][rg];
      s += __shfl_xor(s, 1);
      s += __shfl_xor(s, 2);
      s += __shfl_xor(s, 4);
      s += __shfl_xor(s, 8);
      if (arow == 0) d2red[mt * 16 + (l >> 4) * 4 + rg][w] = s;
    }
  __syncthreads();
  if (tt < 32)
    d2g[bb * 512 + (br & 15) * 32 + tt] =
        d2red[tt][0] + d2red[tt][1] + d2red[tt][2] + d2red[tt][3];
}

// ---------------- stage 3a: prescreen top-32 per base query ----------------
__global__ __launch_bounds__(64, 1) void k_sel32(const float* __restrict__ d2g,
                                                 int* __restrict__ sel32) {
  __shared__ u32 d2u[512];
  const int bb = blockIdx.x;
  const int t = threadIdx.x;
  for (int i = t; i < 512; i += 64) d2u[i] = ordu(d2g[bb * 512 + i]);
  __syncthreads();
  for (int it = 0; it < 32; ++it) {
    u64 m = ~0ull;
#pragma unroll
    for (int e = 0; e < 8; ++e) {
      const int idx = e * 64 + t;
      const u64 key = ((u64)d2u[idx] << 32) | (u32)idx;
      m = (key < m) ? key : m;
    }
#pragma unroll
    for (int sh = 1; sh < 64; sh <<= 1) {
      const u64 o = __shfl_xor(m, sh);
      m = (o < m) ? o : m;
    }
    const int s = (int)(m & 0xFFFFFFFFu);
    if ((s & 63) == t) d2u[s] = 0xFFFFFFFFu;
    if (t == 0) sel32[bb * 32 + it] = s;
  }
}

// ---------------- stage 3b: np-emulated rescore of top-32 ----------------
// seq-FMA over k ascending per accumulator (bitwise-np); float4 activation
// reads; LDS diet -> 5 blocks/CU.
__global__ __launch_bounds__(256, 5) void k_rescore(
    const int* __restrict__ sel32, const int* __restrict__ topc,
    const float* __restrict__ tmp_h, const float* __restrict__ cb,
    const float* __restrict__ xhat, const float* __restrict__ x,
    const float* __restrict__ cc_w, const float* __restrict__ cc_b,
    const float* __restrict__ rb_w1, const float* __restrict__ rb_b1,
    const float* __restrict__ rb_w2, const float* __restrict__ rb_b2,
    const float* __restrict__ out_w, const float* __restrict__ out_b,
    float* __restrict__ d2r, float* __restrict__ candv) {
  __shared__ float A_[8][256], B_[8][256], C_[8][256];
  __shared__ float xhL[8][128], xqL[128];
  __shared__ int codeL[8], rowL[8];
  const int bb = blockIdx.x >> 2;
  const int j0 = (blockIdx.x & 3) * 8;
  const int t = threadIdx.x;
  if (t < 8) {
    const int s = sel32[bb * 32 + j0 + t];
    rowL[t] = bb * 16 + (s >> 5);
    codeL[t] = topc[(bb * 16 + (s >> 5)) * 32 + (s & 31)];
  }
  if (t < 128) xqL[t] = x[bb * 128 + t];
  __syncthreads();
  for (int idx = t; idx < 1024; idx += 256) {
    const int c = idx >> 7, d = idx & 127;
    xhL[c][d] = xhat[rowL[c] * 128 + d];
  }
  for (int idx = t; idx < 2048; idx += 256) {
    const int c = idx >> 8, i = idx & 255;
    A_[c][i] = tmp_h[codeL[c] * 256 + i];
  }
  __syncthreads();
  // h0 = seqFMA(concat(h_in, xhat) @ cc_w) + cc_b  -> B_
  {
    float acc[8] = {};
    for (int i = 0; i < 256; i += 4) {
      const float w0 = cc_w[(i + 0) * 256 + t], w1 = cc_w[(i + 1) * 256 + t];
      const float w2 = cc_w[(i + 2) * 256 + t], w3 = cc_w[(i + 3) * 256 + t];
#pragma unroll
      for (int c = 0; c < 8; ++c) {
        const float4 h = *(const float4*)&A_[c][i];
        acc[c] = __builtin_fmaf(h.x, w0, acc[c]);
        acc[c] = __builtin_fmaf(h.y, w1, acc[c]);
        acc[c] = __builtin_fmaf(h.z, w2, acc[c]);
        acc[c] = __builtin_fmaf(h.w, w3, acc[c]);
      }
    }
    for (int d = 0; d < 128; d += 4) {
      const float w0 = cc_w[(256 + d + 0) * 256 + t];
      const float w1 = cc_w[(256 + d + 1) * 256 + t];
      const float w2 = cc_w[(256 + d + 2) * 256 + t];
      const float w3 = cc_w[(256 + d + 3) * 256 + t];
#pragma unroll
      for (int c = 0; c < 8; ++c) {
        const float4 h = *(const float4*)&xhL[c][d];
        acc[c] = __builtin_fmaf(h.x, w0, acc[c]);
        acc[c] = __builtin_fmaf(h.y, w1, acc[c]);
        acc[c] = __builtin_fmaf(h.z, w2, acc[c]);
        acc[c] = __builtin_fmaf(h.w, w3, acc[c]);
      }
    }
    const float b = cc_b[t];
#pragma unroll
    for (int c = 0; c < 8; ++c) B_[c][t] = __fadd_rn(acc[c], b);
  }
  __syncthreads();
  // r1 = relu(seqFMA(h0 @ w1_0) + b1_0) -> C_
  {
    float acc[8] = {};
    for (int i = 0; i < 256; i += 4) {
      const float w0 = rb_w1[(i + 0) * 256 + t], w1 = rb_w1[(i + 1) * 256 + t];
      const float w2 = rb_w1[(i + 2) * 256 + t], w3 = rb_w1[(i + 3) * 256 + t];
#pragma unroll
      for (int c = 0; c < 8; ++c) {
        const float4 h = *(const float4*)&B_[c][i];
        acc[c] = __builtin_fmaf(h.x, w0, acc[c]);
        acc[c] = __builtin_fmaf(h.y, w1, acc[c]);
        acc[c] = __builtin_fmaf(h.z, w2, acc[c]);
        acc[c] = __builtin_fmaf(h.w, w3, acc[c]);
      }
    }
    const float b = rb_b1[t];
#pragma unroll
    for (int c = 0; c < 8; ++c) C_[c][t] = fmaxf(__fadd_rn(acc[c], b), 0.f);
  }
  __syncthreads();
  // h1 = (h0 + seqFMA(r1 @ w2_0)) + b2_0 -> A_
  {
    float acc[8] = {};
    for (int i = 0; i < 256; i += 4) {
      const float w0 = rb_w2[(i + 0) * 256 + t], w1 = rb_w2[(i + 1) * 256 + t];
      const float w2 = rb_w2[(i + 2) * 256 + t], w3 = rb_w2[(i + 3) * 256 + t];
#pragma unroll
      for (int c = 0; c < 8; ++c) {
        const float4 h = *(const float4*)&C_[c][i];
        acc[c] = __builtin_fmaf(h.x, w0, acc[c]);
        acc[c] = __builtin_fmaf(h.y, w1, acc[c]);
        acc[c] = __builtin_fmaf(h.z, w2, acc[c]);
        acc[c] = __builtin_fmaf(h.w, w3, acc[c]);
      }
    }
    const float b = rb_b2[t];
#pragma unroll
    for (int c = 0; c < 8; ++c)
      A_[c][t] = __fadd_rn(__fadd_rn(B_[c][t], acc[c]), b);
  }
  __syncthreads();
  // r2 = relu(seqFMA(h1 @ w1_1) + b1_1) -> B_
  {
    float acc[8] = {};
    const float* w11 = rb_w1 + 65536;
    for (int i = 0; i < 256; i += 4) {
      const float w0 = w11[(i + 0) * 256 + t], w1 = w11[(i + 1) * 256 + t];
      const float w2 = w11[(i + 2) * 256 + t], w3 = w11[(i + 3) * 256 + t];
#pragma unroll
      for (int c = 0; c < 8; ++c) {
        const float4 h = *(const float4*)&A_[c][i];
        acc[c] = __builtin_fmaf(h.x, w0, acc[c]);
        acc[c] = __builtin_fmaf(h.y, w1, acc[c]);
        acc[c] = __builtin_fmaf(h.z, w2, acc[c]);
        acc[c] = __builtin_fmaf(h.w, w3, acc[c]);
      }
    }
    const float b = rb_b1[256 + t];
#pragma unroll
    for (int c = 0; c < 8; ++c) B_[c][t] = fmaxf(__fadd_rn(acc[c], b), 0.f);
  }
  __syncthreads();
  // h2 = (h1 + seqFMA(r2 @ w2_1)) + b2_1 -> C_
  {
    float acc[8] = {};
    const float* w21 = rb_w2 + 65536;
    for (int i = 0; i < 256; i += 4) {
      const float w0 = w21[(i + 0) * 256 + t], w1 = w21[(i + 1) * 256 + t];
      const float w2 = w21[(i + 2) * 256 + t], w3 = w21[(i + 3) * 256 + t];
#pragma unroll
      for (int c = 0; c < 8; ++c) {
        const float4 h = *(const float4*)&B_[c][i];
        acc[c] = __builtin_fmaf(h.x, w0, acc[c]);
        acc[c] = __builtin_fmaf(h.y, w1, acc[c]);
        acc[c] = __builtin_fmaf(h.z, w2, acc[c]);
        acc[c] = __builtin_fmaf(h.w, w3, acc[c]);
      }
    }
    const float b = rb_b2[256 + t];
#pragma unroll
    for (int c = 0; c < 8; ++c)
      C_[c][t] = __fadd_rn(__fadd_rn(A_[c][t], acc[c]), b);
  }
  __syncthreads();
  // cand = ((seqFMA(h2@out_w) + out_b) + cw_in) + xhat -> B_ (reused)
  if (t < 128) {
    float acc[8] = {};
    for (int i = 0; i < 256; i += 4) {
      const float w0 = out_w[(i + 0) * 128 + t], w1 = out_w[(i + 1) * 128 + t];
      const float w2 = out_w[(i + 2) * 128 + t], w3 = out_w[(i + 3) * 128 + t];
#pragma unroll
      for (int c = 0; c < 8; ++c) {
        const float4 h = *(const float4*)&C_[c][i];
        acc[c] = __builtin_fmaf(h.x, w0, acc[c]);
        acc[c] = __builtin_fmaf(h.y, w1, acc[c]);
        acc[c] = __builtin_fmaf(h.z, w2, acc[c]);
        acc[c] = __builtin_fmaf(h.w, w3, acc[c]);
      }
    }
    const float ob = out_b[t];
#pragma unroll
    for (int c = 0; c < 8; ++c) {
      const float cbv = cb[codeL[c] * 128 + t];
      const float cw_ = __fadd_rn(__fadd_rn(acc[c], ob), cbv);
      const float cand = __fadd_rn(cw_, xhL[c][t]);
      B_[c][t] = cand;
      candv[(bb * 32 + j0 + c) * 128 + t] = cand;
    }
  }
  __syncthreads();
  if (t < 8) {
    float r[8];
#pragma unroll
    for (int j = 0; j < 8; ++j) {
      const float v = B_[t][j];
      r[j] = __fmul_rn(v, v);
    }
    for (int i = 8; i < 128; i += 8) {
#pragma unroll
      for (int j = 0; j < 8; ++j) {
        const float v = B_[t][i + j];
        r[j] = __fadd_rn(r[j], __fmul_rn(v, v));
      }
    }
    const float s1f = __fadd_rn(
        __fadd_rn(__fadd_rn(r[0], r[1]), __fadd_rn(r[2], r[3])),
        __fadd_rn(__fadd_rn(r[4], r[5]), __fadd_rn(r[6], r[7])));
    double s2 = 0.0;
    for (int d = 0; d < 128; ++d)
      s2 += (double)xqL[d] * (double)B_[t][d];
    const float s2f = (float)s2;
    d2r[bb * 32 + j0 + t] = __fsub_rn(s1f, __fmul_rn(2.0f, s2f));
  }
}

// ---------------- stage 3c/4: stable top-16 by f32 d2 ----------------
__global__ __launch_bounds__(64, 1) void k_final(
    const float* __restrict__ d2r, const int* __restrict__ sel32,
    const int* __restrict__ topc, const int* __restrict__ codes_in,
    const float* __restrict__ candv, float* __restrict__ out) {
  __shared__ u32 winLo[16];
  const int bb = blockIdx.x;
  const int t = threadIdx.x;
  u64 key = ~0ull;
  if (t < 32) {
    const u32 s = (u32)sel32[bb * 32 + t];
    key = ((u64)ordu(d2r[bb * 32 + t]) << 32) | (s << 5) | (u32)t;
  }
  for (int it = 0; it < 16; ++it) {
    u64 m = key;
#pragma unroll
    for (int sh = 1; sh < 64; sh <<= 1) {
      const u64 o = __shfl_xor(m, sh);
      m = (o < m) ? o : m;
    }
    if (key == m) key = ~0ull;
    if (t == 0) winLo[it] = (u32)(m & 0xFFFFFFFFu);
  }
  __syncthreads();
  if (t < 16) {
    const u32 lo = winLo[t];
    const int s = (int)((lo >> 5) & 511u);
    const int f = s >> 5;
    const int code = topc[(bb * 16 + f) * 32 + (s & 31)];
    float* oc = out + 512 * 16 * 128;
    oc[bb * 16 + t] = (float)codes_in[bb * 16 + f];
    oc[8192 + bb * 16 + t] = (float)codes_in[8192 + bb * 16 + f];
    oc[16384 + bb * 16 + t] = (float)code;
  }
  __syncthreads();
  for (int idx = t; idx < 2048; idx += 64) {
    const int w_ = idx >> 7, d = idx & 127;
    const int j = (int)(winLo[w_] & 31u);
    out[(bb * 16 + w_) * 128 + d] = candv[(bb * 32 + j) * 128 + d];
  }
}

// ---------------- launch ----------------
extern "C" void kernel_launch(void* const* d_in, const int* in_sizes, int n_in,
                              void* d_out, int out_size, void* d_ws,
                              size_t ws_size, hipStream_t stream) {
  const float* x = (const float*)d_in[0];
  const float* xhat = (const float*)d_in[1];
  const int* codes = (const int*)d_in[2];
  const float* cb = (const float*)d_in[3];
  const float* cbrq = (const float*)d_in[4];
  const float* in_w = (const float*)d_in[5];
  const float* in_b = (const float*)d_in[6];
  const float* cc_w = (const float*)d_in[7];
  const float* cc_b = (const float*)d_in[8];
  const float* rb_w1 = (const float*)d_in[9];
  const float* rb_b1 = (const float*)d_in[10];
  const float* rb_w2 = (const float*)d_in[11];
  const float* rb_b2 = (const float*)d_in[12];
  const float* out_w = (const float*)d_in[13];
  const float* out_b = (const float*)d_in[14];
  float* out = (float*)d_out;

  float* ws = (float*)d_ws;
  size_t o = 0;
  float* cb_sq = ws + o; o += 4096;
  float* xt = ws + o;    const size_t xt_off = o; o += (size_t)8192 * 128;
  float* cbT = ws + o;   o += (size_t)128 * 4096;
  float* tmp_h = ws + o; o += (size_t)4096 * 256;   // LIVE through k_rescore
  float* Wcat = ws + o;  o += (size_t)256 * 640;
  float* M_A = ws + o;   o += (size_t)256 * 640;
  float* M_B = ws + o;   o += (size_t)128 * 640;
  float* cvec = ws + o;  o += 640;
  float* A1 = ws + o;    o += (size_t)4096 * 256;
  float* A2 = ws + o;    o += (size_t)4096 * 256;
  float* Dc = ws + o;    o += (size_t)4096 * 128;
  float* B1 = ws + o;    o += (size_t)8192 * 256;
  float* B2 = ws + o;    o += (size_t)8192 * 256;
  float* Dr = ws + o;    o += (size_t)8192 * 128;
  float* W21 = ws + o;   o += 65536;
  float* V1 = ws + o;    o += 32768;
  float* V2 = ws + o;    o += 32768;
  int* topc = (int*)(ws + o); o += 262144;
  float* d2g = ws + o;   o += 262144;
  u16* W21f = (u16*)(ws + o); o += 32768;  // 65536 bf16
  u16* V1f = (u16*)(ws + o);  o += 16384;  // 32768 bf16
  u16* V2f = (u16*)(ws + o);  o += 16384;
  float* candv = ws + o; o += (size_t)16384 * 128;
  float* d2r = ws + xt_off;                // xt dead post-stage1
  int* sel32 = (int*)(ws + xt_off + 16384);

  k_cbrqT<<<dim3(128), dim3(256), 0, stream>>>(cbrq, cbT);
  k_cbsq<<<dim3(16), dim3(256), 0, stream>>>(cbT, cb_sq);
  k_xt<<<dim3(1024), dim3(256), 0, stream>>>(x, xhat, xt);
  k_codeh<<<dim3(4096), dim3(256), 0, stream>>>(cb, in_w, in_b, tmp_h);
  k_pack<<<dim3(256), dim3(256), 0, stream>>>(rb_w1, out_w, Wcat);
  k_biasprep<<<dim3(1), dim3(256), 0, stream>>>(rb_b1, rb_b2, rb_w1, out_w,
                                                out_b, cc_b, Wcat, cvec);
  // M_A = cc_w0 @ Wcat ; M_B = cc_w1 @ Wcat
  gemm_f32<<<dim3(4, 10), dim3(256), 0, stream>>>(cc_w, Wcat, M_A, 256, 640,
                                                  256, nullptr, nullptr);
  gemm_f32<<<dim3(2, 10), dim3(256), 0, stream>>>(cc_w + 256 * 256, Wcat, M_B,
                                                  128, 640, 256, nullptr,
                                                  nullptr);
  // EA = tmp_h @ M_A -> A1 | A2 | Dc(+cb)
  gemm_scatter<<<dim3(64, 10), dim3(256), 0, stream>>>(
      tmp_h, M_A, 4096, 256, nullptr, cb, A1, A2, Dc);
  // EB = xhat @ M_B + cvec -> B1 | B2 | Dr
  gemm_scatter<<<dim3(128, 10), dim3(256), 0, stream>>>(
      xhat, M_B, 8192, 128, cvec, nullptr, B1, B2, Dr);
  // W21 = w2_0@w1_1 ; V1 = w2_0@out_w ; V2 = w2_1@out_w
  gemm_f32<<<dim3(4, 4), dim3(256), 0, stream>>>(rb_w2, rb_w1 + 65536, W21, 256,
                                                 256, 256, nullptr, nullptr);
  gemm_f32<<<dim3(4, 2), dim3(256), 0, stream>>>(rb_w2, out_w, V1, 256, 128,
                                                 256, nullptr, nullptr);
  gemm_f32<<<dim3(4, 2), dim3(256), 0, stream>>>(rb_w2 + 65536, out_w, V2, 256,
                                                 128, 256, nullptr, nullptr);
  k_wfrag<<<dim3(64), dim3(256), 0, stream>>>(W21, V1, V2, W21f, V1f, V2f);

  k_stage1<<<dim3(2048), dim3(512), 0, stream>>>(xt, cbT, cb_sq, topc);
  k_mlp<<<dim3(8192), dim3(256), 0, stream>>>(topc, A1, A2, B1, B2, Dc, Dr,
                                              W21f, V1f, V2f, xhat, x, d2g);
  k_sel32<<<dim3(512), dim3(64), 0, stream>>>(d2g, sel32);
  k_rescore<<<dim3(2048), dim3(256), 0, stream>>>(
      sel32, topc, tmp_h, cb, xhat, x, cc_w, cc_b, rb_w1, rb_b1, rb_w2, rb_b2,
      out_w, out_b, d2r, candv);
  k_final<<<dim3(512), dim3(64), 0, stream>>>(d2r, sel32, topc, codes, candv,
                                              out);
  (void)in_sizes; (void)n_in; (void)out_size; (void)ws_size;
}

// Round 14
// 878.388 us; speedup vs baseline: 2.3093x; 1.0155x over previous
//
#include <hip/hip_runtime.h>
#include <float.h>

typedef unsigned int u32;
typedef unsigned long long u64;
typedef unsigned short u16;
typedef __attribute__((ext_vector_type(8))) short s16x8;
typedef __attribute__((ext_vector_type(4))) float f32x4;

// Bb=512, F=16 -> 8192 beam rows, D=128, DH=256, K=4096, A=32, Fo=16, M=2.
// Selection-critical math reproduces numpy's f32 arithmetic bitwise (model):
//  - matmul: per-output sequential f32 FMA over k ascending (sgemm micro-kernel)
//  - np.sum(last axis): 8-accumulator pairwise (n<=128 base case), no FMA
//  - dist/d2 combine: separate f32 mul + f32 sub (ufuncs don't fuse)
//  - all top-k: f32 keys, ties -> lower index (stable, = jax top_k & np)
// Rescore shares the code-dependent h0 prefix via P[code][j] (the partial
// accumulator after the tmp_h part of the chain -- bitwise identical).
// The factored MLP prescreen (top-32 cut) runs on MFMA bf16.

static __device__ __forceinline__ u32 ordu(float f) {
  u32 u = __float_as_uint(f);
  return u ^ (u32)(((int)u >> 31) | (int)0x80000000);
}
static __device__ __forceinline__ u16 f2bf(float f) {  // RNE f32->bf16
  u32 b = __float_as_uint(f);
  b += 0x7fffu + ((b >> 16) & 1u);
  return (u16)(b >> 16);
}

// ---------------- prep ----------------

// transpose + fused cb_sq (np pairwise-8, bitwise as before)
__global__ __launch_bounds__(256) void k_cbrqT(const float* __restrict__ cbrq,
                                               float* __restrict__ cbT,
                                               float* __restrict__ cb_sq) {
  __shared__ float tile[128 * 33];
  const int k0 = blockIdx.x * 32;
  const int t = threadIdx.x;
#pragma unroll
  for (int rep = 0; rep < 16; ++rep) {
    const int flat = rep * 256 + t;
    const int kk = flat >> 7, d = flat & 127;
    tile[d * 33 + kk] = cbrq[(k0 + kk) * 128 + d];
  }
  __syncthreads();
#pragma unroll
  for (int rep = 0; rep < 16; ++rep) {
    const int flat = rep * 256 + t;
    const int d = flat >> 5, kk = flat & 31;
    cbT[d * 4096 + k0 + kk] = tile[d * 33 + kk];
  }
  if (t < 32) {
    float r[8];
#pragma unroll
    for (int j = 0; j < 8; ++j) {
      const float v = tile[j * 33 + t];
      r[j] = __fmul_rn(v, v);
    }
    for (int i = 8; i < 128; i += 8) {
#pragma unroll
      for (int j = 0; j < 8; ++j) {
        const float v = tile[(i + j) * 33 + t];
        r[j] = __fadd_rn(r[j], __fmul_rn(v, v));
      }
    }
    cb_sq[k0 + t] = __fadd_rn(
        __fadd_rn(__fadd_rn(r[0], r[1]), __fadd_rn(r[2], r[3])),
        __fadd_rn(__fadd_rn(r[4], r[5]), __fadd_rn(r[6], r[7])));
  }
}

// tmp_h[code][j] = seqFMA_d(cb@in_w) + in_b ; P[code][j] = seqFMA_i(tmp_h@cc_w0)
// P is the h0 chain's partial accumulator after the first 256 terms.
__global__ __launch_bounds__(256) void k_codeh(const float* __restrict__ cb,
                                               const float* __restrict__ in_w,
                                               const float* __restrict__ in_b,
                                               const float* __restrict__ cc_w,
                                               float* __restrict__ tmp_h,
                                               float* __restrict__ P) {
  __shared__ float row[128];
  __shared__ float th[256];
  const int code = blockIdx.x;
  const int t = threadIdx.x;
  if (t < 128) row[t] = cb[code * 128 + t];
  __syncthreads();
  float a = 0.f;
  for (int d = 0; d < 128; ++d) a = __builtin_fmaf(row[d], in_w[d * 256 + t], a);
  const float thv = __fadd_rn(a, in_b[t]);
  tmp_h[code * 256 + t] = thv;
  th[t] = thv;
  __syncthreads();
  float p = 0.f;
  for (int i = 0; i < 256; i += 4) {
    const float w0 = cc_w[(i + 0) * 256 + t], w1 = cc_w[(i + 1) * 256 + t];
    const float w2 = cc_w[(i + 2) * 256 + t], w3 = cc_w[(i + 3) * 256 + t];
    p = __builtin_fmaf(th[i + 0], w0, p);
    p = __builtin_fmaf(th[i + 1], w1, p);
    p = __builtin_fmaf(th[i + 2], w2, p);
    p = __builtin_fmaf(th[i + 3], w3, p);
  }
  P[code * 256 + t] = p;
}

// Wcat[256][640] = [w1_0 | w1_1 | out_w]
__global__ __launch_bounds__(256) void k_pack(const float* __restrict__ rb_w1,
                                              const float* __restrict__ out_w,
                                              float* __restrict__ Wcat) {
  const int i = blockIdx.x;  // 256 rows
  const int t = threadIdx.x;
  Wcat[i * 640 + t] = rb_w1[i * 256 + t];
  Wcat[i * 640 + 256 + t] = rb_w1[65536 + i * 256 + t];
  if (t < 128) Wcat[i * 640 + 512 + t] = out_w[i * 128 + t];
}

// cvec[640] = cc_b @ Wcat + [b1_0 | bias2v | biasDv]  (prescreen-only)
__global__ __launch_bounds__(256) void k_biasprep(
    const float* __restrict__ rb_b1, const float* __restrict__ rb_b2,
    const float* __restrict__ rb_w1, const float* __restrict__ out_w,
    const float* __restrict__ out_b, const float* __restrict__ cc_b,
    const float* __restrict__ Wcat, float* __restrict__ cvec) {
  const int t = threadIdx.x;
  const float* w11 = rb_w1 + 65536;
  float b2v = rb_b1[256 + t];
  for (int i = 0; i < 256; ++i) b2v += rb_b2[i] * w11[i * 256 + t];
  float c0 = rb_b1[t], c1 = b2v;
  for (int i = 0; i < 256; ++i) {
    const float cbi = cc_b[i];
    c0 += cbi * Wcat[i * 640 + t];
    c1 += cbi * Wcat[i * 640 + 256 + t];
  }
  cvec[t] = c0;
  cvec[256 + t] = c1;
  if (t < 128) {
    float bDv = out_b[t];
    for (int i = 0; i < 256; ++i)
      bDv += (rb_b2[i] + rb_b2[256 + i]) * out_w[i * 128 + t];
    float c2 = bDv;
    for (int i = 0; i < 256; ++i) c2 += cc_b[i] * Wcat[i * 640 + 512 + t];
    cvec[512 + t] = c2;
  }
}

// pack W21/V1/V2 (f32) into bf16 MFMA B-fragment layout
__global__ __launch_bounds__(256) void k_wfrag(
    const float* __restrict__ W21, const float* __restrict__ V1,
    const float* __restrict__ V2, u16* __restrict__ W21f,
    u16* __restrict__ V1f, u16* __restrict__ V2f) {
  const int gid = blockIdx.x * 256 + threadIdx.x;  // 16384 total
  const int l = gid & 63;
  const int grp = gid >> 6;  // [0,256)
  const int kq = (l >> 4) * 8;
  const int nn = l & 15;
  if (grp < 128) {
    const int kt = grp >> 4, nt = grp & 15;
    u16* dst = W21f + (size_t)(grp * 64 + l) * 8;
#pragma unroll
    for (int j = 0; j < 8; ++j)
      dst[j] = f2bf(W21[(kt * 32 + kq + j) * 256 + nt * 16 + nn]);
  } else if (grp < 192) {
    const int g2 = grp - 128, kt = g2 >> 3, nt = g2 & 7;
    u16* dst = V1f + (size_t)(g2 * 64 + l) * 8;
#pragma unroll
    for (int j = 0; j < 8; ++j)
      dst[j] = f2bf(V1[(kt * 32 + kq + j) * 128 + nt * 16 + nn]);
  } else {
    const int g2 = grp - 192, kt = g2 >> 3, nt = g2 & 7;
    u16* dst = V2f + (size_t)(g2 * 64 + l) * 8;
#pragma unroll
    for (int j = 0; j < 8; ++j)
      dst[j] = f2bf(V2[(kt * 32 + kq + j) * 128 + nt * 16 + nn]);
  }
}

// ---------------- generic f32 GEMM (small prescreen preps) ----------------
__global__ __launch_bounds__(256, 4) void gemm_f32(
    const float* __restrict__ Am, const float* __restrict__ Bm,
    float* __restrict__ Cm, const int Mi, const int Ni, const int Ki,
    const float* __restrict__ bias, const float* __restrict__ addm) {
  __shared__ float As[16][68];
  __shared__ float Bs[16][68];
  const int m0 = blockIdx.x * 64, n0 = blockIdx.y * 64;
  const int t = threadIdx.x;
  const int tm = (t & 15) * 4, tn = (t >> 4) * 4;
  float acc[4][4] = {};
  for (int k0 = 0; k0 < Ki; k0 += 16) {
    {
      const int row = t >> 2, q = t & 3;
      const float4 a4 = *(const float4*)(Am + (size_t)(m0 + row) * Ki + k0 + q * 4);
      As[q * 4 + 0][row] = a4.x; As[q * 4 + 1][row] = a4.y;
      As[q * 4 + 2][row] = a4.z; As[q * 4 + 3][row] = a4.w;
      const int kk = t >> 4, n4 = t & 15;
      *(float4*)&Bs[kk][n4 * 4] =
          *(const float4*)(Bm + (size_t)(k0 + kk) * Ni + n0 + n4 * 4);
    }
    __syncthreads();
#pragma unroll
    for (int kk = 0; kk < 16; ++kk) {
      const float4 av = *(const float4*)&As[kk][tm];
      const float4 bv = *(const float4*)&Bs[kk][tn];
      const float aa[4] = {av.x, av.y, av.z, av.w};
      const float bb[4] = {bv.x, bv.y, bv.z, bv.w};
#pragma unroll
      for (int i = 0; i < 4; ++i)
#pragma unroll
        for (int j = 0; j < 4; ++j) acc[i][j] += aa[i] * bb[j];
    }
    __syncthreads();
  }
#pragma unroll
  for (int i = 0; i < 4; ++i) {
    const int m = m0 + tm + i;
#pragma unroll
    for (int j = 0; j < 4; ++j) {
      const int n = n0 + tn + j;
      float v = acc[i][j];
      if (bias) v += bias[n];
      if (addm) v += addm[(size_t)m * Ni + n];
      Cm[(size_t)m * Ni + n] = v;
    }
  }
}

// ---------------- scatter GEMM: E = A[M,K]@B[K,640] (+bias) -> O1|O2|O3(+add3) ----------------
__global__ __launch_bounds__(256, 4) void gemm_scatter(
    const float* __restrict__ Am, const float* __restrict__ Bm, const int Mi,
    const int Ki, const float* __restrict__ bias,
    const float* __restrict__ add3, float* __restrict__ O1,
    float* __restrict__ O2, float* __restrict__ O3) {
  __shared__ float As[16][68];
  __shared__ float Bs[16][68];
  const int m0 = blockIdx.x * 64, n0 = blockIdx.y * 64;
  const int t = threadIdx.x;
  const int tm = (t & 15) * 4, tn = (t >> 4) * 4;
  float acc[4][4] = {};
  for (int k0 = 0; k0 < Ki; k0 += 16) {
    {
      const int row = t >> 2, q = t & 3;
      const float4 a4 = *(const float4*)(Am + (size_t)(m0 + row) * Ki + k0 + q * 4);
      As[q * 4 + 0][row] = a4.x; As[q * 4 + 1][row] = a4.y;
      As[q * 4 + 2][row] = a4.z; As[q * 4 + 3][row] = a4.w;
      const int kk = t >> 4, n4 = t & 15;
      *(float4*)&Bs[kk][n4 * 4] =
          *(const float4*)(Bm + (size_t)(k0 + kk) * 640 + n0 + n4 * 4);
    }
    __syncthreads();
#pragma unroll
    for (int kk = 0; kk < 16; ++kk) {
      const float4 av = *(const float4*)&As[kk][tm];
      const float4 bv = *(const float4*)&Bs[kk][tn];
      const float aa[4] = {av.x, av.y, av.z, av.w};
      const float bb[4] = {bv.x, bv.y, bv.z, bv.w};
#pragma unroll
      for (int i = 0; i < 4; ++i)
#pragma unroll
        for (int j = 0; j < 4; ++j) acc[i][j] += aa[i] * bb[j];
    }
    __syncthreads();
  }
#pragma unroll
  for (int i = 0; i < 4; ++i) {
    const int m = m0 + tm + i;
#pragma unroll
    for (int j = 0; j < 4; ++j) {
      const int n = n0 + tn + j;
      float v = acc[i][j];
      if (bias) v += bias[n];
      if (n < 256) {
        O1[(size_t)m * 256 + n] = v;
      } else if (n < 512) {
        O2[(size_t)m * 256 + n - 256] = v;
      } else {
        if (add3) v += add3[(size_t)m * 128 + n - 512];
        O3[(size_t)m * 128 + n - 512] = v;
      }
    }
  }
}

// ---------------- stage 1: bitwise-np f32 dists + stable top-32 ----------------
// xt computed inline (single f32 sub, as reference).
__global__ __launch_bounds__(512, 2) void k_stage1(
    const float* __restrict__ x, const float* __restrict__ xhat,
    const float* __restrict__ cbT, const float* __restrict__ cb_sq,
    int* __restrict__ topc) {
  __shared__ u32 distL[4 * 4096];  // 64 KB
  __shared__ float xtL[512];
  const int r0 = blockIdx.x * 4;
  const int t = threadIdx.x;
  {
    const int rr = r0 + (t >> 7), d = t & 127;
    xtL[t] = __fsub_rn(x[(rr >> 4) * 128 + d], xhat[rr * 128 + d]);
  }
  __syncthreads();
  {
    const int k0 = t * 8;
    float acc[4][8] = {};
    for (int d = 0; d < 128; ++d) {
      const float4 c0 = *(const float4*)&cbT[d * 4096 + k0];
      const float4 c1 = *(const float4*)&cbT[d * 4096 + k0 + 4];
      const float cv[8] = {c0.x, c0.y, c0.z, c0.w, c1.x, c1.y, c1.z, c1.w};
      const float x0 = xtL[d], x1 = xtL[128 + d], x2 = xtL[256 + d],
                  x3 = xtL[384 + d];
#pragma unroll
      for (int j = 0; j < 8; ++j) {
        acc[0][j] = __builtin_fmaf(x0, cv[j], acc[0][j]);
        acc[1][j] = __builtin_fmaf(x1, cv[j], acc[1][j]);
        acc[2][j] = __builtin_fmaf(x2, cv[j], acc[2][j]);
        acc[3][j] = __builtin_fmaf(x3, cv[j], acc[3][j]);
      }
    }
    const float4 s0 = *(const float4*)&cb_sq[k0];
    const float4 s1 = *(const float4*)&cb_sq[k0 + 4];
    const float cs[8] = {s0.x, s0.y, s0.z, s0.w, s1.x, s1.y, s1.z, s1.w};
#pragma unroll
    for (int rr = 0; rr < 4; ++rr)
#pragma unroll
      for (int j = 0; j < 8; ++j)
        distL[rr * 4096 + k0 + j] =
            ordu(__fsub_rn(cs[j], __fmul_rn(2.0f, acc[rr][j])));
  }
  __syncthreads();
  const int w = t >> 6, lane = t & 63;
  if (w < 4) {
    u32* dr = distL + w * 4096;
    u64 m1 = ~0ull, m2 = ~0ull;
    for (int e = 0; e < 64; ++e) {
      const int idx = e * 64 + lane;
      const u64 key = ((u64)dr[idx] << 32) | (u32)idx;
      if (key < m1) { m2 = m1; m1 = key; } else if (key < m2) { m2 = key; }
    }
    bool have2 = true;
    for (int it = 0; it < 32; ++it) {
      u64 g = m1;
#pragma unroll
      for (int sh = 1; sh < 64; sh <<= 1) {
        const u64 o = __shfl_xor(g, sh);
        g = (o < g) ? o : g;
      }
      const int bi = (int)(g & 0xFFFFFFFFu);
      if (lane == 0) topc[(r0 + w) * 32 + it] = bi;
      if ((bi & 63) == lane) {
        dr[bi] = 0xFFFFFFFFu;
        if (have2) {
          m1 = m2; m2 = ~0ull; have2 = false;
        } else {
          m1 = m2 = ~0ull;
          for (int e = 0; e < 64; ++e) {
            const int idx = e * 64 + lane;
            const u64 key = ((u64)dr[idx] << 32) | (u32)idx;
            if (key < m1) { m2 = m1; m1 = key; } else if (key < m2) { m2 = key; }
          }
          have2 = true;
        }
      }
    }
  }
}

// ---------------- stage 2: MFMA bf16 prescreen ----------------
__global__ __launch_bounds__(256, 4) void k_mlp(
    const int* __restrict__ topc, const float* __restrict__ A1,
    const float* __restrict__ A2, const float* __restrict__ B1,
    const float* __restrict__ B2, const float* __restrict__ Dc,
    const float* __restrict__ Dr, const u16* __restrict__ W21f,
    const u16* __restrict__ V1f, const u16* __restrict__ V2f,
    const float* __restrict__ xhat, const float* __restrict__ x,
    float* __restrict__ d2g) {
  __shared__ __align__(16) u16 abuf[32 * 264];  // 16.5 KB, r1 then r2
  __shared__ float B1r[256];
  __shared__ int codesL[32];
  __shared__ float d2red[32][4];

  const int tt = threadIdx.x;
  const int br = blockIdx.x;  // beam row
  const int bb = br >> 4;
  const int w = tt >> 6, l = tt & 63;

  B1r[tt] = B1[br * 256 + tt];
  if (tt < 32) codesL[tt] = topc[br * 32 + tt];
  __syncthreads();

  {
    const int c = tt & 31, g = tt >> 5;
    const int code = codesL[c];
    const float4* A14 = (const float4*)(A1 + code * 256 + g * 32);
    u32* dst = (u32*)(abuf + c * 264 + g * 32);
#pragma unroll
    for (int e4 = 0; e4 < 8; ++e4) {
      const float4 a = A14[e4];
      const int i = g * 32 + e4 * 4;
      const u32 p0 = (u32)f2bf(fmaxf(a.x + B1r[i], 0.f)) |
                     ((u32)f2bf(fmaxf(a.y + B1r[i + 1], 0.f)) << 16);
      const u32 p1 = (u32)f2bf(fmaxf(a.z + B1r[i + 2], 0.f)) |
                     ((u32)f2bf(fmaxf(a.w + B1r[i + 3], 0.f)) << 16);
      dst[e4 * 2] = p0;
      dst[e4 * 2 + 1] = p1;
    }
  }
  __syncthreads();

  const int arow = l & 15;
  const int kq = (l >> 4) * 8;
  const s16x8* wf = (const s16x8*)W21f;
  const s16x8* v1f = (const s16x8*)V1f;
  const s16x8* v2f = (const s16x8*)V2f;
  const f32x4 zero4 = {0.f, 0.f, 0.f, 0.f};

  f32x4 accf[2][4];
#pragma unroll
  for (int mt = 0; mt < 2; ++mt)
#pragma unroll
    for (int ntl = 0; ntl < 4; ++ntl) accf[mt][ntl] = zero4;
  for (int kt = 0; kt < 8; ++kt) {
    const s16x8 a0 = *(const s16x8*)(abuf + arow * 264 + kt * 32 + kq);
    const s16x8 a1 = *(const s16x8*)(abuf + (16 + arow) * 264 + kt * 32 + kq);
#pragma unroll
    for (int ntl = 0; ntl < 4; ++ntl) {
      const s16x8 b = wf[(kt * 16 + w * 4 + ntl) * 64 + l];
      accf[0][ntl] =
          __builtin_amdgcn_mfma_f32_16x16x32_bf16(a0, b, accf[0][ntl], 0, 0, 0);
      accf[1][ntl] =
          __builtin_amdgcn_mfma_f32_16x16x32_bf16(a1, b, accf[1][ntl], 0, 0, 0);
    }
  }

  f32x4 acc2f[2][2];
#pragma unroll
  for (int mt = 0; mt < 2; ++mt)
#pragma unroll
    for (int ntl = 0; ntl < 2; ++ntl) acc2f[mt][ntl] = zero4;
  for (int kt = 0; kt < 8; ++kt) {
    const s16x8 a0 = *(const s16x8*)(abuf + arow * 264 + kt * 32 + kq);
    const s16x8 a1 = *(const s16x8*)(abuf + (16 + arow) * 264 + kt * 32 + kq);
#pragma unroll
    for (int ntl = 0; ntl < 2; ++ntl) {
      const s16x8 b = v1f[(kt * 8 + w * 2 + ntl) * 64 + l];
      acc2f[0][ntl] = __builtin_amdgcn_mfma_f32_16x16x32_bf16(
          a0, b, acc2f[0][ntl], 0, 0, 0);
      acc2f[1][ntl] = __builtin_amdgcn_mfma_f32_16x16x32_bf16(
          a1, b, acc2f[1][ntl], 0, 0, 0);
    }
  }

  u16 r2v[2][4][4];
#pragma unroll
  for (int mt = 0; mt < 2; ++mt)
#pragma unroll
    for (int ntl = 0; ntl < 4; ++ntl) {
      const int n = w * 64 + ntl * 16 + arow;
      const float b2 = B2[br * 256 + n];
      const f32x4 cf = accf[mt][ntl];
#pragma unroll
      for (int rg = 0; rg < 4; ++rg) {
        const int m = mt * 16 + (l >> 4) * 4 + rg;
        const float a2 = A2[codesL[m] * 256 + n];
        r2v[mt][ntl][rg] = f2bf(fmaxf(cf[rg] + a2 + b2, 0.f));
      }
    }
  __syncthreads();
#pragma unroll
  for (int mt = 0; mt < 2; ++mt)
#pragma unroll
    for (int ntl = 0; ntl < 4; ++ntl) {
      const int n = w * 64 + ntl * 16 + arow;
#pragma unroll
      for (int rg = 0; rg < 4; ++rg) {
        const int m = mt * 16 + (l >> 4) * 4 + rg;
        abuf[m * 264 + n] = r2v[mt][ntl][rg];
      }
    }
  __syncthreads();

  for (int kt = 0; kt < 8; ++kt) {
    const s16x8 a0 = *(const s16x8*)(abuf + arow * 264 + kt * 32 + kq);
    const s16x8 a1 = *(const s16x8*)(abuf + (16 + arow) * 264 + kt * 32 + kq);
#pragma unroll
    for (int ntl = 0; ntl < 2; ++ntl) {
      const s16x8 b = v2f[(kt * 8 + w * 2 + ntl) * 64 + l];
      acc2f[0][ntl] = __builtin_amdgcn_mfma_f32_16x16x32_bf16(
          a0, b, acc2f[0][ntl], 0, 0, 0);
      acc2f[1][ntl] = __builtin_amdgcn_mfma_f32_16x16x32_bf16(
          a1, b, acc2f[1][ntl], 0, 0, 0);
    }
  }

  float sm[2][4];
#pragma unroll
  for (int mt = 0; mt < 2; ++mt)
#pragma unroll
    for (int rg = 0; rg < 4; ++rg) sm[mt][rg] = 0.f;
#pragma unroll
  for (int ntl = 0; ntl < 2; ++ntl) {
    const int d = w * 32 + ntl * 16 + arow;
    const float dr = Dr[br * 128 + d];
    const float xh = xhat[br * 128 + d];
    const float xq = x[bb * 128 + d];
#pragma unroll
    for (int mt = 0; mt < 2; ++mt) {
      const f32x4 cf = acc2f[mt][ntl];
#pragma unroll
      for (int rg = 0; rg < 4; ++rg) {
        const int m = mt * 16 + (l >> 4) * 4 + rg;
        const float cand = cf[rg] + Dc[codesL[m] * 128 + d] + dr + xh;
        sm[mt][rg] += cand * cand - 2.f * xq * cand;
      }
    }
  }
#pragma unroll
  for (int mt = 0; mt < 2; ++mt)
#pragma unroll
    for (int rg = 0; rg < 4; ++rg) {
      float s = sm[mt][rg];
      s += __shfl_xor(s, 1);
      s += __shfl_xor(s, 2);
      s += __shfl_xor(s, 4);
      s += __shfl_xor(s, 8);
      if (arow == 0) d2red[mt * 16 + (l >> 4) * 4 + rg][w] = s;
    }
  __syncthreads();
  if (tt < 32)
    d2g[bb * 512 + (br & 15) * 32 + tt] =
        d2red[tt][0] + d2red[tt][1] + d2red[tt][2] + d2red[tt][3];
}

// ---------------- stage 3a: prescreen top-32 per base query ----------------
__global__ __launch_bounds__(64, 1) void k_sel32(const float* __restrict__ d2g,
                                                 int* __restrict__ sel32) {
  __shared__ u32 d2u[512];
  const int bb = blockIdx.x;
  const int t = threadIdx.x;
  for (int i = t; i < 512; i += 64) d2u[i] = ordu(d2g[bb * 512 + i]);
  __syncthreads();
  for (int it = 0; it < 32; ++it) {
    u64 m = ~0ull;
#pragma unroll
    for (int e = 0; e < 8; ++e) {
      const int idx = e * 64 + t;
      const u64 key = ((u64)d2u[idx] << 32) | (u32)idx;
      m = (key < m) ? key : m;
    }
#pragma unroll
    for (int sh = 1; sh < 64; sh <<= 1) {
      const u64 o = __shfl_xor(m, sh);
      m = (o < m) ? o : m;
    }
    const int s = (int)(m & 0xFFFFFFFFu);
    if ((s & 63) == t) d2u[s] = 0xFFFFFFFFu;
    if (t == 0) sel32[bb * 32 + it] = s;
  }
}

// ---------------- stage 3b: np-emulated rescore of top-32 ----------------
// seq-FMA over k ascending per accumulator (bitwise-np); h0 prefix from P.
__global__ __launch_bounds__(256, 5) void k_rescore(
    const int* __restrict__ sel32, const int* __restrict__ topc,
    const float* __restrict__ P, const float* __restrict__ cb,
    const float* __restrict__ xhat, const float* __restrict__ x,
    const float* __restrict__ cc_w, const float* __restrict__ cc_b,
    const float* __restrict__ rb_w1, const float* __restrict__ rb_b1,
    const float* __restrict__ rb_w2, const float* __restrict__ rb_b2,
    const float* __restrict__ out_w, const float* __restrict__ out_b,
    float* __restrict__ d2r, float* __restrict__ candv) {
  __shared__ float A_[8][256], B_[8][256], C_[8][256];
  __shared__ float xhL[8][128], xqL[128];
  __shared__ int codeL[8], rowL[8];
  const int bb = blockIdx.x >> 2;
  const int j0 = (blockIdx.x & 3) * 8;
  const int t = threadIdx.x;
  if (t < 8) {
    const int s = sel32[bb * 32 + j0 + t];
    rowL[t] = bb * 16 + (s >> 5);
    codeL[t] = topc[(bb * 16 + (s >> 5)) * 32 + (s & 31)];
  }
  if (t < 128) xqL[t] = x[bb * 128 + t];
  __syncthreads();
  for (int idx = t; idx < 1024; idx += 256) {
    const int c = idx >> 7, d = idx & 127;
    xhL[c][d] = xhat[rowL[c] * 128 + d];
  }
  __syncthreads();
  // h0: acc starts at P[code] (chain value after tmp_h part), continue xhat part
  {
    float acc[8];
#pragma unroll
    for (int c = 0; c < 8; ++c) acc[c] = P[codeL[c] * 256 + t];
    for (int d = 0; d < 128; d += 4) {
      const float w0 = cc_w[(256 + d + 0) * 256 + t];
      const float w1 = cc_w[(256 + d + 1) * 256 + t];
      const float w2 = cc_w[(256 + d + 2) * 256 + t];
      const float w3 = cc_w[(256 + d + 3) * 256 + t];
#pragma unroll
      for (int c = 0; c < 8; ++c) {
        const float4 h = *(const float4*)&xhL[c][d];
        acc[c] = __builtin_fmaf(h.x, w0, acc[c]);
        acc[c] = __builtin_fmaf(h.y, w1, acc[c]);
        acc[c] = __builtin_fmaf(h.z, w2, acc[c]);
        acc[c] = __builtin_fmaf(h.w, w3, acc[c]);
      }
    }
    const float b = cc_b[t];
#pragma unroll
    for (int c = 0; c < 8; ++c) B_[c][t] = __fadd_rn(acc[c], b);
  }
  __syncthreads();
  // r1 = relu(seqFMA(h0 @ w1_0) + b1_0) -> C_
  {
    float acc[8] = {};
    for (int i = 0; i < 256; i += 4) {
      const float w0 = rb_w1[(i + 0) * 256 + t], w1 = rb_w1[(i + 1) * 256 + t];
      const float w2 = rb_w1[(i + 2) * 256 + t], w3 = rb_w1[(i + 3) * 256 + t];
#pragma unroll
      for (int c = 0; c < 8; ++c) {
        const float4 h = *(const float4*)&B_[c][i];
        acc[c] = __builtin_fmaf(h.x, w0, acc[c]);
        acc[c] = __builtin_fmaf(h.y, w1, acc[c]);
        acc[c] = __builtin_fmaf(h.z, w2, acc[c]);
        acc[c] = __builtin_fmaf(h.w, w3, acc[c]);
      }
    }
    const float b = rb_b1[t];
#pragma unroll
    for (int c = 0; c < 8; ++c) C_[c][t] = fmaxf(__fadd_rn(acc[c], b), 0.f);
  }
  __syncthreads();
  // h1 = (h0 + seqFMA(r1 @ w2_0)) + b2_0 -> A_
  {
    float acc[8] = {};
    for (int i = 0; i < 256; i += 4) {
      const float w0 = rb_w2[(i + 0) * 256 + t], w1 = rb_w2[(i + 1) * 256 + t];
      const float w2 = rb_w2[(i + 2) * 256 + t], w3 = rb_w2[(i + 3) * 256 + t];
#pragma unroll
      for (int c = 0; c < 8; ++c) {
        const float4 h = *(const float4*)&C_[c][i];
        acc[c] = __builtin_fmaf(h.x, w0, acc[c]);
        acc[c] = __builtin_fmaf(h.y, w1, acc[c]);
        acc[c] = __builtin_fmaf(h.z, w2, acc[c]);
        acc[c] = __builtin_fmaf(h.w, w3, acc[c]);
      }
    }
    const float b = rb_b2[t];
#pragma unroll
    for (int c = 0; c < 8; ++c)
      A_[c][t] = __fadd_rn(__fadd_rn(B_[c][t], acc[c]), b);
  }
  __syncthreads();
  // r2 = relu(seqFMA(h1 @ w1_1) + b1_1) -> B_
  {
    float acc[8] = {};
    const float* w11 = rb_w1 + 65536;
    for (int i = 0; i < 256; i += 4) {
      const float w0 = w11[(i + 0) * 256 + t], w1 = w11[(i + 1) * 256 + t];
      const float w2 = w11[(i + 2) * 256 + t], w3 = w11[(i + 3) * 256 + t];
#pragma unroll
      for (int c = 0; c < 8; ++c) {
        const float4 h = *(const float4*)&A_[c][i];
        acc[c] = __builtin_fmaf(h.x, w0, acc[c]);
        acc[c] = __builtin_fmaf(h.y, w1, acc[c]);
        acc[c] = __builtin_fmaf(h.z, w2, acc[c]);
        acc[c] = __builtin_fmaf(h.w, w3, acc[c]);
      }
    }
    const float b = rb_b1[256 + t];
#pragma unroll
    for (int c = 0; c < 8; ++c) B_[c][t] = fmaxf(__fadd_rn(acc[c], b), 0.f);
  }
  __syncthreads();
  // h2 = (h1 + seqFMA(r2 @ w2_1)) + b2_1 -> C_
  {
    float acc[8] = {};
    const float* w21 = rb_w2 + 65536;
    for (int i = 0; i < 256; i += 4) {
      const float w0 = w21[(i + 0) * 256 + t], w1 = w21[(i + 1) * 256 + t];
      const float w2 = w21[(i + 2) * 256 + t], w3 = w21[(i + 3) * 256 + t];
#pragma unroll
      for (int c = 0; c < 8; ++c) {
        const float4 h = *(const float4*)&B_[c][i];
        acc[c] = __builtin_fmaf(h.x, w0, acc[c]);
        acc[c] = __builtin_fmaf(h.y, w1, acc[c]);
        acc[c] = __builtin_fmaf(h.z, w2, acc[c]);
        acc[c] = __builtin_fmaf(h.w, w3, acc[c]);
      }
    }
    const float b = rb_b2[256 + t];
#pragma unroll
    for (int c = 0; c < 8; ++c)
      C_[c][t] = __fadd_rn(__fadd_rn(A_[c][t], acc[c]), b);
  }
  __syncthreads();
  // cand = ((seqFMA(h2@out_w) + out_b) + cw_in) + xhat -> B_ (reused)
  if (t < 128) {
    float acc[8] = {};
    for (int i = 0; i < 256; i += 4) {
      const float w0 = out_w[(i + 0) * 128 + t], w1 = out_w[(i + 1) * 128 + t];
      const float w2 = out_w[(i + 2) * 128 + t], w3 = out_w[(i + 3) * 128 + t];
#pragma unroll
      for (int c = 0; c < 8; ++c) {
        const float4 h = *(const float4*)&C_[c][i];
        acc[c] = __builtin_fmaf(h.x, w0, acc[c]);
        acc[c] = __builtin_fmaf(h.y, w1, acc[c]);
        acc[c] = __builtin_fmaf(h.z, w2, acc[c]);
        acc[c] = __builtin_fmaf(h.w, w3, acc[c]);
      }
    }
    const float ob = out_b[t];
#pragma unroll
    for (int c = 0; c < 8; ++c) {
      const float cbv = cb[codeL[c] * 128 + t];
      const float cw_ = __fadd_rn(__fadd_rn(acc[c], ob), cbv);
      const float cand = __fadd_rn(cw_, xhL[c][t]);
      B_[c][t] = cand;
      candv[(bb * 32 + j0 + c) * 128 + t] = cand;
    }
  }
  __syncthreads();
  if (t < 8) {
    float r[8];
#pragma unroll
    for (int j = 0; j < 8; ++j) {
      const float v = B_[t][j];
      r[j] = __fmul_rn(v, v);
    }
    for (int i = 8; i < 128; i += 8) {
#pragma unroll
      for (int j = 0; j < 8; ++j) {
        const float v = B_[t][i + j];
        r[j] = __fadd_rn(r[j], __fmul_rn(v, v));
      }
    }
    const float s1f = __fadd_rn(
        __fadd_rn(__fadd_rn(r[0], r[1]), __fadd_rn(r[2], r[3])),
        __fadd_rn(__fadd_rn(r[4], r[5]), __fadd_rn(r[6], r[7])));
    double s2 = 0.0;
    for (int d = 0; d < 128; ++d)
      s2 += (double)xqL[d] * (double)B_[t][d];
    const float s2f = (float)s2;
    d2r[bb * 32 + j0 + t] = __fsub_rn(s1f, __fmul_rn(2.0f, s2f));
  }
}

// ---------------- stage 3c/4: stable top-16 by f32 d2 ----------------
__global__ __launch_bounds__(64, 1) void k_final(
    const float* __restrict__ d2r, const int* __restrict__ sel32,
    const int* __restrict__ topc, const int* __restrict__ codes_in,
    const float* __restrict__ candv, float* __restrict__ out) {
  __shared__ u32 winLo[16];
  const int bb = blockIdx.x;
  const int t = threadIdx.x;
  u64 key = ~0ull;
  if (t < 32) {
    const u32 s = (u32)sel32[bb * 32 + t];
    key = ((u64)ordu(d2r[bb * 32 + t]) << 32) | (s << 5) | (u32)t;
  }
  for (int it = 0; it < 16; ++it) {
    u64 m = key;
#pragma unroll
    for (int sh = 1; sh < 64; sh <<= 1) {
      const u64 o = __shfl_xor(m, sh);
      m = (o < m) ? o : m;
    }
    if (key == m) key = ~0ull;
    if (t == 0) winLo[it] = (u32)(m & 0xFFFFFFFFu);
  }
  __syncthreads();
  if (t < 16) {
    const u32 lo = winLo[t];
    const int s = (int)((lo >> 5) & 511u);
    const int f = s >> 5;
    const int code = topc[(bb * 16 + f) * 32 + (s & 31)];
    float* oc = out + 512 * 16 * 128;
    oc[bb * 16 + t] = (float)codes_in[bb * 16 + f];
    oc[8192 + bb * 16 + t] = (float)codes_in[8192 + bb * 16 + f];
    oc[16384 + bb * 16 + t] = (float)code;
  }
  __syncthreads();
  for (int idx = t; idx < 2048; idx += 64) {
    const int w_ = idx >> 7, d = idx & 127;
    const int j = (int)(winLo[w_] & 31u);
    out[(bb * 16 + w_) * 128 + d] = candv[(bb * 32 + j) * 128 + d];
  }
}

// ---------------- launch ----------------
extern "C" void kernel_launch(void* const* d_in, const int* in_sizes, int n_in,
                              void* d_out, int out_size, void* d_ws,
                              size_t ws_size, hipStream_t stream) {
  const float* x = (const float*)d_in[0];
  const float* xhat = (const float*)d_in[1];
  const int* codes = (const int*)d_in[2];
  const float* cb = (const float*)d_in[3];
  const float* cbrq = (const float*)d_in[4];
  const float* in_w = (const float*)d_in[5];
  const float* in_b = (const float*)d_in[6];
  const float* cc_w = (const float*)d_in[7];
  const float* cc_b = (const float*)d_in[8];
  const float* rb_w1 = (const float*)d_in[9];
  const float* rb_b1 = (const float*)d_in[10];
  const float* rb_w2 = (const float*)d_in[11];
  const float* rb_b2 = (const float*)d_in[12];
  const float* out_w = (const float*)d_in[13];
  const float* out_b = (const float*)d_in[14];
  float* out = (float*)d_out;

  float* ws = (float*)d_ws;
  size_t o = 0;
  float* cb_sq = ws + o; o += 4096;
  float* P = ws + o;     o += (size_t)4096 * 256;
  float* cbT = ws + o;   const size_t cbT_off = o; o += (size_t)128 * 4096;
  float* tmp_h = ws + o; o += (size_t)4096 * 256;
  float* Wcat = ws + o;  o += (size_t)256 * 640;
  float* M_A = ws + o;   o += (size_t)256 * 640;
  float* M_B = ws + o;   o += (size_t)128 * 640;
  float* cvec = ws + o;  o += 640;
  float* A1 = ws + o;    o += (size_t)4096 * 256;
  float* A2 = ws + o;    o += (size_t)4096 * 256;
  float* Dc = ws + o;    o += (size_t)4096 * 128;
  float* B1 = ws + o;    o += (size_t)8192 * 256;
  float* B2 = ws + o;    o += (size_t)8192 * 256;
  float* Dr = ws + o;    o += (size_t)8192 * 128;
  float* W21 = ws + o;   o += 65536;
  float* V1 = ws + o;    o += 32768;
  float* V2 = ws + o;    o += 32768;
  int* topc = (int*)(ws + o); o += 262144;
  float* d2g = ws + o;   o += 262144;
  u16* W21f = (u16*)(ws + o); o += 32768;  // 65536 bf16
  u16* V1f = (u16*)(ws + o);  o += 16384;  // 32768 bf16
  u16* V2f = (u16*)(ws + o);  o += 16384;
  float* candv = ws + o; o += (size_t)16384 * 128;
  float* d2r = ws + cbT_off;                 // cbT dead after k_stage1
  int* sel32 = (int*)(ws + cbT_off + 16384);

  k_cbrqT<<<dim3(128), dim3(256), 0, stream>>>(cbrq, cbT, cb_sq);
  k_codeh<<<dim3(4096), dim3(256), 0, stream>>>(cb, in_w, in_b, cc_w, tmp_h, P);
  k_pack<<<dim3(256), dim3(256), 0, stream>>>(rb_w1, out_w, Wcat);
  k_biasprep<<<dim3(1), dim3(256), 0, stream>>>(rb_b1, rb_b2, rb_w1, out_w,
                                                out_b, cc_b, Wcat, cvec);
  // M_A = cc_w0 @ Wcat ; M_B = cc_w1 @ Wcat
  gemm_f32<<<dim3(4, 10), dim3(256), 0, stream>>>(cc_w, Wcat, M_A, 256, 640,
                                                  256, nullptr, nullptr);
  gemm_f32<<<dim3(2, 10), dim3(256), 0, stream>>>(cc_w + 256 * 256, Wcat, M_B,
                                                  128, 640, 256, nullptr,
                                                  nullptr);
  // EA = tmp_h @ M_A -> A1 | A2 | Dc(+cb)
  gemm_scatter<<<dim3(64, 10), dim3(256), 0, stream>>>(
      tmp_h, M_A, 4096, 256, nullptr, cb, A1, A2, Dc);
  // EB = xhat @ M_B + cvec -> B1 | B2 | Dr
  gemm_scatter<<<dim3(128, 10), dim3(256), 0, stream>>>(
      xhat, M_B, 8192, 128, cvec, nullptr, B1, B2, Dr);
  // W21 = w2_0@w1_1 ; V1 = w2_0@out_w ; V2 = w2_1@out_w
  gemm_f32<<<dim3(4, 4), dim3(256), 0, stream>>>(rb_w2, rb_w1 + 65536, W21, 256,
                                                 256, 256, nullptr, nullptr);
  gemm_f32<<<dim3(4, 2), dim3(256), 0, stream>>>(rb_w2, out_w, V1, 256, 128,
                                                 256, nullptr, nullptr);
  gemm_f32<<<dim3(4, 2), dim3(256), 0, stream>>>(rb_w2 + 65536, out_w, V2, 256,
                                                 128, 256, nullptr, nullptr);
  k_wfrag<<<dim3(64), dim3(256), 0, stream>>>(W21, V1, V2, W21f, V1f, V2f);

  k_stage1<<<dim3(2048), dim3(512), 0, stream>>>(x, xhat, cbT, cb_sq, topc);
  k_mlp<<<dim3(8192), dim3(256), 0, stream>>>(topc, A1, A2, B1, B2, Dc, Dr,
                                              W21f, V1f, V2f, xhat, x, d2g);
  k_sel32<<<dim3(512), dim3(64), 0, stream>>>(d2g, sel32);
  k_rescore<<<dim3(2048), dim3(256), 0, stream>>>(
      sel32, topc, P, cb, xhat, x, cc_w, cc_b, rb_w1, rb_b1, rb_w2, rb_b2,
      out_w, out_b, d2r, candv);
  k_final<<<dim3(512), dim3(64), 0, stream>>>(d2r, sel32, topc, codes, candv,
                                              out);
  (void)in_sizes; (void)n_in; (void)out_size; (void)ws_size;
}

// Round 16
// 773.019 us; speedup vs baseline: 2.6241x; 1.1363x over previous
//
#include <hip/hip_runtime.h>
#include <float.h>

typedef unsigned int u32;
typedef unsigned long long u64;
typedef unsigned short u16;
typedef __attribute__((ext_vector_type(8))) short s16x8;
typedef __attribute__((ext_vector_type(4))) float f32x4;

// Bb=512, F=16 -> 8192 beam rows, D=128, DH=256, K=4096, A=32, Fo=16, M=2.
// Selection-critical math reproduces numpy's f32 arithmetic bitwise (model):
//  - matmul: per-output sequential f32 FMA over k ascending (sgemm micro-kernel)
//  - np.sum(last axis): 8-accumulator pairwise (n<=128 base case), no FMA
//  - dist/d2 combine: separate f32 mul + f32 sub (ufuncs don't fuse)
//  - all top-k: f32 keys, ties -> lower index (stable, = jax top_k & np)
// Rescore shares the code-dependent h0 prefix via P[code][j]; its thread
// layout is 4cand x 2col (halves LDS b128 traffic; chains bit-identical).
// The factored MLP prescreen (top-32 cut) runs on MFMA bf16.

static __device__ __forceinline__ u32 ordu(float f) {
  u32 u = __float_as_uint(f);
  return u ^ (u32)(((int)u >> 31) | (int)0x80000000);
}
static __device__ __forceinline__ u16 f2bf(float f) {  // RNE f32->bf16
  u32 b = __float_as_uint(f);
  b += 0x7fffu + ((b >> 16) & 1u);
  return (u16)(b >> 16);
}

// 4cand x 2col seq-FMA layer core: for each of 4 candidates, accumulate
// k-ascending over SRC row (stride srcStride) against weight columns jc and
// jc+128 of WBASE (row stride 256). Bitwise identical chain per accumulator.
static __device__ __forceinline__ void layer_fma(
    const float* __restrict__ src, int srcStride, int c0, int jc,
    const float* __restrict__ wbase, int klen, float a0[4], float a1[4]) {
  for (int i = 0; i < klen; i += 4) {
    const float wa0 = wbase[(i + 0) * 256 + jc];
    const float wa1 = wbase[(i + 1) * 256 + jc];
    const float wa2 = wbase[(i + 2) * 256 + jc];
    const float wa3 = wbase[(i + 3) * 256 + jc];
    const float wb0 = wbase[(i + 0) * 256 + jc + 128];
    const float wb1 = wbase[(i + 1) * 256 + jc + 128];
    const float wb2 = wbase[(i + 2) * 256 + jc + 128];
    const float wb3 = wbase[(i + 3) * 256 + jc + 128];
#pragma unroll
    for (int c4 = 0; c4 < 4; ++c4) {
      const float4 h = *(const float4*)&src[(c0 + c4) * srcStride + i];
      a0[c4] = __builtin_fmaf(h.x, wa0, a0[c4]);
      a0[c4] = __builtin_fmaf(h.y, wa1, a0[c4]);
      a0[c4] = __builtin_fmaf(h.z, wa2, a0[c4]);
      a0[c4] = __builtin_fmaf(h.w, wa3, a0[c4]);
      a1[c4] = __builtin_fmaf(h.x, wb0, a1[c4]);
      a1[c4] = __builtin_fmaf(h.y, wb1, a1[c4]);
      a1[c4] = __builtin_fmaf(h.z, wb2, a1[c4]);
      a1[c4] = __builtin_fmaf(h.w, wb3, a1[c4]);
    }
  }
}

// ---------------- mega prep kernel (block-range partitioned) ----------------
__global__ __launch_bounds__(256) void k_prep1(
    const float* __restrict__ cbrq, float* __restrict__ cbT,
    float* __restrict__ cb_sq, const float* __restrict__ cb,
    const float* __restrict__ in_w, const float* __restrict__ in_b,
    const float* __restrict__ cc_w, float* __restrict__ tmp_h,
    float* __restrict__ P, const float* __restrict__ rb_b1,
    const float* __restrict__ rb_b2, const float* __restrict__ rb_w1,
    const float* __restrict__ out_w, const float* __restrict__ out_b,
    const float* __restrict__ cc_b, float* __restrict__ cvec,
    float* __restrict__ Wcat, const float* __restrict__ rb_w2,
    u16* __restrict__ W21f, u16* __restrict__ V1f, u16* __restrict__ V2f) {
  __shared__ float sh[128 * 33];
  const int b = blockIdx.x;
  const int t = threadIdx.x;
  if (b < 128) {
    const int k0 = b * 32;
#pragma unroll
    for (int rep = 0; rep < 16; ++rep) {
      const int flat = rep * 256 + t;
      const int kk = flat >> 7, d = flat & 127;
      sh[d * 33 + kk] = cbrq[(k0 + kk) * 128 + d];
    }
    __syncthreads();
#pragma unroll
    for (int rep = 0; rep < 16; ++rep) {
      const int flat = rep * 256 + t;
      const int d = flat >> 5, kk = flat & 31;
      cbT[d * 4096 + k0 + kk] = sh[d * 33 + kk];
    }
    if (t < 32) {
      float r[8];
#pragma unroll
      for (int j = 0; j < 8; ++j) {
        const float v = sh[j * 33 + t];
        r[j] = __fmul_rn(v, v);
      }
      for (int i = 8; i < 128; i += 8) {
#pragma unroll
        for (int j = 0; j < 8; ++j) {
          const float v = sh[(i + j) * 33 + t];
          r[j] = __fadd_rn(r[j], __fmul_rn(v, v));
        }
      }
      cb_sq[k0 + t] = __fadd_rn(
          __fadd_rn(__fadd_rn(r[0], r[1]), __fadd_rn(r[2], r[3])),
          __fadd_rn(__fadd_rn(r[4], r[5]), __fadd_rn(r[6], r[7])));
    }
  } else if (b < 4224) {
    const int code = b - 128;
    float* row = sh;       // 128
    float* th = sh + 128;  // 256
    if (t < 128) row[t] = cb[code * 128 + t];
    __syncthreads();
    float a = 0.f;
    for (int d = 0; d < 128; ++d)
      a = __builtin_fmaf(row[d], in_w[d * 256 + t], a);
    const float thv = __fadd_rn(a, in_b[t]);
    tmp_h[code * 256 + t] = thv;
    th[t] = thv;
    __syncthreads();
    float p = 0.f;
    for (int i = 0; i < 256; i += 4) {
      const float w0 = cc_w[(i + 0) * 256 + t], w1 = cc_w[(i + 1) * 256 + t];
      const float w2 = cc_w[(i + 2) * 256 + t], w3 = cc_w[(i + 3) * 256 + t];
      p = __builtin_fmaf(th[i + 0], w0, p);
      p = __builtin_fmaf(th[i + 1], w1, p);
      p = __builtin_fmaf(th[i + 2], w2, p);
      p = __builtin_fmaf(th[i + 3], w3, p);
    }
    P[code * 256 + t] = p;
  } else if (b == 4224) {
    const float* w11 = rb_w1 + 65536;
    float b2v = rb_b1[256 + t];
    for (int i = 0; i < 256; ++i) b2v += rb_b2[i] * w11[i * 256 + t];
    float c0 = rb_b1[t], c1 = b2v;
    for (int i = 0; i < 256; ++i) {
      const float cbi = cc_b[i];
      c0 += cbi * rb_w1[i * 256 + t];
      c1 += cbi * w11[i * 256 + t];
    }
    cvec[t] = c0;
    cvec[256 + t] = c1;
    if (t < 128) {
      float bDv = out_b[t];
      for (int i = 0; i < 256; ++i)
        bDv += (rb_b2[i] + rb_b2[256 + i]) * out_w[i * 128 + t];
      float c2 = bDv;
      for (int i = 0; i < 256; ++i) c2 += cc_b[i] * out_w[i * 128 + t];
      cvec[512 + t] = c2;
    }
  } else if (b < 4481) {
    const int i = b - 4225;
    Wcat[i * 640 + t] = rb_w1[i * 256 + t];
    Wcat[i * 640 + 256 + t] = rb_w1[65536 + i * 256 + t];
    if (t < 128) Wcat[i * 640 + 512 + t] = out_w[i * 128 + t];
  } else {
    const int gid = (b - 4481) * 256 + t;  // 16384
    const int l = gid & 63;
    const int grp = gid >> 6;
    const int kq = (l >> 4) * 8;
    const int nn = l & 15;
    float acc[8] = {};
    if (grp < 128) {
      const int kt = grp >> 4, nt = grp & 15;
      const int col = nt * 16 + nn;
      const int r0 = kt * 32 + kq;
      const float* w11 = rb_w1 + 65536;
      for (int k = 0; k < 256; ++k) {
        const float wv = w11[k * 256 + col];
#pragma unroll
        for (int j = 0; j < 8; ++j)
          acc[j] = __builtin_fmaf(rb_w2[(r0 + j) * 256 + k], wv, acc[j]);
      }
      u16* dst = W21f + (size_t)(grp * 64 + l) * 8;
#pragma unroll
      for (int j = 0; j < 8; ++j) dst[j] = f2bf(acc[j]);
    } else if (grp < 192) {
      const int g2 = grp - 128, kt = g2 >> 3, nt = g2 & 7;
      const int col = nt * 16 + nn;
      const int r0 = kt * 32 + kq;
      for (int k = 0; k < 256; ++k) {
        const float wv = out_w[k * 128 + col];
#pragma unroll
        for (int j = 0; j < 8; ++j)
          acc[j] = __builtin_fmaf(rb_w2[(r0 + j) * 256 + k], wv, acc[j]);
      }
      u16* dst = V1f + (size_t)(g2 * 64 + l) * 8;
#pragma unroll
      for (int j = 0; j < 8; ++j) dst[j] = f2bf(acc[j]);
    } else {
      const int g2 = grp - 192, kt = g2 >> 3, nt = g2 & 7;
      const int col = nt * 16 + nn;
      const int r0 = kt * 32 + kq;
      const float* w21 = rb_w2 + 65536;
      for (int k = 0; k < 256; ++k) {
        const float wv = out_w[k * 128 + col];
#pragma unroll
        for (int j = 0; j < 8; ++j)
          acc[j] = __builtin_fmaf(w21[(r0 + j) * 256 + k], wv, acc[j]);
      }
      u16* dst = V2f + (size_t)(g2 * 64 + l) * 8;
#pragma unroll
      for (int j = 0; j < 8; ++j) dst[j] = f2bf(acc[j]);
    }
  }
}

// ---------------- generic f32 GEMM (M_A/M_B only) ----------------
__global__ __launch_bounds__(256, 4) void gemm_f32(
    const float* __restrict__ Am, const float* __restrict__ Bm,
    float* __restrict__ Cm, const int Mi, const int Ni, const int Ki,
    const float* __restrict__ bias, const float* __restrict__ addm) {
  __shared__ float As[16][68];
  __shared__ float Bs[16][68];
  const int m0 = blockIdx.x * 64, n0 = blockIdx.y * 64;
  const int t = threadIdx.x;
  const int tm = (t & 15) * 4, tn = (t >> 4) * 4;
  float acc[4][4] = {};
  for (int k0 = 0; k0 < Ki; k0 += 16) {
    {
      const int row = t >> 2, q = t & 3;
      const float4 a4 = *(const float4*)(Am + (size_t)(m0 + row) * Ki + k0 + q * 4);
      As[q * 4 + 0][row] = a4.x; As[q * 4 + 1][row] = a4.y;
      As[q * 4 + 2][row] = a4.z; As[q * 4 + 3][row] = a4.w;
      const int kk = t >> 4, n4 = t & 15;
      *(float4*)&Bs[kk][n4 * 4] =
          *(const float4*)(Bm + (size_t)(k0 + kk) * Ni + n0 + n4 * 4);
    }
    __syncthreads();
#pragma unroll
    for (int kk = 0; kk < 16; ++kk) {
      const float4 av = *(const float4*)&As[kk][tm];
      const float4 bv = *(const float4*)&Bs[kk][tn];
      const float aa[4] = {av.x, av.y, av.z, av.w};
      const float bb[4] = {bv.x, bv.y, bv.z, bv.w};
#pragma unroll
      for (int i = 0; i < 4; ++i)
#pragma unroll
        for (int j = 0; j < 4; ++j) acc[i][j] += aa[i] * bb[j];
    }
    __syncthreads();
  }
#pragma unroll
  for (int i = 0; i < 4; ++i) {
    const int m = m0 + tm + i;
#pragma unroll
    for (int j = 0; j < 4; ++j) {
      const int n = n0 + tn + j;
      float v = acc[i][j];
      if (bias) v += bias[n];
      if (addm) v += addm[(size_t)m * Ni + n];
      Cm[(size_t)m * Ni + n] = v;
    }
  }
}

// ---------------- fused scatter GEMMs: EA (x<64) and EB (x>=64) ----------------
__global__ __launch_bounds__(256, 4) void gemm_scatter2(
    const float* __restrict__ tmp_h, const float* __restrict__ M_A,
    const float* __restrict__ xhat, const float* __restrict__ M_B,
    const float* __restrict__ cvec, const float* __restrict__ cb,
    float* __restrict__ A1, float* __restrict__ A2, float* __restrict__ Dc,
    float* __restrict__ B1, float* __restrict__ B2, float* __restrict__ Dr) {
  __shared__ float As[16][68];
  __shared__ float Bs[16][68];
  const bool isA = blockIdx.x < 64;
  const float* Am = isA ? tmp_h : xhat;
  const float* Bm = isA ? M_A : M_B;
  const int Ki = isA ? 256 : 128;
  const float* bias = isA ? nullptr : cvec;
  const float* add3 = isA ? cb : nullptr;
  float* O1 = isA ? A1 : B1;
  float* O2 = isA ? A2 : B2;
  float* O3 = isA ? Dc : Dr;
  const int m0 = (isA ? blockIdx.x : blockIdx.x - 64) * 64;
  const int n0 = blockIdx.y * 64;
  const int t = threadIdx.x;
  const int tm = (t & 15) * 4, tn = (t >> 4) * 4;
  float acc[4][4] = {};
  for (int k0 = 0; k0 < Ki; k0 += 16) {
    {
      const int row = t >> 2, q = t & 3;
      const float4 a4 = *(const float4*)(Am + (size_t)(m0 + row) * Ki + k0 + q * 4);
      As[q * 4 + 0][row] = a4.x; As[q * 4 + 1][row] = a4.y;
      As[q * 4 + 2][row] = a4.z; As[q * 4 + 3][row] = a4.w;
      const int kk = t >> 4, n4 = t & 15;
      *(float4*)&Bs[kk][n4 * 4] =
          *(const float4*)(Bm + (size_t)(k0 + kk) * 640 + n0 + n4 * 4);
    }
    __syncthreads();
#pragma unroll
    for (int kk = 0; kk < 16; ++kk) {
      const float4 av = *(const float4*)&As[kk][tm];
      const float4 bv = *(const float4*)&Bs[kk][tn];
      const float aa[4] = {av.x, av.y, av.z, av.w};
      const float bb[4] = {bv.x, bv.y, bv.z, bv.w};
#pragma unroll
      for (int i = 0; i < 4; ++i)
#pragma unroll
        for (int j = 0; j < 4; ++j) acc[i][j] += aa[i] * bb[j];
    }
    __syncthreads();
  }
#pragma unroll
  for (int i = 0; i < 4; ++i) {
    const int m = m0 + tm + i;
#pragma unroll
    for (int j = 0; j < 4; ++j) {
      const int n = n0 + tn + j;
      float v = acc[i][j];
      if (bias) v += bias[n];
      if (n < 256) {
        O1[(size_t)m * 256 + n] = v;
      } else if (n < 512) {
        O2[(size_t)m * 256 + n - 256] = v;
      } else {
        if (add3) v += add3[(size_t)m * 128 + n - 512];
        O3[(size_t)m * 128 + n - 512] = v;
      }
    }
  }
}

// ---------------- stage 1: bitwise-np f32 dists + stable top-32 ----------------
__global__ __launch_bounds__(512, 2) void k_stage1(
    const float* __restrict__ x, const float* __restrict__ xhat,
    const float* __restrict__ cbT, const float* __restrict__ cb_sq,
    int* __restrict__ topc) {
  __shared__ u32 distL[4 * 4096];  // 64 KB
  __shared__ float xtL[512];
  const int r0 = blockIdx.x * 4;
  const int t = threadIdx.x;
  {
    const int rr = r0 + (t >> 7), d = t & 127;
    xtL[t] = __fsub_rn(x[(rr >> 4) * 128 + d], xhat[rr * 128 + d]);
  }
  __syncthreads();
  {
    const int k0 = t * 8;
    float acc[4][8] = {};
    for (int d = 0; d < 128; ++d) {
      const float4 c0 = *(const float4*)&cbT[d * 4096 + k0];
      const float4 c1 = *(const float4*)&cbT[d * 4096 + k0 + 4];
      const float cv[8] = {c0.x, c0.y, c0.z, c0.w, c1.x, c1.y, c1.z, c1.w};
      const float x0 = xtL[d], x1 = xtL[128 + d], x2 = xtL[256 + d],
                  x3 = xtL[384 + d];
#pragma unroll
      for (int j = 0; j < 8; ++j) {
        acc[0][j] = __builtin_fmaf(x0, cv[j], acc[0][j]);
        acc[1][j] = __builtin_fmaf(x1, cv[j], acc[1][j]);
        acc[2][j] = __builtin_fmaf(x2, cv[j], acc[2][j]);
        acc[3][j] = __builtin_fmaf(x3, cv[j], acc[3][j]);
      }
    }
    const float4 s0 = *(const float4*)&cb_sq[k0];
    const float4 s1 = *(const float4*)&cb_sq[k0 + 4];
    const float cs[8] = {s0.x, s0.y, s0.z, s0.w, s1.x, s1.y, s1.z, s1.w};
#pragma unroll
    for (int rr = 0; rr < 4; ++rr)
#pragma unroll
      for (int j = 0; j < 8; ++j)
        distL[rr * 4096 + k0 + j] =
            ordu(__fsub_rn(cs[j], __fmul_rn(2.0f, acc[rr][j])));
  }
  __syncthreads();
  const int w = t >> 6, lane = t & 63;
  if (w < 4) {
    u32* dr = distL + w * 4096;
    u64 m1 = ~0ull, m2 = ~0ull;
    for (int e = 0; e < 64; ++e) {
      const int idx = e * 64 + lane;
      const u64 key = ((u64)dr[idx] << 32) | (u32)idx;
      if (key < m1) { m2 = m1; m1 = key; } else if (key < m2) { m2 = key; }
    }
    bool have2 = true;
    for (int it = 0; it < 32; ++it) {
      u64 g = m1;
#pragma unroll
      for (int sh = 1; sh < 64; sh <<= 1) {
        const u64 o = __shfl_xor(g, sh);
        g = (o < g) ? o : g;
      }
      const int bi = (int)(g & 0xFFFFFFFFu);
      if (lane == 0) topc[(r0 + w) * 32 + it] = bi;
      if ((bi & 63) == lane) {
        dr[bi] = 0xFFFFFFFFu;
        if (have2) {
          m1 = m2; m2 = ~0ull; have2 = false;
        } else {
          m1 = m2 = ~0ull;
          for (int e = 0; e < 64; ++e) {
            const int idx = e * 64 + lane;
            const u64 key = ((u64)dr[idx] << 32) | (u32)idx;
            if (key < m1) { m2 = m1; m1 = key; } else if (key < m2) { m2 = key; }
          }
          have2 = true;
        }
      }
    }
  }
}

// ---------------- stage 2: MFMA bf16 prescreen ----------------
__global__ __launch_bounds__(256, 4) void k_mlp(
    const int* __restrict__ topc, const float* __restrict__ A1,
    const float* __restrict__ A2, const float* __restrict__ B1,
    const float* __restrict__ B2, const float* __restrict__ Dc,
    const float* __restrict__ Dr, const u16* __restrict__ W21f,
    const u16* __restrict__ V1f, const u16* __restrict__ V2f,
    const float* __restrict__ xhat, const float* __restrict__ x,
    float* __restrict__ d2g) {
  __shared__ __align__(16) u16 abuf[32 * 264];  // 16.5 KB, r1 then r2
  __shared__ float B1r[256];
  __shared__ int codesL[32];
  __shared__ float d2red[32][4];

  const int tt = threadIdx.x;
  const int br = blockIdx.x;  // beam row
  const int bb = br >> 4;
  const int w = tt >> 6, l = tt & 63;

  B1r[tt] = B1[br * 256 + tt];
  if (tt < 32) codesL[tt] = topc[br * 32 + tt];
  __syncthreads();

  {
    const int c = tt & 31, g = tt >> 5;
    const int code = codesL[c];
    const float4* A14 = (const float4*)(A1 + code * 256 + g * 32);
    u32* dst = (u32*)(abuf + c * 264 + g * 32);
#pragma unroll
    for (int e4 = 0; e4 < 8; ++e4) {
      const float4 a = A14[e4];
      const int i = g * 32 + e4 * 4;
      const u32 p0 = (u32)f2bf(fmaxf(a.x + B1r[i], 0.f)) |
                     ((u32)f2bf(fmaxf(a.y + B1r[i + 1], 0.f)) << 16);
      const u32 p1 = (u32)f2bf(fmaxf(a.z + B1r[i + 2], 0.f)) |
                     ((u32)f2bf(fmaxf(a.w + B1r[i + 3], 0.f)) << 16);
      dst[e4 * 2] = p0;
      dst[e4 * 2 + 1] = p1;
    }
  }
  __syncthreads();

  const int arow = l & 15;
  const int kq = (l >> 4) * 8;
  const s16x8* wf = (const s16x8*)W21f;
  const s16x8* v1f = (const s16x8*)V1f;
  const s16x8* v2f = (const s16x8*)V2f;
  const f32x4 zero4 = {0.f, 0.f, 0.f, 0.f};

  f32x4 accf[2][4];
#pragma unroll
  for (int mt = 0; mt < 2; ++mt)
#pragma unroll
    for (int ntl = 0; ntl < 4; ++ntl) accf[mt][ntl] = zero4;
  for (int kt = 0; kt < 8; ++kt) {
    const s16x8 a0 = *(const s16x8*)(abuf + arow * 264 + kt * 32 + kq);
    const s16x8 a1 = *(const s16x8*)(abuf + (16 + arow) * 264 + kt * 32 + kq);
#pragma unroll
    for (int ntl = 0; ntl < 4; ++ntl) {
      const s16x8 b = wf[(kt * 16 + w * 4 + ntl) * 64 + l];
      accf[0][ntl] =
          __builtin_amdgcn_mfma_f32_16x16x32_bf16(a0, b, accf[0][ntl], 0, 0, 0);
      accf[1][ntl] =
          __builtin_amdgcn_mfma_f32_16x16x32_bf16(a1, b, accf[1][ntl], 0, 0, 0);
    }
  }

  f32x4 acc2f[2][2];
#pragma unroll
  for (int mt = 0; mt < 2; ++mt)
#pragma unroll
    for (int ntl = 0; ntl < 2; ++ntl) acc2f[mt][ntl] = zero4;
  for (int kt = 0; kt < 8; ++kt) {
    const s16x8 a0 = *(const s16x8*)(abuf + arow * 264 + kt * 32 + kq);
    const s16x8 a1 = *(const s16x8*)(abuf + (16 + arow) * 264 + kt * 32 + kq);
#pragma unroll
    for (int ntl = 0; ntl < 2; ++ntl) {
      const s16x8 b = v1f[(kt * 8 + w * 2 + ntl) * 64 + l];
      acc2f[0][ntl] = __builtin_amdgcn_mfma_f32_16x16x32_bf16(
          a0, b, acc2f[0][ntl], 0, 0, 0);
      acc2f[1][ntl] = __builtin_amdgcn_mfma_f32_16x16x32_bf16(
          a1, b, acc2f[1][ntl], 0, 0, 0);
    }
  }

  u16 r2v[2][4][4];
#pragma unroll
  for (int mt = 0; mt < 2; ++mt)
#pragma unroll
    for (int ntl = 0; ntl < 4; ++ntl) {
      const int n = w * 64 + ntl * 16 + arow;
      const float b2 = B2[br * 256 + n];
      const f32x4 cf = accf[mt][ntl];
#pragma unroll
      for (int rg = 0; rg < 4; ++rg) {
        const int m = mt * 16 + (l >> 4) * 4 + rg;
        const float a2 = A2[codesL[m] * 256 + n];
        r2v[mt][ntl][rg] = f2bf(fmaxf(cf[rg] + a2 + b2, 0.f));
      }
    }
  __syncthreads();
#pragma unroll
  for (int mt = 0; mt < 2; ++mt)
#pragma unroll
    for (int ntl = 0; ntl < 4; ++ntl) {
      const int n = w * 64 + ntl * 16 + arow;
#pragma unroll
      for (int rg = 0; rg < 4; ++rg) {
        const int m = mt * 16 + (l >> 4) * 4 + rg;
        abuf[m * 264 + n] = r2v[mt][ntl][rg];
      }
    }
  __syncthreads();

  for (int kt = 0; kt < 8; ++kt) {
    const s16x8 a0 = *(const s16x8*)(abuf + arow * 264 + kt * 32 + kq);
    const s16x8 a1 = *(const s16x8*)(abuf + (16 + arow) * 264 + kt * 32 + kq);
#pragma unroll
    for (int ntl = 0; ntl < 2; ++ntl) {
      const s16x8 b = v2f[(kt * 8 + w * 2 + ntl) * 64 + l];
      acc2f[0][ntl] = __builtin_amdgcn_mfma_f32_16x16x32_bf16(
          a0, b, acc2f[0][ntl], 0, 0, 0);
      acc2f[1][ntl] = __builtin_amdgcn_mfma_f32_16x16x32_bf16(
          a1, b, acc2f[1][ntl], 0, 0, 0);
    }
  }

  float sm[2][4];
#pragma unroll
  for (int mt = 0; mt < 2; ++mt)
#pragma unroll
    for (int rg = 0; rg < 4; ++rg) sm[mt][rg] = 0.f;
#pragma unroll
  for (int ntl = 0; ntl < 2; ++ntl) {
    const int d = w * 32 + ntl * 16 + arow;
    const float dr = Dr[br * 128 + d];
    const float xh = xhat[br * 128 + d];
    const float xq = x[bb * 128 + d];
#pragma unroll
    for (int mt = 0; mt < 2; ++mt) {
      const f32x4 cf = acc2f[mt][ntl];
#pragma unroll
      for (int rg = 0; rg < 4; ++rg) {
        const int m = mt * 16 + (l >> 4) * 4 + rg;
        const float cand = cf[rg] + Dc[codesL[m] * 128 + d] + dr + xh;
        sm[mt][rg] += cand * cand - 2.f * xq * cand;
      }
    }
  }
#pragma unroll
  for (int mt = 0; mt < 2; ++mt)
#pragma unroll
    for (int rg = 0; rg < 4; ++rg) {
      float s = sm[mt][rg];
      s += __shfl_xor(s, 1);
      s += __shfl_xor(s, 2);
      s += __shfl_xor(s, 4);
      s += __shfl_xor(s, 8);
      if (arow == 0) d2red[mt * 16 + (l >> 4) * 4 + rg][w] = s;
    }
  __syncthreads();
  if (tt < 32)
    d2g[bb * 512 + (br & 15) * 32 + tt] =
        d2red[tt][0] + d2red[tt][1] + d2red[tt][2] + d2red[tt][3];
}

// ---------------- stage 3a: prescreen top-32 per base query ----------------
__global__ __launch_bounds__(64, 1) void k_sel32(const float* __restrict__ d2g,
                                                 int* __restrict__ sel32) {
  __shared__ u32 d2u[512];
  const int bb = blockIdx.x;
  const int t = threadIdx.x;
  for (int i = t; i < 512; i += 64) d2u[i] = ordu(d2g[bb * 512 + i]);
  __syncthreads();
  for (int it = 0; it < 32; ++it) {
    u64 m = ~0ull;
#pragma unroll
    for (int e = 0; e < 8; ++e) {
      const int idx = e * 64 + t;
      const u64 key = ((u64)d2u[idx] << 32) | (u32)idx;
      m = (key < m) ? key : m;
    }
#pragma unroll
    for (int sh = 1; sh < 64; sh <<= 1) {
      const u64 o = __shfl_xor(m, sh);
      m = (o < m) ? o : m;
    }
    const int s = (int)(m & 0xFFFFFFFFu);
    if ((s & 63) == t) d2u[s] = 0xFFFFFFFFu;
    if (t == 0) sel32[bb * 32 + it] = s;
  }
}

// ---------------- stage 3b: np-emulated rescore of top-32 ----------------
// Thread layout: half (t>>7) owns 4 candidates, column pair (t&127, +128).
// Each accumulator's FMA chain (k ascending) is bit-identical to before.
__global__ __launch_bounds__(256, 5) void k_rescore(
    const int* __restrict__ sel32, const int* __restrict__ topc,
    const float* __restrict__ P, const float* __restrict__ cb,
    const float* __restrict__ xhat, const float* __restrict__ x,
    const float* __restrict__ cc_w, const float* __restrict__ cc_b,
    const float* __restrict__ rb_w1, const float* __restrict__ rb_b1,
    const float* __restrict__ rb_w2, const float* __restrict__ rb_b2,
    const float* __restrict__ out_w, const float* __restrict__ out_b,
    float* __restrict__ d2r, float* __restrict__ candv) {
  __shared__ float A_[8][256], B_[8][256], C_[8][256];
  __shared__ float xhL[8][128], xqL[128];
  __shared__ int codeL[8], rowL[8];
  const int bb = blockIdx.x >> 2;
  const int j0 = (blockIdx.x & 3) * 8;
  const int t = threadIdx.x;
  if (t < 8) {
    const int s = sel32[bb * 32 + j0 + t];
    rowL[t] = bb * 16 + (s >> 5);
    codeL[t] = topc[(bb * 16 + (s >> 5)) * 32 + (s & 31)];
  }
  if (t < 128) xqL[t] = x[bb * 128 + t];
  __syncthreads();
  for (int idx = t; idx < 1024; idx += 256) {
    const int c = idx >> 7, d = idx & 127;
    xhL[c][d] = xhat[rowL[c] * 128 + d];
  }
  __syncthreads();
  const int hc = t >> 7;   // candidate half
  const int c0 = hc * 4;
  const int jc = t & 127;  // columns jc, jc+128
  float a0[4], a1[4];

  // h0: acc starts at P[code] prefix; k-range = xhat part (cc_w rows 256..383)
#pragma unroll
  for (int c4 = 0; c4 < 4; ++c4) {
    a0[c4] = P[codeL[c0 + c4] * 256 + jc];
    a1[c4] = P[codeL[c0 + c4] * 256 + jc + 128];
  }
  layer_fma(&xhL[0][0], 128, c0, jc, cc_w + 256 * 256, 128, a0, a1);
  {
    const float ba = cc_b[jc], bbv = cc_b[jc + 128];
#pragma unroll
    for (int c4 = 0; c4 < 4; ++c4) {
      B_[c0 + c4][jc] = __fadd_rn(a0[c4], ba);
      B_[c0 + c4][jc + 128] = __fadd_rn(a1[c4], bbv);
    }
  }
  __syncthreads();
  // r1 = relu(h0 @ w1_0 + b1_0) -> C_
#pragma unroll
  for (int c4 = 0; c4 < 4; ++c4) { a0[c4] = 0.f; a1[c4] = 0.f; }
  layer_fma(&B_[0][0], 256, c0, jc, rb_w1, 256, a0, a1);
  {
    const float ba = rb_b1[jc], bbv = rb_b1[jc + 128];
#pragma unroll
    for (int c4 = 0; c4 < 4; ++c4) {
      C_[c0 + c4][jc] = fmaxf(__fadd_rn(a0[c4], ba), 0.f);
      C_[c0 + c4][jc + 128] = fmaxf(__fadd_rn(a1[c4], bbv), 0.f);
    }
  }
  __syncthreads();
  // h1 = (h0 + r1@w2_0) + b2_0 -> A_
#pragma unroll
  for (int c4 = 0; c4 < 4; ++c4) { a0[c4] = 0.f; a1[c4] = 0.f; }
  layer_fma(&C_[0][0], 256, c0, jc, rb_w2, 256, a0, a1);
  {
    const float ba = rb_b2[jc], bbv = rb_b2[jc + 128];
#pragma unroll
    for (int c4 = 0; c4 < 4; ++c4) {
      A_[c0 + c4][jc] = __fadd_rn(__fadd_rn(B_[c0 + c4][jc], a0[c4]), ba);
      A_[c0 + c4][jc + 128] =
          __fadd_rn(__fadd_rn(B_[c0 + c4][jc + 128], a1[c4]), bbv);
    }
  }
  __syncthreads();
  // r2 = relu(h1 @ w1_1 + b1_1) -> B_
#pragma unroll
  for (int c4 = 0; c4 < 4; ++c4) { a0[c4] = 0.f; a1[c4] = 0.f; }
  layer_fma(&A_[0][0], 256, c0, jc, rb_w1 + 65536, 256, a0, a1);
  {
    const float ba = rb_b1[256 + jc], bbv = rb_b1[256 + jc + 128];
#pragma unroll
    for (int c4 = 0; c4 < 4; ++c4) {
      B_[c0 + c4][jc] = fmaxf(__fadd_rn(a0[c4], ba), 0.f);
      B_[c0 + c4][jc + 128] = fmaxf(__fadd_rn(a1[c4], bbv), 0.f);
    }
  }
  __syncthreads();
  // h2 = (h1 + r2@w2_1) + b2_1 -> C_
#pragma unroll
  for (int c4 = 0; c4 < 4; ++c4) { a0[c4] = 0.f; a1[c4] = 0.f; }
  layer_fma(&B_[0][0], 256, c0, jc, rb_w2 + 65536, 256, a0, a1);
  {
    const float ba = rb_b2[256 + jc], bbv = rb_b2[256 + jc + 128];
#pragma unroll
    for (int c4 = 0; c4 < 4; ++c4) {
      C_[c0 + c4][jc] = __fadd_rn(__fadd_rn(A_[c0 + c4][jc], a0[c4]), ba);
      C_[c0 + c4][jc + 128] =
          __fadd_rn(__fadd_rn(A_[c0 + c4][jc + 128], a1[c4]), bbv);
    }
  }
  __syncthreads();
  // out: cand = ((h2@out_w + out_b) + cw_in) + xhat ; 4 cand x 1 d per thread
  {
    const int d = jc;
    float acc[4] = {};
    for (int i = 0; i < 256; i += 4) {
      const float w0 = out_w[(i + 0) * 128 + d], w1 = out_w[(i + 1) * 128 + d];
      const float w2 = out_w[(i + 2) * 128 + d], w3 = out_w[(i + 3) * 128 + d];
#pragma unroll
      for (int c4 = 0; c4 < 4; ++c4) {
        const float4 h = *(const float4*)&C_[c0 + c4][i];
        acc[c4] = __builtin_fmaf(h.x, w0, acc[c4]);
        acc[c4] = __builtin_fmaf(h.y, w1, acc[c4]);
        acc[c4] = __builtin_fmaf(h.z, w2, acc[c4]);
        acc[c4] = __builtin_fmaf(h.w, w3, acc[c4]);
      }
    }
    const float ob = out_b[d];
#pragma unroll
    for (int c4 = 0; c4 < 4; ++c4) {
      const int c = c0 + c4;
      const float cbv = cb[codeL[c] * 128 + d];
      const float cw_ = __fadd_rn(__fadd_rn(acc[c4], ob), cbv);
      const float cand = __fadd_rn(cw_, xhL[c][d]);
      B_[c][d] = cand;
      candv[(bb * 32 + j0 + c) * 128 + d] = cand;
    }
  }
  __syncthreads();
  if (t < 8) {
    float r[8];
#pragma unroll
    for (int j = 0; j < 8; ++j) {
      const float v = B_[t][j];
      r[j] = __fmul_rn(v, v);
    }
    for (int i = 8; i < 128; i += 8) {
#pragma unroll
      for (int j = 0; j < 8; ++j) {
        const float v = B_[t][i + j];
        r[j] = __fadd_rn(r[j], __fmul_rn(v, v));
      }
    }
    const float s1f = __fadd_rn(
        __fadd_rn(__fadd_rn(r[0], r[1]), __fadd_rn(r[2], r[3])),
        __fadd_rn(__fadd_rn(r[4], r[5]), __fadd_rn(r[6], r[7])));
    double s2 = 0.0;
    for (int d = 0; d < 128; ++d)
      s2 += (double)xqL[d] * (double)B_[t][d];
    const float s2f = (float)s2;
    d2r[bb * 32 + j0 + t] = __fsub_rn(s1f, __fmul_rn(2.0f, s2f));
  }
}

// ---------------- stage 3c/4: stable top-16 by f32 d2 ----------------
__global__ __launch_bounds__(64, 1) void k_final(
    const float* __restrict__ d2r, const int* __restrict__ sel32,
    const int* __restrict__ topc, const int* __restrict__ codes_in,
    const float* __restrict__ candv, float* __restrict__ out) {
  __shared__ u32 winLo[16];
  const int bb = blockIdx.x;
  const int t = threadIdx.x;
  u64 key = ~0ull;
  if (t < 32) {
    const u32 s = (u32)sel32[bb * 32 + t];
    key = ((u64)ordu(d2r[bb * 32 + t]) << 32) | (s << 5) | (u32)t;
  }
  for (int it = 0; it < 16; ++it) {
    u64 m = key;
#pragma unroll
    for (int sh = 1; sh < 64; sh <<= 1) {
      const u64 o = __shfl_xor(m, sh);
      m = (o < m) ? o : m;
    }
    if (key == m) key = ~0ull;
    if (t == 0) winLo[it] = (u32)(m & 0xFFFFFFFFu);
  }
  __syncthreads();
  if (t < 16) {
    const u32 lo = winLo[t];
    const int s = (int)((lo >> 5) & 511u);
    const int f = s >> 5;
    const int code = topc[(bb * 16 + f) * 32 + (s & 31)];
    float* oc = out + 512 * 16 * 128;
    oc[bb * 16 + t] = (float)codes_in[bb * 16 + f];
    oc[8192 + bb * 16 + t] = (float)codes_in[8192 + bb * 16 + f];
    oc[16384 + bb * 16 + t] = (float)code;
  }
  __syncthreads();
  for (int idx = t; idx < 2048; idx += 64) {
    const int w_ = idx >> 7, d = idx & 127;
    const int j = (int)(winLo[w_] & 31u);
    out[(bb * 16 + w_) * 128 + d] = candv[(bb * 32 + j) * 128 + d];
  }
}

// ---------------- launch ----------------
extern "C" void kernel_launch(void* const* d_in, const int* in_sizes, int n_in,
                              void* d_out, int out_size, void* d_ws,
                              size_t ws_size, hipStream_t stream) {
  const float* x = (const float*)d_in[0];
  const float* xhat = (const float*)d_in[1];
  const int* codes = (const int*)d_in[2];
  const float* cb = (const float*)d_in[3];
  const float* cbrq = (const float*)d_in[4];
  const float* in_w = (const float*)d_in[5];
  const float* in_b = (const float*)d_in[6];
  const float* cc_w = (const float*)d_in[7];
  const float* cc_b = (const float*)d_in[8];
  const float* rb_w1 = (const float*)d_in[9];
  const float* rb_b1 = (const float*)d_in[10];
  const float* rb_w2 = (const float*)d_in[11];
  const float* rb_b2 = (const float*)d_in[12];
  const float* out_w = (const float*)d_in[13];
  const float* out_b = (const float*)d_in[14];
  float* out = (float*)d_out;

  float* ws = (float*)d_ws;
  size_t o = 0;
  float* cb_sq = ws + o; o += 4096;
  float* P = ws + o;     o += (size_t)4096 * 256;
  float* cbT = ws + o;   const size_t cbT_off = o; o += (size_t)128 * 4096;
  float* tmp_h = ws + o; o += (size_t)4096 * 256;
  float* Wcat = ws + o;  o += (size_t)256 * 640;
  float* M_A = ws + o;   o += (size_t)256 * 640;
  float* M_B = ws + o;   o += (size_t)128 * 640;
  float* cvec = ws + o;  o += 640;
  float* A1 = ws + o;    o += (size_t)4096 * 256;
  float* A2 = ws + o;    o += (size_t)4096 * 256;
  float* Dc = ws + o;    o += (size_t)4096 * 128;
  float* B1 = ws + o;    o += (size_t)8192 * 256;
  float* B2 = ws + o;    o += (size_t)8192 * 256;
  float* Dr = ws + o;    o += (size_t)8192 * 128;
  int* topc = (int*)(ws + o); o += 262144;
  float* d2g = ws + o;   o += 262144;
  u16* W21f = (u16*)(ws + o); o += 32768;  // 65536 bf16
  u16* V1f = (u16*)(ws + o);  o += 16384;  // 32768 bf16
  u16* V2f = (u16*)(ws + o);  o += 16384;
  float* candv = ws + o; o += (size_t)16384 * 128;
  float* d2r = ws + cbT_off;                 // cbT dead after k_stage1
  int* sel32 = (int*)(ws + cbT_off + 16384);

  k_prep1<<<dim3(4545), dim3(256), 0, stream>>>(
      cbrq, cbT, cb_sq, cb, in_w, in_b, cc_w, tmp_h, P, rb_b1, rb_b2, rb_w1,
      out_w, out_b, cc_b, cvec, Wcat, rb_w2, W21f, V1f, V2f);
  gemm_f32<<<dim3(4, 10), dim3(256), 0, stream>>>(cc_w, Wcat, M_A, 256, 640,
                                                  256, nullptr, nullptr);
  gemm_f32<<<dim3(2, 10), dim3(256), 0, stream>>>(cc_w + 256 * 256, Wcat, M_B,
                                                  128, 640, 256, nullptr,
                                                  nullptr);
  gemm_scatter2<<<dim3(192, 10), dim3(256), 0, stream>>>(
      tmp_h, M_A, xhat, M_B, cvec, cb, A1, A2, Dc, B1, B2, Dr);

  k_stage1<<<dim3(2048), dim3(512), 0, stream>>>(x, xhat, cbT, cb_sq, topc);
  k_mlp<<<dim3(8192), dim3(256), 0, stream>>>(topc, A1, A2, B1, B2, Dc, Dr,
                                              W21f, V1f, V2f, xhat, x, d2g);
  k_sel32<<<dim3(512), dim3(64), 0, stream>>>(d2g, sel32);
  k_rescore<<<dim3(2048), dim3(256), 0, stream>>>(
      sel32, topc, P, cb, xhat, x, cc_w, cc_b, rb_w1, rb_b1, rb_w2, rb_b2,
      out_w, out_b, d2r, candv);
  k_final<<<dim3(512), dim3(64), 0, stream>>>(d2r, sel32, topc, codes, candv,
                                              out);
  (void)in_sizes; (void)n_in; (void)out_size; (void)ws_size;
}